// Round 10
// baseline (6094.823 us; speedup 1.0000x reference)
//
#include <hip/hip_runtime.h>
#include <hip/hip_bf16.h>
#include <math.h>

// ============================================================================
// PPGPeakPerformer forward on MI355X (gfx950)
// B=32 S=4096 D=256 DH=128 H=8 HD=32 F=64 L=4
// GEMM: 128xBN tile (BN=128 wide-N, BN=64 narrow-N for grid parallelism),
// BK=32, double-buffered LDS, depth-1 prefetch, tight vmcnt(0) + raw
// s_barrier. Occupancy-first (r5-r9 evidence: TLP is the lever):
// BN=128 -> 32KB LDS, 5 blocks/CU; BN=64 -> 24KB LDS, 6 blocks/CU.
// Swizzle slot^((row>>1)&3) both-sides. Fast rational erf. Fused q/k RF
// projection GEMM. kv_reduce folded into combine_mfma.
// ============================================================================

typedef __bf16 bf16_t;
typedef __bf16 bf16x8 __attribute__((ext_vector_type(8)));
typedef __bf16 bf16x4 __attribute__((ext_vector_type(4)));
typedef float  f32x4  __attribute__((ext_vector_type(4)));

#define DEV __device__ __forceinline__

DEV float erf_fast(float x) {
  float ax = fabsf(x);
  float t = __builtin_amdgcn_rcpf(1.f + 0.3275911f * ax);
  float p = t * (0.254829592f + t * (-0.284496736f + t * (1.421413741f +
            t * (-1.453152027f + t * 1.061405429f))));
  float r = 1.f - p * __expf(-ax * ax);
  return copysignf(r, x);
}
DEV float geluf(float v) { return 0.5f * v * (1.f + erf_fast(v * 0.70710678118654752440f)); }
DEV float softplusf(float v) {
  float e = __expf(-fabsf(v));
  return fmaxf(v, 0.f) + __logf(1.f + e);
}

// Direct global->LDS 16B staging. LDS dest is wave-uniform base + lane*16.
DEV void gload16(const bf16_t* g, bf16_t* l) {
  __builtin_amdgcn_global_load_lds(
      (const __attribute__((address_space(1))) void*)g,
      (__attribute__((address_space(3))) void*)l, 16, 0, 0);
}

// ---------------------------------------------------------------------------
// GEMM: C[m,n] = sum_k A[m,k]*Bt[n,k].  A bf16 (batched rows), Bt bf16 [N][K].
// EPI: 1 = +bias +resid -> fp32; 2 = gelu(+bias) -> bf16;
//      3 = gelu(scale*x+bias)+pe -> fp32; 4 = gelu(scale*x+bias) -> bf16;
//      5 = col<1024 ? softplus(+bias) : (+bias) -> bf16
// Tile 128 x BN.  BN=128: 4 waves 2x2, each 64x64, acc[4][4], all waves
// stage 32 A-rows + 32 B-rows.  BN=64: 4 waves 4x1, each 32x64, acc[2][4],
// all waves stage 32 A-rows, waves 0/1 stage 32 B-rows each.
// BK=32 (64B rows = 4x16B slots). Swizzle: LDS slot = src_slot ^ ((row>>1)&3)
// via pre-swizzled global source; LDS dest linear (gload_lds rule).
// Double buffer, depth-1: wait S(t) [vmcnt(0), tight], barrier, issue S(t+1),
// compute t. Residual stall hidden by 5-6 independent blocks/CU of TLP.
// ---------------------------------------------------------------------------
template <int EPI, int K, int BN>
__global__ __launch_bounds__(256, (BN == 64 ? 6 : 5))
void gemm_bf16(const bf16_t* __restrict__ A, const bf16_t* __restrict__ Bt,
               void* Cout, const float* __restrict__ bias,
               const float* __restrict__ scale, const float* resid,
               const float* __restrict__ pe,
               int lda, long a_bstride, int rpb,
               int N, int ldc, long c_bstride, int c_roff)
{
  constexpr int MI = (BN == 128) ? 4 : 2;   // row-fragments per wave
  __shared__ bf16_t As[2][128 * 32];
  __shared__ bf16_t Bs[2][BN * 32];
  const int t = threadIdx.x;
  const int lane = t & 63;
  const int w = t >> 6;
  const int wrow = (BN == 128) ? (w >> 1) * 64 : w * 32;
  const int wcol = (BN == 128) ? (w & 1) * 64 : 0;
  const long m0 = (long)blockIdx.x * 128;
  const int n0 = blockIdx.y * BN;
  const int b = (int)(m0 / rpb);
  const int s_base = (int)(m0 % rpb);
  const bf16_t* Ab = A + (long)b * a_bstride + (long)s_base * lda;
  const bf16_t* Bb = Bt + (long)n0 * K;

  // staging source (pre-swizzled): lane covers row (lane>>2) of a 16-row
  // block, 16B slot ((lane&3) ^ ((row>>1)&3)).
  const int srow = lane >> 2;
  const int sslot = (lane & 3) ^ ((srow >> 1) & 3);
  const bf16_t* aS = Ab + (long)(w * 32 + srow) * lda + sslot * 8;
  const bf16_t* bS = Bb + (long)(w * 32 + srow) * K + sslot * 8;
  const int dsto = w * 1024;  // 32 rows x 32 elems per wave

#define STAGE(bufidx, kk)                                   \
  {                                                         \
    bf16_t* a_ = &As[bufidx][dsto];                         \
    gload16(aS + (kk), a_);                                 \
    gload16(aS + (kk) + 16 * (long)lda, a_ + 512);          \
    if (BN == 128 || w < 2) {                               \
      bf16_t* b_ = &Bs[bufidx][dsto];                       \
      gload16(bS + (kk), b_);                               \
      gload16(bS + (kk) + 16 * (long)K, b_ + 512);          \
    }                                                       \
  }

  f32x4 acc[MI][4];
#pragma unroll
  for (int i = 0; i < MI; i++)
#pragma unroll
    for (int j = 0; j < 4; j++) acc[i][j] = (f32x4){0.f, 0.f, 0.f, 0.f};

  constexpr int NT = K >> 5;
  STAGE(0, 0);

#pragma unroll
  for (int tt = 0; tt < NT; ++tt) {
    asm volatile("s_waitcnt vmcnt(0)" ::: "memory");
    __builtin_amdgcn_s_barrier();
    __builtin_amdgcn_sched_barrier(0);
    if (tt + 1 < NT) STAGE((tt + 1) & 1, (tt + 1) * 32);
    const int cb = tt & 1;
    const bf16_t* Acur = As[cb];
    const bf16_t* Bcur = Bs[cb];
    const int kb = (lane >> 4) * 16;
    bf16x8 af[MI], bfr[4];
#pragma unroll
    for (int i = 0; i < MI; i++) {
      int rA = wrow + i * 16 + (lane & 15);
      af[i] = *(const bf16x8*)((const char*)Acur + rA * 64 + (kb ^ (((rA >> 1) & 3) << 4)));
    }
#pragma unroll
    for (int j = 0; j < 4; j++) {
      int rB = wcol + j * 16 + (lane & 15);
      bfr[j] = *(const bf16x8*)((const char*)Bcur + rB * 64 + (kb ^ (((rB >> 1) & 3) << 4)));
    }
    __builtin_amdgcn_s_setprio(1);
#pragma unroll
    for (int mi = 0; mi < MI; mi++)
#pragma unroll
      for (int ni = 0; ni < 4; ni++)
        acc[mi][ni] = __builtin_amdgcn_mfma_f32_16x16x32_bf16(af[mi], bfr[ni], acc[mi][ni], 0, 0, 0);
    __builtin_amdgcn_s_setprio(0);
  }
#undef STAGE

  const int colbase = n0 + wcol + (lane & 15);
  float bias_r[4], scale_r[4];
#pragma unroll
  for (int ni = 0; ni < 4; ni++) {
    int col = colbase + ni * 16;
    bias_r[ni] = bias[col];
    scale_r[ni] = (EPI == 3 || EPI == 4) ? scale[col] : 0.f;
  }
#pragma unroll
  for (int mi = 0; mi < MI; mi++) {
#pragma unroll
    for (int j = 0; j < 4; j++) {
      int row = wrow + mi * 16 + ((lane >> 4) << 2) + j;
      long s = s_base + row;
      long cro = (long)b * c_bstride + (s + c_roff) * (long)ldc;
#pragma unroll
      for (int ni = 0; ni < 4; ni++) {
        int col = colbase + ni * 16;
        float v = acc[mi][ni][j];
        if constexpr (EPI == 1) {
          v += bias_r[ni] + resid[cro + col];
          ((float*)Cout)[cro + col] = v;
        } else if constexpr (EPI == 2) {
          v = geluf(v + bias_r[ni]);
          ((bf16_t*)Cout)[cro + col] = (bf16_t)v;
        } else if constexpr (EPI == 3) {
          v = geluf(v * scale_r[ni] + bias_r[ni]) + pe[s * 256 + col];
          ((float*)Cout)[cro + col] = v;
        } else if constexpr (EPI == 4) {
          v = geluf(v * scale_r[ni] + bias_r[ni]);
          ((bf16_t*)Cout)[cro + col] = (bf16_t)v;
        } else {  // 5
          v += bias_r[ni];
          if (col < 1024) v = softplusf(v);
          ((bf16_t*)Cout)[cro + col] = (bf16_t)v;
        }
      }
    }
  }
}

// ---------------------------------------------------------------------------
// LayerNorm over D=256, fp32 in -> bf16 out. 4 rows/block (1 wave per row).
// ---------------------------------------------------------------------------
__global__ __launch_bounds__(256)
void ln_kernel(const float* __restrict__ h, const float* __restrict__ g,
               const float* __restrict__ bta, bf16_t* __restrict__ out)
{
  int t = threadIdx.x;
  int lane = t & 63;
  long row = (long)blockIdx.x * 4 + (t >> 6);
  const float* hp = h + row * 256 + lane * 4;
  float4 v = *(const float4*)hp;
  float s = v.x + v.y + v.z + v.w;
  float q = v.x * v.x + v.y * v.y + v.z * v.z + v.w * v.w;
#pragma unroll
  for (int m = 32; m >= 1; m >>= 1) {
    s += __shfl_xor(s, m);
    q += __shfl_xor(q, m);
  }
  float mean = s * 0.00390625f;
  float var = q * 0.00390625f - mean * mean;
  float rstd = rsqrtf(var + 1e-5f);
  int c = lane * 4;
  float4 gv = *(const float4*)(g + c);
  float4 bv = *(const float4*)(bta + c);
  bf16x4 o;
  o[0] = (bf16_t)((v.x - mean) * rstd * gv.x + bv.x);
  o[1] = (bf16_t)((v.y - mean) * rstd * gv.y + bv.y);
  o[2] = (bf16_t)((v.z - mean) * rstd * gv.z + bv.z);
  o[3] = (bf16_t)((v.w - mean) * rstd * gv.w + bv.w);
  *(bf16x4*)(out + row * 256 + c) = o;
}

// ---------------------------------------------------------------------------
// Embedding conv1: x[Bc,S] -> gelu(bn(conv1d k=7 pad=3)) -> h1p[Bc,S+4,128]
// ---------------------------------------------------------------------------
__global__ __launch_bounds__(256)
void conv1_kernel(const float* __restrict__ x, const float* __restrict__ w1,
                  const float* __restrict__ sc, const float* __restrict__ sb,
                  bf16_t* __restrict__ h1p)
{
  int b = blockIdx.x >> 6;
  int s0 = (blockIdx.x & 63) << 6;
  __shared__ float xs[70];
  __shared__ float ws[896];
  int t = threadIdx.x;
  if (t < 70) {
    int s = s0 + t - 3;
    xs[t] = (s >= 0 && s < 4096) ? x[(long)b * 4096 + s] : 0.f;
  }
  for (int i = t; i < 896; i += 256) ws[i] = w1[i];
  __syncthreads();
  int c = t & 127, so = t >> 7;
  float wr[7];
#pragma unroll
  for (int k = 0; k < 7; k++) wr[k] = ws[c * 7 + k];
  float scl = sc[c], sbv = sb[c];
  for (int p = 0; p < 32; p++) {
    int sl = p * 2 + so;
    float a = 0.f;
#pragma unroll
    for (int k = 0; k < 7; k++) a += xs[sl + k] * wr[k];
    a = geluf(a * scl + sbv);
    h1p[((long)b * 4100 + s0 + sl + 2) * 128 + c] = (bf16_t)a;
  }
}

// ---------------------------------------------------------------------------
// kv partial: per (b,h,chunk of 512 s): acc[f][d] += kp[s,f]*v[s,d]; +ksum.
// ---------------------------------------------------------------------------
__global__ __launch_bounds__(256)
void kv_partial(const bf16_t* __restrict__ qpkpv,
                float* __restrict__ pkv, float* __restrict__ pks)
{
  int bh = blockIdx.x >> 3, ch = blockIdx.x & 7;
  int b = bh >> 3, hh = bh & 7;
  int s0 = ch * 512;
  __shared__ float kps[32 * 64];
  __shared__ float vs[32 * 32];
  int t = threadIdx.x;
  int f = t & 63, dg = t >> 6;
  float acc[8] = {0.f, 0.f, 0.f, 0.f, 0.f, 0.f, 0.f, 0.f};
  float ks = 0.f;
  const int row = t >> 3, slot8 = (t & 7) * 8, slot4 = (t & 7) * 4;
  for (int sb = 0; sb < 512; sb += 32) {
    __syncthreads();
    {
      const bf16_t* rowp = qpkpv + ((long)b * 4096 + s0 + sb + row) * 1280;
      bf16x8 k8 = *(const bf16x8*)(rowp + 512 + hh * 64 + slot8);
#pragma unroll
      for (int j = 0; j < 8; j++) kps[row * 64 + slot8 + j] = (float)k8[j];
      bf16x4 v4 = *(const bf16x4*)(rowp + 1024 + hh * 32 + slot4);
#pragma unroll
      for (int j = 0; j < 4; j++) vs[row * 32 + slot4 + j] = (float)v4[j];
    }
    __syncthreads();
#pragma unroll 4
    for (int s = 0; s < 32; s++) {
      float kval = kps[s * 64 + f];
      float4 v0 = *(const float4*)&vs[s * 32 + dg * 8];
      float4 v1 = *(const float4*)&vs[s * 32 + dg * 8 + 4];
      acc[0] += kval * v0.x; acc[1] += kval * v0.y;
      acc[2] += kval * v0.z; acc[3] += kval * v0.w;
      acc[4] += kval * v1.x; acc[5] += kval * v1.y;
      acc[6] += kval * v1.z; acc[7] += kval * v1.w;
      ks += kval;
    }
  }
  long o = (long)blockIdx.x * 2048 + f * 32 + dg * 8;
#pragma unroll
  for (int j = 0; j < 8; j++) pkv[o + j] = acc[j];
  if (dg == 0) pks[blockIdx.x * 64 + f] = ks;
}

// ---------------------------------------------------------------------------
// combine: ao[s, h*32+d] = (qp[s,:] @ kv[:,d]) / (qp[s,:]@ksum + 1e-8)
// kv/ksum reduced from 8 chunk-partials inline (deterministic order).
// ---------------------------------------------------------------------------
__global__ __launch_bounds__(256, 2)
void combine_mfma(const bf16_t* __restrict__ qpkpv, const float* __restrict__ pkv,
                  const float* __restrict__ pks, bf16_t* __restrict__ ao)
{
  int bh = blockIdx.x >> 5;
  int s0 = (blockIdx.x & 31) << 7;
  int b = bh >> 3, hh = bh & 7;
  __shared__ bf16_t A_s[128 * 72];
  __shared__ bf16_t B_s[48 * 72];
  int t = threadIdx.x;
  for (int g = t; g < 1024; g += 256) {
    int row = g >> 3, slot = (g & 7) * 8;
    *(bf16x8*)&A_s[row * 72 + slot] =
        *(const bf16x8*)(qpkpv + ((long)b * 4096 + s0 + row) * 1280 + hh * 64 + slot);
  }
  for (int i = t; i < 2048; i += 256) {
    float s = 0.f;
#pragma unroll
    for (int ch = 0; ch < 8; ch++) s += pkv[((long)(bh * 8 + ch)) * 2048 + i];
    int f = i >> 5, d = i & 31;
    B_s[d * 72 + f] = (bf16_t)s;
  }
  if (t < 64) {
    float s = 0.f;
#pragma unroll
    for (int ch = 0; ch < 8; ch++) s += pks[(bh * 8 + ch) * 64 + t];
    B_s[32 * 72 + t] = (bf16_t)s;
  }
  for (int i = t; i < 960; i += 256) {
    int n = 33 + (i >> 6), f = i & 63;
    B_s[n * 72 + f] = (bf16_t)0.f;
  }
  __syncthreads();
  int lane = t & 63, w = t >> 6;
  f32x4 acc[2][3];
#pragma unroll
  for (int i = 0; i < 2; i++)
#pragma unroll
    for (int j = 0; j < 3; j++) acc[i][j] = (f32x4){0.f, 0.f, 0.f, 0.f};
#pragma unroll
  for (int kt = 0; kt < 2; kt++) {
    int ko = kt * 32 + (lane >> 4) * 8;
    bf16x8 a[2], bb[3];
#pragma unroll
    for (int i = 0; i < 2; i++)
      a[i] = *(const bf16x8*)&A_s[(w * 32 + i * 16 + (lane & 15)) * 72 + ko];
#pragma unroll
    for (int i = 0; i < 3; i++)
      bb[i] = *(const bf16x8*)&B_s[(i * 16 + (lane & 15)) * 72 + ko];
#pragma unroll
    for (int mi = 0; mi < 2; mi++)
#pragma unroll
      for (int ni = 0; ni < 3; ni++)
        acc[mi][ni] = __builtin_amdgcn_mfma_f32_16x16x32_bf16(a[mi], bb[ni], acc[mi][ni], 0, 0, 0);
  }
  long sbase = (long)b * 4096 + s0;
#pragma unroll
  for (int mi = 0; mi < 2; mi++)
#pragma unroll
    for (int j = 0; j < 4; j++) {
      int r = w * 32 + mi * 16 + ((lane >> 4) << 2) + j;
      float den = __shfl(acc[mi][2][j], (lane & 48)) + 1e-8f;
#pragma unroll
      for (int ni = 0; ni < 2; ni++) {
        int d = ni * 16 + (lane & 15);
        ao[(sbase + r) * 256 + hh * 32 + d] = (bf16_t)(acc[mi][ni][j] / den);
      }
    }
}

// ---------------------------------------------------------------------------
// h fp32 -> h_padded bf16 [Bc, S+4, 256] (rows offset +2)
// ---------------------------------------------------------------------------
__global__ __launch_bounds__(256)
void cast_pad(const float* __restrict__ h, bf16_t* __restrict__ hp)
{
  long i8 = ((long)blockIdx.x * 256 + threadIdx.x) * 8;
  long r = i8 >> 8;
  int c = (int)(i8 & 255);
  int b = (int)(r >> 12), s = (int)(r & 4095);
  float4 v0 = *(const float4*)(h + i8);
  float4 v1 = *(const float4*)(h + i8 + 4);
  bf16x8 o;
  o[0] = (bf16_t)v0.x; o[1] = (bf16_t)v0.y; o[2] = (bf16_t)v0.z; o[3] = (bf16_t)v0.w;
  o[4] = (bf16_t)v1.x; o[5] = (bf16_t)v1.y; o[6] = (bf16_t)v1.z; o[7] = (bf16_t)v1.w;
  *(bf16x8*)(hp + ((long)b * 4100 + s + 2) * 256 + c) = o;
}

// ---------------------------------------------------------------------------
// Final conv (DH->1, k=3, pad=1) + sigmoid -> out [Bc,S] fp32
// ---------------------------------------------------------------------------
__global__ __launch_bounds__(256)
void conv_final(const bf16_t* __restrict__ hdp, const float* __restrict__ w2,
                const float* __restrict__ b2, float* __restrict__ out)
{
  __shared__ float ws[384];
  int t = threadIdx.x;
  for (int i = t; i < 384; i += 256) ws[i] = w2[i];  // [c][k]
  __syncthreads();
  long idx = (long)blockIdx.x * 256 + t;
  int b = (int)(idx >> 12);
  const bf16_t* base = hdp + ((long)b * 4098 + (idx & 4095)) * 128;
  float a = b2[0];
#pragma unroll
  for (int k = 0; k < 3; k++) {
#pragma unroll
    for (int c8 = 0; c8 < 16; c8++) {
      bf16x8 v = *(const bf16x8*)(base + k * 128 + c8 * 8);
#pragma unroll
      for (int j = 0; j < 8; j++) a += (float)v[j] * ws[(c8 * 8 + j) * 3 + k];
    }
  }
  out[idx] = 1.f / (1.f + __expf(-a));
}

// ---------------------------------------------------------------------------
// Prep kernels (once per launch)
// ---------------------------------------------------------------------------
__global__ __launch_bounds__(256)
void prep_weff(const float* __restrict__ wq, const float* __restrict__ wk,
               const float* __restrict__ wv, const float* __restrict__ bq,
               const float* __restrict__ bk, const float* __restrict__ bv,
               const float* __restrict__ rf, bf16_t* __restrict__ weff,
               float* __restrict__ beff)
{
  long idx = (long)blockIdx.x * 256 + threadIdx.x;  // 4*1280*256
  int d = (int)(idx & 255);
  long r = idx >> 8;
  int n = (int)(r % 1280);
  int l = (int)(r / 1280);
  float val;
  if (n < 1024) {
    int qk = n >> 9;
    int h = (n >> 6) & 7;
    int f = n & 63;
    const float* w = qk ? wk : wq;
    const float* rfh = rf + ((long)(l * 8 + h) * 32) * 64 + f;
    const float* wrow = w + ((long)l * 256 + d) * 256 + h * 32;
    float s = 0.f;
#pragma unroll
    for (int hd = 0; hd < 32; hd++) s += wrow[hd] * rfh[hd * 64];
    val = s;
  } else {
    val = wv[((long)l * 256 + d) * 256 + (n - 1024)];
  }
  weff[idx] = (bf16_t)val;
  if (idx < 4 * 1280) {
    int nn = (int)(idx % 1280);
    int ll = (int)(idx / 1280);
    float bvv;
    if (nn < 1024) {
      int qk = nn >> 9;
      int h = (nn >> 6) & 7;
      int f = nn & 63;
      const float* bsrc = qk ? bk : bq;
      float s = 0.f;
      for (int hd = 0; hd < 32; hd++)
        s += bsrc[ll * 256 + h * 32 + hd] * rf[((long)(ll * 8 + h) * 32 + hd) * 64 + f];
      bvv = s;
    } else {
      bvv = bv[ll * 256 + (nn - 1024)];
    }
    beff[idx] = bvv;
  }
}

__global__ __launch_bounds__(256)
void prep_cast_t(const float* __restrict__ src, bf16_t* __restrict__ dst, int K, int N)
{
  long idx = (long)blockIdx.x * 256 + threadIdx.x;  // nmats*N*K
  int k = (int)(idx % K);
  long r = idx / K;
  int n = (int)(r % N);
  int l = (int)(r / N);
  dst[idx] = (bf16_t)src[((long)l * K + k) * N + n];
}

__global__ __launch_bounds__(256)
void prep_conv_t(const float* __restrict__ w, bf16_t* __restrict__ dst, int C, int KW)
{
  long idx = (long)blockIdx.x * 256 + threadIdx.x;  // O*C*KW
  int ckw = C * KW;
  int kk = (int)(idx % ckw);
  int o = (int)(idx / ckw);
  int kw = kk / C, c = kk % C;
  dst[idx] = (bf16_t)w[((long)o * C + c) * KW + kw];
}

__global__ __launch_bounds__(256)
void prep_bn(const float* g1, const float* b1, const float* cb1,
             const float* g2, const float* b2, const float* cb2,
             const float* g3, const float* b3, const float* cb3,
             float* sc1, float* sb1, float* sc2, float* sb2,
             float* sc3, float* sb3)
{
  int t = threadIdx.x;
  const float r = rsqrtf(1.f + 1e-5f);
  if (t < 128) { float s = g1[t] * r; sc1[t] = s; sb1[t] = cb1[t] * s + b1[t]; }
  if (t < 256) { float s = g2[t] * r; sc2[t] = s; sb2[t] = cb2[t] * s + b2[t]; }
  if (t < 128) { float s = g3[t] * r; sc3[t] = s; sb3[t] = cb3[t] * s + b3[t]; }
}

__global__ __launch_bounds__(256)
void pe_fill(float* __restrict__ pe)
{
  long idx = (long)blockIdx.x * 256 + threadIdx.x;  // 4096*256
  int dcol = (int)(idx & 255);
  int s = (int)(idx >> 8);
  int i2 = dcol >> 1;
  float freq = expf(-9.210340371976184f * (float)(2 * i2) / 256.f);
  float a = (float)s * freq;
  pe[idx] = (dcol & 1) ? cosf(a) : sinf(a);
}

// ---------------------------------------------------------------------------
extern "C" void kernel_launch(void* const* d_in, const int* in_sizes, int n_in,
                              void* d_out, int out_size, void* d_ws, size_t ws_size,
                              hipStream_t stream)
{
  (void)in_sizes; (void)n_in; (void)out_size;
  const float* x      = (const float*)d_in[0];
  const float* emb_w1 = (const float*)d_in[1];
  const float* emb_b1 = (const float*)d_in[2];
  const float* bn1_g  = (const float*)d_in[3];
  const float* bn1_b  = (const float*)d_in[4];
  const float* emb_w2 = (const float*)d_in[5];
  const float* emb_b2 = (const float*)d_in[6];
  const float* bn2_g  = (const float*)d_in[7];
  const float* bn2_b  = (const float*)d_in[8];
  const float* wq     = (const float*)d_in[9];
  const float* bq     = (const float*)d_in[10];
  const float* wk     = (const float*)d_in[11];
  const float* bk     = (const float*)d_in[12];
  const float* wv     = (const float*)d_in[13];
  const float* bv     = (const float*)d_in[14];
  const float* wo     = (const float*)d_in[15];
  const float* bo     = (const float*)d_in[16];
  const float* rf     = (const float*)d_in[17];
  const float* ln1_g  = (const float*)d_in[18];
  const float* ln1_b  = (const float*)d_in[19];
  const float* ln2_g  = (const float*)d_in[20];
  const float* ln2_b  = (const float*)d_in[21];
  const float* ff_w1  = (const float*)d_in[22];
  const float* ff_b1  = (const float*)d_in[23];
  const float* ff_w2  = (const float*)d_in[24];
  const float* ff_b2  = (const float*)d_in[25];
  const float* dec_w1 = (const float*)d_in[26];
  const float* dec_b1 = (const float*)d_in[27];
  const float* bn3_g  = (const float*)d_in[28];
  const float* bn3_b  = (const float*)d_in[29];
  const float* dec_w2 = (const float*)d_in[30];
  const float* dec_b2 = (const float*)d_in[31];

  char* W = (char*)d_ws;

  // ---- fixed region (weights, ~12.2 MB; reserve 16 MB) ----
  bf16_t* weff = (bf16_t*)(W + 0);                     // 4*1280*256*2 = 2,621,440
  float*  beff = (float*)(W + 2621440);                // 20,480
  bf16_t* wot  = (bf16_t*)(W + 2641920);               // 524,288
  bf16_t* w1t  = (bf16_t*)(W + 3166208);               // 2,097,152
  bf16_t* w2t  = (bf16_t*)(W + 5263360);               // 2,097,152
  bf16_t* c2t  = (bf16_t*)(W + 7360512);               // 327,680
  bf16_t* d1t  = (bf16_t*)(W + 7688192);               // 327,680
  float*  pe   = (float*)(W + 8015872);                // 4,194,304
  float*  sc1  = (float*)(W + 12210176);
  float*  sb1  = (float*)(W + 12211200);
  float*  sc2  = (float*)(W + 12212224);
  float*  sb2  = (float*)(W + 12213248);
  float*  sc3  = (float*)(W + 12214272);
  float*  sb3  = (float*)(W + 12215296);
  const size_t FIXED_END = 16777216;

  // ---- pick batch chunk Bc so workspace fits ws_size ----
  const size_t PER_B = 17385472;
  int Bc = 32;
  while (Bc > 1 && FIXED_END + (size_t)Bc * PER_B > ws_size) Bc >>= 1;

  char* P = W + FIXED_END;
  float*  h     = (float*)P;
  bf16_t* xa    = (bf16_t*)(P + (size_t)Bc * 4194304);
  bf16_t* ao    = xa;  // xa dead after fused qkv gemm; ao dead before ln2
  char*   big   = P + (size_t)Bc * (4194304 + 2097152);
  bf16_t* qpkpv = (bf16_t*)big;
  bf16_t* f1    = (bf16_t*)big;                               // after qpkpv dead
  bf16_t* h1p   = (bf16_t*)big;                               // pre-loop
  bf16_t* hpad  = (bf16_t*)big;                               // post-loop
  bf16_t* hdp   = (bf16_t*)(big + (size_t)Bc * 4100 * 256 * 2);
  float*  pkv   = (float*)(big + (size_t)Bc * 10485760);
  float*  pks   = (float*)((char*)pkv + (size_t)Bc * 524288);

  // ---- weight prep (once) ----
  prep_weff<<<5120, 256, 0, stream>>>(wq, wk, wv, bq, bk, bv, rf, weff, beff);
  prep_cast_t<<<1024, 256, 0, stream>>>(wo, wot, 256, 256);
  prep_cast_t<<<4096, 256, 0, stream>>>(ff_w1, w1t, 256, 1024);
  prep_cast_t<<<4096, 256, 0, stream>>>(ff_w2, w2t, 1024, 256);
  prep_conv_t<<<640, 256, 0, stream>>>(emb_w2, c2t, 128, 5);
  prep_conv_t<<<640, 256, 0, stream>>>(dec_w1, d1t, 256, 5);
  prep_bn<<<1, 256, 0, stream>>>(bn1_g, bn1_b, emb_b1, bn2_g, bn2_b, emb_b2,
                                 bn3_g, bn3_b, dec_b1, sc1, sb1, sc2, sb2, sc3, sb3);
  pe_fill<<<4096, 256, 0, stream>>>(pe);

  for (int c0 = 0; c0 < 32; c0 += Bc) {
    const float* xc = x + (size_t)c0 * 4096;

    // ---- embedding ----
    hipMemsetAsync(h1p, 0, (size_t)Bc * 4100 * 128 * 2, stream);
    conv1_kernel<<<Bc * 64, 256, 0, stream>>>(xc, emb_w1, sc1, sb1, h1p);
    gemm_bf16<3, 640, 64><<<dim3(Bc * 32, 4), 256, 0, stream>>>(
        h1p, c2t, h, sb2, sc2, nullptr, pe,
        128, 4100L * 128, 4096, 256, 256, 4096L * 256, 0);

    // ---- transformer layers ----
    for (int l = 0; l < 4; l++) {
      ln_kernel<<<Bc * 1024, 256, 0, stream>>>(h, ln1_g + l * 256, ln1_b + l * 256, xa);
      gemm_bf16<5, 256, 128><<<dim3(Bc * 32, 10), 256, 0, stream>>>(
          xa, weff + (long)l * 327680, qpkpv, beff + l * 1280, nullptr, nullptr, nullptr,
          256, 4096L * 256, 4096, 1280, 1280, 4096L * 1280, 0);
      kv_partial<<<Bc * 64, 256, 0, stream>>>(qpkpv, pkv, pks);
      combine_mfma<<<Bc * 256, 256, 0, stream>>>(qpkpv, pkv, pks, ao);
      gemm_bf16<1, 256, 64><<<dim3(Bc * 32, 4), 256, 0, stream>>>(
          ao, wot + (long)l * 65536, h, bo + l * 256, nullptr, h, nullptr,
          256, 4096L * 256, 4096, 256, 256, 4096L * 256, 0);
      ln_kernel<<<Bc * 1024, 256, 0, stream>>>(h, ln2_g + l * 256, ln2_b + l * 256, xa);
      gemm_bf16<2, 256, 128><<<dim3(Bc * 32, 8), 256, 0, stream>>>(
          xa, w1t + (long)l * 262144, f1, ff_b1 + l * 1024, nullptr, nullptr, nullptr,
          256, 4096L * 256, 4096, 1024, 1024, 4096L * 1024, 0);
      gemm_bf16<1, 1024, 64><<<dim3(Bc * 32, 4), 256, 0, stream>>>(
          f1, w2t + (long)l * 262144, h, ff_b2 + l * 256, nullptr, h, nullptr,
          1024, 4096L * 1024, 4096, 256, 256, 4096L * 256, 0);
    }

    // ---- decoder ----
    hipMemsetAsync(hpad, 0, (size_t)Bc * 4100 * 256 * 2, stream);
    cast_pad<<<Bc * 512, 256, 0, stream>>>(h, hpad);
    hipMemsetAsync(hdp, 0, (size_t)Bc * 4098 * 128 * 2, stream);
    gemm_bf16<4, 1280, 64><<<dim3(Bc * 32, 2), 256, 0, stream>>>(
        hpad, d1t, hdp, sb3, sc3, nullptr, nullptr,
        256, 4100L * 256, 4096, 128, 128, 4098L * 128, 1);
    conv_final<<<Bc * 16, 256, 0, stream>>>(hdp, dec_w2, dec_b2,
                                            (float*)d_out + (size_t)c0 * 4096);
  }
}

// Round 11
// 4285.308 us; speedup vs baseline: 1.4223x; 1.4223x over previous
//
#include <hip/hip_runtime.h>
#include <hip/hip_bf16.h>
#include <math.h>

// ============================================================================
// PPGPeakPerformer forward on MI355X (gfx950)
// B=32 S=4096 D=256 DH=128 H=8 HD=32 F=64 L=4
// GEMM: 128xBN tile (BN=128 wide-N, BN=64 narrow-N for grid parallelism),
// BK=32, double-buffered LDS, depth-1 prefetch, tight vmcnt(0) + raw
// s_barrier. launch_bounds(256,4) EVERYWHERE: r10 showed (256,5) forces the
// allocator past the 64-VGPR occupancy granule -> acc spills to scratch
// (VGPR 48, 284MB scratch writes, 2x regression). 4 waves/SIMD is the
// occupancy ceiling for this register footprint.
// Swizzle slot^((row>>1)&3) both-sides. Fast rational erf. Fused q/k RF
// projection GEMM. kv_reduce folded into combine_mfma.
// ============================================================================

typedef __bf16 bf16_t;
typedef __bf16 bf16x8 __attribute__((ext_vector_type(8)));
typedef __bf16 bf16x4 __attribute__((ext_vector_type(4)));
typedef float  f32x4  __attribute__((ext_vector_type(4)));

#define DEV __device__ __forceinline__

DEV float erf_fast(float x) {
  float ax = fabsf(x);
  float t = __builtin_amdgcn_rcpf(1.f + 0.3275911f * ax);
  float p = t * (0.254829592f + t * (-0.284496736f + t * (1.421413741f +
            t * (-1.453152027f + t * 1.061405429f))));
  float r = 1.f - p * __expf(-ax * ax);
  return copysignf(r, x);
}
DEV float geluf(float v) { return 0.5f * v * (1.f + erf_fast(v * 0.70710678118654752440f)); }
DEV float softplusf(float v) {
  float e = __expf(-fabsf(v));
  return fmaxf(v, 0.f) + __logf(1.f + e);
}

// Direct global->LDS 16B staging. LDS dest is wave-uniform base + lane*16.
DEV void gload16(const bf16_t* g, bf16_t* l) {
  __builtin_amdgcn_global_load_lds(
      (const __attribute__((address_space(1))) void*)g,
      (__attribute__((address_space(3))) void*)l, 16, 0, 0);
}

// ---------------------------------------------------------------------------
// GEMM: C[m,n] = sum_k A[m,k]*Bt[n,k].  A bf16 (batched rows), Bt bf16 [N][K].
// EPI: 1 = +bias +resid -> fp32; 2 = gelu(+bias) -> bf16;
//      3 = gelu(scale*x+bias)+pe -> fp32; 4 = gelu(scale*x+bias) -> bf16;
//      5 = col<1024 ? softplus(+bias) : (+bias) -> bf16
// Tile 128 x BN.  BN=128: 4 waves 2x2, each 64x64, acc[4][4], all waves
// stage 32 A-rows + 32 B-rows.  BN=64: 4 waves 4x1, each 32x64, acc[2][4],
// all waves stage 32 A-rows, waves 0/1 stage 32 B-rows each.
// BK=32 (64B rows = 4x16B slots). Swizzle: LDS slot = src_slot ^ ((row>>1)&3)
// via pre-swizzled global source; LDS dest linear (gload_lds rule).
// Double buffer, depth-1: wait S(t) [vmcnt(0), tight], barrier, issue S(t+1),
// compute t. Residual stall hidden by 4 blocks/CU of TLP.
// ---------------------------------------------------------------------------
template <int EPI, int K, int BN>
__global__ __launch_bounds__(256, 4)
void gemm_bf16(const bf16_t* __restrict__ A, const bf16_t* __restrict__ Bt,
               void* Cout, const float* __restrict__ bias,
               const float* __restrict__ scale, const float* resid,
               const float* __restrict__ pe,
               int lda, long a_bstride, int rpb,
               int N, int ldc, long c_bstride, int c_roff)
{
  constexpr int MI = (BN == 128) ? 4 : 2;   // row-fragments per wave
  __shared__ bf16_t As[2][128 * 32];
  __shared__ bf16_t Bs[2][BN * 32];
  const int t = threadIdx.x;
  const int lane = t & 63;
  const int w = t >> 6;
  const int wrow = (BN == 128) ? (w >> 1) * 64 : w * 32;
  const int wcol = (BN == 128) ? (w & 1) * 64 : 0;
  const long m0 = (long)blockIdx.x * 128;
  const int n0 = blockIdx.y * BN;
  const int b = (int)(m0 / rpb);
  const int s_base = (int)(m0 % rpb);
  const bf16_t* Ab = A + (long)b * a_bstride + (long)s_base * lda;
  const bf16_t* Bb = Bt + (long)n0 * K;

  // staging source (pre-swizzled): lane covers row (lane>>2) of a 16-row
  // block, 16B slot ((lane&3) ^ ((row>>1)&3)).
  const int srow = lane >> 2;
  const int sslot = (lane & 3) ^ ((srow >> 1) & 3);
  const bf16_t* aS = Ab + (long)(w * 32 + srow) * lda + sslot * 8;
  const bf16_t* bS = Bb + (long)(w * 32 + srow) * K + sslot * 8;
  const int dsto = w * 1024;  // 32 rows x 32 elems per wave

#define STAGE(bufidx, kk)                                   \
  {                                                         \
    bf16_t* a_ = &As[bufidx][dsto];                         \
    gload16(aS + (kk), a_);                                 \
    gload16(aS + (kk) + 16 * (long)lda, a_ + 512);          \
    if (BN == 128 || w < 2) {                               \
      bf16_t* b_ = &Bs[bufidx][dsto];                       \
      gload16(bS + (kk), b_);                               \
      gload16(bS + (kk) + 16 * (long)K, b_ + 512);          \
    }                                                       \
  }

  f32x4 acc[MI][4];
#pragma unroll
  for (int i = 0; i < MI; i++)
#pragma unroll
    for (int j = 0; j < 4; j++) acc[i][j] = (f32x4){0.f, 0.f, 0.f, 0.f};

  constexpr int NT = K >> 5;
  STAGE(0, 0);

#pragma unroll
  for (int tt = 0; tt < NT; ++tt) {
    asm volatile("s_waitcnt vmcnt(0)" ::: "memory");
    __builtin_amdgcn_s_barrier();
    __builtin_amdgcn_sched_barrier(0);
    if (tt + 1 < NT) STAGE((tt + 1) & 1, (tt + 1) * 32);
    const int cb = tt & 1;
    const bf16_t* Acur = As[cb];
    const bf16_t* Bcur = Bs[cb];
    const int kb = (lane >> 4) * 16;
    bf16x8 af[MI], bfr[4];
#pragma unroll
    for (int i = 0; i < MI; i++) {
      int rA = wrow + i * 16 + (lane & 15);
      af[i] = *(const bf16x8*)((const char*)Acur + rA * 64 + (kb ^ (((rA >> 1) & 3) << 4)));
    }
#pragma unroll
    for (int j = 0; j < 4; j++) {
      int rB = wcol + j * 16 + (lane & 15);
      bfr[j] = *(const bf16x8*)((const char*)Bcur + rB * 64 + (kb ^ (((rB >> 1) & 3) << 4)));
    }
    __builtin_amdgcn_s_setprio(1);
#pragma unroll
    for (int mi = 0; mi < MI; mi++)
#pragma unroll
      for (int ni = 0; ni < 4; ni++)
        acc[mi][ni] = __builtin_amdgcn_mfma_f32_16x16x32_bf16(af[mi], bfr[ni], acc[mi][ni], 0, 0, 0);
    __builtin_amdgcn_s_setprio(0);
  }
#undef STAGE

  const int colbase = n0 + wcol + (lane & 15);
  float bias_r[4], scale_r[4];
#pragma unroll
  for (int ni = 0; ni < 4; ni++) {
    int col = colbase + ni * 16;
    bias_r[ni] = bias[col];
    scale_r[ni] = (EPI == 3 || EPI == 4) ? scale[col] : 0.f;
  }
#pragma unroll
  for (int mi = 0; mi < MI; mi++) {
#pragma unroll
    for (int j = 0; j < 4; j++) {
      int row = wrow + mi * 16 + ((lane >> 4) << 2) + j;
      long s = s_base + row;
      long cro = (long)b * c_bstride + (s + c_roff) * (long)ldc;
#pragma unroll
      for (int ni = 0; ni < 4; ni++) {
        int col = colbase + ni * 16;
        float v = acc[mi][ni][j];
        if constexpr (EPI == 1) {
          v += bias_r[ni] + resid[cro + col];
          ((float*)Cout)[cro + col] = v;
        } else if constexpr (EPI == 2) {
          v = geluf(v + bias_r[ni]);
          ((bf16_t*)Cout)[cro + col] = (bf16_t)v;
        } else if constexpr (EPI == 3) {
          v = geluf(v * scale_r[ni] + bias_r[ni]) + pe[s * 256 + col];
          ((float*)Cout)[cro + col] = v;
        } else if constexpr (EPI == 4) {
          v = geluf(v * scale_r[ni] + bias_r[ni]);
          ((bf16_t*)Cout)[cro + col] = (bf16_t)v;
        } else {  // 5
          v += bias_r[ni];
          if (col < 1024) v = softplusf(v);
          ((bf16_t*)Cout)[cro + col] = (bf16_t)v;
        }
      }
    }
  }
}

// ---------------------------------------------------------------------------
// LayerNorm over D=256, fp32 in -> bf16 out. 4 rows/block (1 wave per row).
// ---------------------------------------------------------------------------
__global__ __launch_bounds__(256)
void ln_kernel(const float* __restrict__ h, const float* __restrict__ g,
               const float* __restrict__ bta, bf16_t* __restrict__ out)
{
  int t = threadIdx.x;
  int lane = t & 63;
  long row = (long)blockIdx.x * 4 + (t >> 6);
  const float* hp = h + row * 256 + lane * 4;
  float4 v = *(const float4*)hp;
  float s = v.x + v.y + v.z + v.w;
  float q = v.x * v.x + v.y * v.y + v.z * v.z + v.w * v.w;
#pragma unroll
  for (int m = 32; m >= 1; m >>= 1) {
    s += __shfl_xor(s, m);
    q += __shfl_xor(q, m);
  }
  float mean = s * 0.00390625f;
  float var = q * 0.00390625f - mean * mean;
  float rstd = rsqrtf(var + 1e-5f);
  int c = lane * 4;
  float4 gv = *(const float4*)(g + c);
  float4 bv = *(const float4*)(bta + c);
  bf16x4 o;
  o[0] = (bf16_t)((v.x - mean) * rstd * gv.x + bv.x);
  o[1] = (bf16_t)((v.y - mean) * rstd * gv.y + bv.y);
  o[2] = (bf16_t)((v.z - mean) * rstd * gv.z + bv.z);
  o[3] = (bf16_t)((v.w - mean) * rstd * gv.w + bv.w);
  *(bf16x4*)(out + row * 256 + c) = o;
}

// ---------------------------------------------------------------------------
// Embedding conv1: x[Bc,S] -> gelu(bn(conv1d k=7 pad=3)) -> h1p[Bc,S+4,128]
// ---------------------------------------------------------------------------
__global__ __launch_bounds__(256)
void conv1_kernel(const float* __restrict__ x, const float* __restrict__ w1,
                  const float* __restrict__ sc, const float* __restrict__ sb,
                  bf16_t* __restrict__ h1p)
{
  int b = blockIdx.x >> 6;
  int s0 = (blockIdx.x & 63) << 6;
  __shared__ float xs[70];
  __shared__ float ws[896];
  int t = threadIdx.x;
  if (t < 70) {
    int s = s0 + t - 3;
    xs[t] = (s >= 0 && s < 4096) ? x[(long)b * 4096 + s] : 0.f;
  }
  for (int i = t; i < 896; i += 256) ws[i] = w1[i];
  __syncthreads();
  int c = t & 127, so = t >> 7;
  float wr[7];
#pragma unroll
  for (int k = 0; k < 7; k++) wr[k] = ws[c * 7 + k];
  float scl = sc[c], sbv = sb[c];
  for (int p = 0; p < 32; p++) {
    int sl = p * 2 + so;
    float a = 0.f;
#pragma unroll
    for (int k = 0; k < 7; k++) a += xs[sl + k] * wr[k];
    a = geluf(a * scl + sbv);
    h1p[((long)b * 4100 + s0 + sl + 2) * 128 + c] = (bf16_t)a;
  }
}

// ---------------------------------------------------------------------------
// kv partial: per (b,h,chunk of 512 s): acc[f][d] += kp[s,f]*v[s,d]; +ksum.
// ---------------------------------------------------------------------------
__global__ __launch_bounds__(256)
void kv_partial(const bf16_t* __restrict__ qpkpv,
                float* __restrict__ pkv, float* __restrict__ pks)
{
  int bh = blockIdx.x >> 3, ch = blockIdx.x & 7;
  int b = bh >> 3, hh = bh & 7;
  int s0 = ch * 512;
  __shared__ float kps[32 * 64];
  __shared__ float vs[32 * 32];
  int t = threadIdx.x;
  int f = t & 63, dg = t >> 6;
  float acc[8] = {0.f, 0.f, 0.f, 0.f, 0.f, 0.f, 0.f, 0.f};
  float ks = 0.f;
  const int row = t >> 3, slot8 = (t & 7) * 8, slot4 = (t & 7) * 4;
  for (int sb = 0; sb < 512; sb += 32) {
    __syncthreads();
    {
      const bf16_t* rowp = qpkpv + ((long)b * 4096 + s0 + sb + row) * 1280;
      bf16x8 k8 = *(const bf16x8*)(rowp + 512 + hh * 64 + slot8);
#pragma unroll
      for (int j = 0; j < 8; j++) kps[row * 64 + slot8 + j] = (float)k8[j];
      bf16x4 v4 = *(const bf16x4*)(rowp + 1024 + hh * 32 + slot4);
#pragma unroll
      for (int j = 0; j < 4; j++) vs[row * 32 + slot4 + j] = (float)v4[j];
    }
    __syncthreads();
#pragma unroll 4
    for (int s = 0; s < 32; s++) {
      float kval = kps[s * 64 + f];
      float4 v0 = *(const float4*)&vs[s * 32 + dg * 8];
      float4 v1 = *(const float4*)&vs[s * 32 + dg * 8 + 4];
      acc[0] += kval * v0.x; acc[1] += kval * v0.y;
      acc[2] += kval * v0.z; acc[3] += kval * v0.w;
      acc[4] += kval * v1.x; acc[5] += kval * v1.y;
      acc[6] += kval * v1.z; acc[7] += kval * v1.w;
      ks += kval;
    }
  }
  long o = (long)blockIdx.x * 2048 + f * 32 + dg * 8;
#pragma unroll
  for (int j = 0; j < 8; j++) pkv[o + j] = acc[j];
  if (dg == 0) pks[blockIdx.x * 64 + f] = ks;
}

// ---------------------------------------------------------------------------
// combine: ao[s, h*32+d] = (qp[s,:] @ kv[:,d]) / (qp[s,:]@ksum + 1e-8)
// kv/ksum reduced from 8 chunk-partials inline (deterministic order).
// ---------------------------------------------------------------------------
__global__ __launch_bounds__(256, 2)
void combine_mfma(const bf16_t* __restrict__ qpkpv, const float* __restrict__ pkv,
                  const float* __restrict__ pks, bf16_t* __restrict__ ao)
{
  int bh = blockIdx.x >> 5;
  int s0 = (blockIdx.x & 31) << 7;
  int b = bh >> 3, hh = bh & 7;
  __shared__ bf16_t A_s[128 * 72];
  __shared__ bf16_t B_s[48 * 72];
  int t = threadIdx.x;
  for (int g = t; g < 1024; g += 256) {
    int row = g >> 3, slot = (g & 7) * 8;
    *(bf16x8*)&A_s[row * 72 + slot] =
        *(const bf16x8*)(qpkpv + ((long)b * 4096 + s0 + row) * 1280 + hh * 64 + slot);
  }
  for (int i = t; i < 2048; i += 256) {
    float s = 0.f;
#pragma unroll
    for (int ch = 0; ch < 8; ch++) s += pkv[((long)(bh * 8 + ch)) * 2048 + i];
    int f = i >> 5, d = i & 31;
    B_s[d * 72 + f] = (bf16_t)s;
  }
  if (t < 64) {
    float s = 0.f;
#pragma unroll
    for (int ch = 0; ch < 8; ch++) s += pks[(bh * 8 + ch) * 64 + t];
    B_s[32 * 72 + t] = (bf16_t)s;
  }
  for (int i = t; i < 960; i += 256) {
    int n = 33 + (i >> 6), f = i & 63;
    B_s[n * 72 + f] = (bf16_t)0.f;
  }
  __syncthreads();
  int lane = t & 63, w = t >> 6;
  f32x4 acc[2][3];
#pragma unroll
  for (int i = 0; i < 2; i++)
#pragma unroll
    for (int j = 0; j < 3; j++) acc[i][j] = (f32x4){0.f, 0.f, 0.f, 0.f};
#pragma unroll
  for (int kt = 0; kt < 2; kt++) {
    int ko = kt * 32 + (lane >> 4) * 8;
    bf16x8 a[2], bb[3];
#pragma unroll
    for (int i = 0; i < 2; i++)
      a[i] = *(const bf16x8*)&A_s[(w * 32 + i * 16 + (lane & 15)) * 72 + ko];
#pragma unroll
    for (int i = 0; i < 3; i++)
      bb[i] = *(const bf16x8*)&B_s[(i * 16 + (lane & 15)) * 72 + ko];
#pragma unroll
    for (int mi = 0; mi < 2; mi++)
#pragma unroll
      for (int ni = 0; ni < 3; ni++)
        acc[mi][ni] = __builtin_amdgcn_mfma_f32_16x16x32_bf16(a[mi], bb[ni], acc[mi][ni], 0, 0, 0);
  }
  long sbase = (long)b * 4096 + s0;
#pragma unroll
  for (int mi = 0; mi < 2; mi++)
#pragma unroll
    for (int j = 0; j < 4; j++) {
      int r = w * 32 + mi * 16 + ((lane >> 4) << 2) + j;
      float den = __shfl(acc[mi][2][j], (lane & 48)) + 1e-8f;
#pragma unroll
      for (int ni = 0; ni < 2; ni++) {
        int d = ni * 16 + (lane & 15);
        ao[(sbase + r) * 256 + hh * 32 + d] = (bf16_t)(acc[mi][ni][j] / den);
      }
    }
}

// ---------------------------------------------------------------------------
// h fp32 -> h_padded bf16 [Bc, S+4, 256] (rows offset +2)
// ---------------------------------------------------------------------------
__global__ __launch_bounds__(256)
void cast_pad(const float* __restrict__ h, bf16_t* __restrict__ hp)
{
  long i8 = ((long)blockIdx.x * 256 + threadIdx.x) * 8;
  long r = i8 >> 8;
  int c = (int)(i8 & 255);
  int b = (int)(r >> 12), s = (int)(r & 4095);
  float4 v0 = *(const float4*)(h + i8);
  float4 v1 = *(const float4*)(h + i8 + 4);
  bf16x8 o;
  o[0] = (bf16_t)v0.x; o[1] = (bf16_t)v0.y; o[2] = (bf16_t)v0.z; o[3] = (bf16_t)v0.w;
  o[4] = (bf16_t)v1.x; o[5] = (bf16_t)v1.y; o[6] = (bf16_t)v1.z; o[7] = (bf16_t)v1.w;
  *(bf16x8*)(hp + ((long)b * 4100 + s + 2) * 256 + c) = o;
}

// ---------------------------------------------------------------------------
// Final conv (DH->1, k=3, pad=1) + sigmoid -> out [Bc,S] fp32
// ---------------------------------------------------------------------------
__global__ __launch_bounds__(256)
void conv_final(const bf16_t* __restrict__ hdp, const float* __restrict__ w2,
                const float* __restrict__ b2, float* __restrict__ out)
{
  __shared__ float ws[384];
  int t = threadIdx.x;
  for (int i = t; i < 384; i += 256) ws[i] = w2[i];  // [c][k]
  __syncthreads();
  long idx = (long)blockIdx.x * 256 + t;
  int b = (int)(idx >> 12);
  const bf16_t* base = hdp + ((long)b * 4098 + (idx & 4095)) * 128;
  float a = b2[0];
#pragma unroll
  for (int k = 0; k < 3; k++) {
#pragma unroll
    for (int c8 = 0; c8 < 16; c8++) {
      bf16x8 v = *(const bf16x8*)(base + k * 128 + c8 * 8);
#pragma unroll
      for (int j = 0; j < 8; j++) a += (float)v[j] * ws[(c8 * 8 + j) * 3 + k];
    }
  }
  out[idx] = 1.f / (1.f + __expf(-a));
}

// ---------------------------------------------------------------------------
// Prep kernels (once per launch)
// ---------------------------------------------------------------------------
__global__ __launch_bounds__(256)
void prep_weff(const float* __restrict__ wq, const float* __restrict__ wk,
               const float* __restrict__ wv, const float* __restrict__ bq,
               const float* __restrict__ bk, const float* __restrict__ bv,
               const float* __restrict__ rf, bf16_t* __restrict__ weff,
               float* __restrict__ beff)
{
  long idx = (long)blockIdx.x * 256 + threadIdx.x;  // 4*1280*256
  int d = (int)(idx & 255);
  long r = idx >> 8;
  int n = (int)(r % 1280);
  int l = (int)(r / 1280);
  float val;
  if (n < 1024) {
    int qk = n >> 9;
    int h = (n >> 6) & 7;
    int f = n & 63;
    const float* w = qk ? wk : wq;
    const float* rfh = rf + ((long)(l * 8 + h) * 32) * 64 + f;
    const float* wrow = w + ((long)l * 256 + d) * 256 + h * 32;
    float s = 0.f;
#pragma unroll
    for (int hd = 0; hd < 32; hd++) s += wrow[hd] * rfh[hd * 64];
    val = s;
  } else {
    val = wv[((long)l * 256 + d) * 256 + (n - 1024)];
  }
  weff[idx] = (bf16_t)val;
  if (idx < 4 * 1280) {
    int nn = (int)(idx % 1280);
    int ll = (int)(idx / 1280);
    float bvv;
    if (nn < 1024) {
      int qk = nn >> 9;
      int h = (nn >> 6) & 7;
      int f = nn & 63;
      const float* bsrc = qk ? bk : bq;
      float s = 0.f;
      for (int hd = 0; hd < 32; hd++)
        s += bsrc[ll * 256 + h * 32 + hd] * rf[((long)(ll * 8 + h) * 32 + hd) * 64 + f];
      bvv = s;
    } else {
      bvv = bv[ll * 256 + (nn - 1024)];
    }
    beff[idx] = bvv;
  }
}

__global__ __launch_bounds__(256)
void prep_cast_t(const float* __restrict__ src, bf16_t* __restrict__ dst, int K, int N)
{
  long idx = (long)blockIdx.x * 256 + threadIdx.x;  // nmats*N*K
  int k = (int)(idx % K);
  long r = idx / K;
  int n = (int)(r % N);
  int l = (int)(r / N);
  dst[idx] = (bf16_t)src[((long)l * K + k) * N + n];
}

__global__ __launch_bounds__(256)
void prep_conv_t(const float* __restrict__ w, bf16_t* __restrict__ dst, int C, int KW)
{
  long idx = (long)blockIdx.x * 256 + threadIdx.x;  // O*C*KW
  int ckw = C * KW;
  int kk = (int)(idx % ckw);
  int o = (int)(idx / ckw);
  int kw = kk / C, c = kk % C;
  dst[idx] = (bf16_t)w[((long)o * C + c) * KW + kw];
}

__global__ __launch_bounds__(256)
void prep_bn(const float* g1, const float* b1, const float* cb1,
             const float* g2, const float* b2, const float* cb2,
             const float* g3, const float* b3, const float* cb3,
             float* sc1, float* sb1, float* sc2, float* sb2,
             float* sc3, float* sb3)
{
  int t = threadIdx.x;
  const float r = rsqrtf(1.f + 1e-5f);
  if (t < 128) { float s = g1[t] * r; sc1[t] = s; sb1[t] = cb1[t] * s + b1[t]; }
  if (t < 256) { float s = g2[t] * r; sc2[t] = s; sb2[t] = cb2[t] * s + b2[t]; }
  if (t < 128) { float s = g3[t] * r; sc3[t] = s; sb3[t] = cb3[t] * s + b3[t]; }
}

__global__ __launch_bounds__(256)
void pe_fill(float* __restrict__ pe)
{
  long idx = (long)blockIdx.x * 256 + threadIdx.x;  // 4096*256
  int dcol = (int)(idx & 255);
  int s = (int)(idx >> 8);
  int i2 = dcol >> 1;
  float freq = expf(-9.210340371976184f * (float)(2 * i2) / 256.f);
  float a = (float)s * freq;
  pe[idx] = (dcol & 1) ? cosf(a) : sinf(a);
}

// ---------------------------------------------------------------------------
extern "C" void kernel_launch(void* const* d_in, const int* in_sizes, int n_in,
                              void* d_out, int out_size, void* d_ws, size_t ws_size,
                              hipStream_t stream)
{
  (void)in_sizes; (void)n_in; (void)out_size;
  const float* x      = (const float*)d_in[0];
  const float* emb_w1 = (const float*)d_in[1];
  const float* emb_b1 = (const float*)d_in[2];
  const float* bn1_g  = (const float*)d_in[3];
  const float* bn1_b  = (const float*)d_in[4];
  const float* emb_w2 = (const float*)d_in[5];
  const float* emb_b2 = (const float*)d_in[6];
  const float* bn2_g  = (const float*)d_in[7];
  const float* bn2_b  = (const float*)d_in[8];
  const float* wq     = (const float*)d_in[9];
  const float* bq     = (const float*)d_in[10];
  const float* wk     = (const float*)d_in[11];
  const float* bk     = (const float*)d_in[12];
  const float* wv     = (const float*)d_in[13];
  const float* bv     = (const float*)d_in[14];
  const float* wo     = (const float*)d_in[15];
  const float* bo     = (const float*)d_in[16];
  const float* rf     = (const float*)d_in[17];
  const float* ln1_g  = (const float*)d_in[18];
  const float* ln1_b  = (const float*)d_in[19];
  const float* ln2_g  = (const float*)d_in[20];
  const float* ln2_b  = (const float*)d_in[21];
  const float* ff_w1  = (const float*)d_in[22];
  const float* ff_b1  = (const float*)d_in[23];
  const float* ff_w2  = (const float*)d_in[24];
  const float* ff_b2  = (const float*)d_in[25];
  const float* dec_w1 = (const float*)d_in[26];
  const float* dec_b1 = (const float*)d_in[27];
  const float* bn3_g  = (const float*)d_in[28];
  const float* bn3_b  = (const float*)d_in[29];
  const float* dec_w2 = (const float*)d_in[30];
  const float* dec_b2 = (const float*)d_in[31];

  char* W = (char*)d_ws;

  // ---- fixed region (weights, ~12.2 MB; reserve 16 MB) ----
  bf16_t* weff = (bf16_t*)(W + 0);                     // 4*1280*256*2 = 2,621,440
  float*  beff = (float*)(W + 2621440);                // 20,480
  bf16_t* wot  = (bf16_t*)(W + 2641920);               // 524,288
  bf16_t* w1t  = (bf16_t*)(W + 3166208);               // 2,097,152
  bf16_t* w2t  = (bf16_t*)(W + 5263360);               // 2,097,152
  bf16_t* c2t  = (bf16_t*)(W + 7360512);               // 327,680
  bf16_t* d1t  = (bf16_t*)(W + 7688192);               // 327,680
  float*  pe   = (float*)(W + 8015872);                // 4,194,304
  float*  sc1  = (float*)(W + 12210176);
  float*  sb1  = (float*)(W + 12211200);
  float*  sc2  = (float*)(W + 12212224);
  float*  sb2  = (float*)(W + 12213248);
  float*  sc3  = (float*)(W + 12214272);
  float*  sb3  = (float*)(W + 12215296);
  const size_t FIXED_END = 16777216;

  // ---- pick batch chunk Bc so workspace fits ws_size ----
  const size_t PER_B = 17385472;
  int Bc = 32;
  while (Bc > 1 && FIXED_END + (size_t)Bc * PER_B > ws_size) Bc >>= 1;

  char* P = W + FIXED_END;
  float*  h     = (float*)P;
  bf16_t* xa    = (bf16_t*)(P + (size_t)Bc * 4194304);
  bf16_t* ao    = xa;  // xa dead after fused qkv gemm; ao dead before ln2
  char*   big   = P + (size_t)Bc * (4194304 + 2097152);
  bf16_t* qpkpv = (bf16_t*)big;
  bf16_t* f1    = (bf16_t*)big;                               // after qpkpv dead
  bf16_t* h1p   = (bf16_t*)big;                               // pre-loop
  bf16_t* hpad  = (bf16_t*)big;                               // post-loop
  bf16_t* hdp   = (bf16_t*)(big + (size_t)Bc * 4100 * 256 * 2);
  float*  pkv   = (float*)(big + (size_t)Bc * 10485760);
  float*  pks   = (float*)((char*)pkv + (size_t)Bc * 524288);

  // ---- weight prep (once) ----
  prep_weff<<<5120, 256, 0, stream>>>(wq, wk, wv, bq, bk, bv, rf, weff, beff);
  prep_cast_t<<<1024, 256, 0, stream>>>(wo, wot, 256, 256);
  prep_cast_t<<<4096, 256, 0, stream>>>(ff_w1, w1t, 256, 1024);
  prep_cast_t<<<4096, 256, 0, stream>>>(ff_w2, w2t, 1024, 256);
  prep_conv_t<<<640, 256, 0, stream>>>(emb_w2, c2t, 128, 5);
  prep_conv_t<<<640, 256, 0, stream>>>(dec_w1, d1t, 256, 5);
  prep_bn<<<1, 256, 0, stream>>>(bn1_g, bn1_b, emb_b1, bn2_g, bn2_b, emb_b2,
                                 bn3_g, bn3_b, dec_b1, sc1, sb1, sc2, sb2, sc3, sb3);
  pe_fill<<<4096, 256, 0, stream>>>(pe);

  for (int c0 = 0; c0 < 32; c0 += Bc) {
    const float* xc = x + (size_t)c0 * 4096;

    // ---- embedding ----
    hipMemsetAsync(h1p, 0, (size_t)Bc * 4100 * 128 * 2, stream);
    conv1_kernel<<<Bc * 64, 256, 0, stream>>>(xc, emb_w1, sc1, sb1, h1p);
    gemm_bf16<3, 640, 64><<<dim3(Bc * 32, 4), 256, 0, stream>>>(
        h1p, c2t, h, sb2, sc2, nullptr, pe,
        128, 4100L * 128, 4096, 256, 256, 4096L * 256, 0);

    // ---- transformer layers ----
    for (int l = 0; l < 4; l++) {
      ln_kernel<<<Bc * 1024, 256, 0, stream>>>(h, ln1_g + l * 256, ln1_b + l * 256, xa);
      gemm_bf16<5, 256, 128><<<dim3(Bc * 32, 10), 256, 0, stream>>>(
          xa, weff + (long)l * 327680, qpkpv, beff + l * 1280, nullptr, nullptr, nullptr,
          256, 4096L * 256, 4096, 1280, 1280, 4096L * 1280, 0);
      kv_partial<<<Bc * 64, 256, 0, stream>>>(qpkpv, pkv, pks);
      combine_mfma<<<Bc * 256, 256, 0, stream>>>(qpkpv, pkv, pks, ao);
      gemm_bf16<1, 256, 64><<<dim3(Bc * 32, 4), 256, 0, stream>>>(
          ao, wot + (long)l * 65536, h, bo + l * 256, nullptr, h, nullptr,
          256, 4096L * 256, 4096, 256, 256, 4096L * 256, 0);
      ln_kernel<<<Bc * 1024, 256, 0, stream>>>(h, ln2_g + l * 256, ln2_b + l * 256, xa);
      gemm_bf16<2, 256, 128><<<dim3(Bc * 32, 8), 256, 0, stream>>>(
          xa, w1t + (long)l * 262144, f1, ff_b1 + l * 1024, nullptr, nullptr, nullptr,
          256, 4096L * 256, 4096, 1024, 1024, 4096L * 1024, 0);
      gemm_bf16<1, 1024, 64><<<dim3(Bc * 32, 4), 256, 0, stream>>>(
          f1, w2t + (long)l * 262144, h, ff_b2 + l * 256, nullptr, h, nullptr,
          1024, 4096L * 1024, 4096, 256, 256, 4096L * 256, 0);
    }

    // ---- decoder ----
    hipMemsetAsync(hpad, 0, (size_t)Bc * 4100 * 256 * 2, stream);
    cast_pad<<<Bc * 512, 256, 0, stream>>>(h, hpad);
    hipMemsetAsync(hdp, 0, (size_t)Bc * 4098 * 128 * 2, stream);
    gemm_bf16<4, 1280, 64><<<dim3(Bc * 32, 2), 256, 0, stream>>>(
        hpad, d1t, hdp, sb3, sc3, nullptr, nullptr,
        256, 4100L * 256, 4096, 128, 128, 4098L * 128, 1);
    conv_final<<<Bc * 16, 256, 0, stream>>>(hdp, dec_w2, dec_b2,
                                            (float*)d_out + (size_t)c0 * 4096);
  }
}

// Round 12
// 4242.501 us; speedup vs baseline: 1.4366x; 1.0101x over previous
//
#include <hip/hip_runtime.h>
#include <hip/hip_bf16.h>
#include <math.h>

// ============================================================================
// PPGPeakPerformer forward on MI355X (gfx950)
// B=32 S=4096 D=256 DH=128 H=8 HD=32 F=64 L=4
// GEMM: 128xBN tile (BN=128 wide-N, BN=64 narrow-N), BK=32, double-buffered
// LDS, depth-1 prefetch, tight vmcnt(0) + raw s_barrier, launch_bounds(256,4)
// (r10: 5+ waves/SIMD trips the VGPR-allocator cliff -> acc spills).
// NEW: 1D grid + bijective XCD swizzle (m204), n-tile fastest: each XCD gets
// a contiguous m-chunk x all n-tiles, so the N-tiles sharing an A-tile run on
// the SAME XCD -> A-loads become L2 hits (~200cy vs ~900cy HBM) -> directly
// shrinks the vmcnt(0) stall that dominates this latency-bound regime.
// Swizzle slot^((row>>1)&3) both-sides. Fast rational erf. Fused q/k RF
// projection GEMM. kv_reduce folded into combine_mfma.
// ============================================================================

typedef __bf16 bf16_t;
typedef __bf16 bf16x8 __attribute__((ext_vector_type(8)));
typedef __bf16 bf16x4 __attribute__((ext_vector_type(4)));
typedef float  f32x4  __attribute__((ext_vector_type(4)));

#define DEV __device__ __forceinline__

DEV float erf_fast(float x) {
  float ax = fabsf(x);
  float t = __builtin_amdgcn_rcpf(1.f + 0.3275911f * ax);
  float p = t * (0.254829592f + t * (-0.284496736f + t * (1.421413741f +
            t * (-1.453152027f + t * 1.061405429f))));
  float r = 1.f - p * __expf(-ax * ax);
  return copysignf(r, x);
}
DEV float geluf(float v) { return 0.5f * v * (1.f + erf_fast(v * 0.70710678118654752440f)); }
DEV float softplusf(float v) {
  float e = __expf(-fabsf(v));
  return fmaxf(v, 0.f) + __logf(1.f + e);
}

// Direct global->LDS 16B staging. LDS dest is wave-uniform base + lane*16.
DEV void gload16(const bf16_t* g, bf16_t* l) {
  __builtin_amdgcn_global_load_lds(
      (const __attribute__((address_space(1))) void*)g,
      (__attribute__((address_space(3))) void*)l, 16, 0, 0);
}

// ---------------------------------------------------------------------------
// GEMM: C[m,n] = sum_k A[m,k]*Bt[n,k].  A bf16 (batched rows), Bt bf16 [N][K].
// EPI: 1 = +bias +resid -> fp32; 2 = gelu(+bias) -> bf16;
//      3 = gelu(scale*x+bias)+pe -> fp32; 4 = gelu(scale*x+bias) -> bf16;
//      5 = col<1024 ? softplus(+bias) : (+bias) -> bf16
// Tile 128 x BN, NTL n-tiles. 1D grid, XCD-swizzled (m204 bijective remap,
// n fastest within each XCD's contiguous wgid chunk).
// BN=128: 4 waves 2x2, acc[4][4]. BN=64: 4 waves 4x1, acc[2][4]; waves 0/1
// stage B. BK=32; swizzle slot^((row>>1)&3) via pre-swizzled global source.
// Double buffer, depth-1: wait S(t) [vmcnt(0)], barrier, issue S(t+1).
// ---------------------------------------------------------------------------
template <int EPI, int K, int BN, int NTL>
__global__ __launch_bounds__(256, 4)
void gemm_bf16(const bf16_t* __restrict__ A, const bf16_t* __restrict__ Bt,
               void* Cout, const float* __restrict__ bias,
               const float* __restrict__ scale, const float* resid,
               const float* __restrict__ pe,
               int lda, long a_bstride, int rpb,
               int N, int ldc, long c_bstride, int c_roff)
{
  constexpr int MI = (BN == 128) ? 4 : 2;   // row-fragments per wave
  __shared__ bf16_t As[2][128 * 32];
  __shared__ bf16_t Bs[2][BN * 32];
  const int t = threadIdx.x;
  const int lane = t & 63;
  const int w = t >> 6;
  const int wrow = (BN == 128) ? (w >> 1) * 64 : w * 32;
  const int wcol = (BN == 128) ? (w & 1) * 64 : 0;

  // XCD-aware bijective remap (m204): HW assigns bid%8 -> XCD round-robin;
  // give XCD k the contiguous wgid chunk [start(k), start(k)+size(k)) so the
  // NTL n-tiles sharing an A-tile co-reside on one XCD's L2.
  const int nwg = gridDim.x;
  {
  }
  const int q_ = nwg >> 3, r_ = nwg & 7;
  const int xcd = blockIdx.x & 7, idx_ = blockIdx.x >> 3;
  const int wgid = (xcd < r_ ? xcd * (q_ + 1) : r_ * (q_ + 1) + (xcd - r_) * q_) + idx_;
  const long m0 = (long)(wgid / NTL) * 128;
  const int n0 = (wgid % NTL) * BN;

  const int b = (int)(m0 / rpb);
  const int s_base = (int)(m0 % rpb);
  const bf16_t* Ab = A + (long)b * a_bstride + (long)s_base * lda;
  const bf16_t* Bb = Bt + (long)n0 * K;

  // staging source (pre-swizzled): lane covers row (lane>>2) of a 16-row
  // block, 16B slot ((lane&3) ^ ((row>>1)&3)).
  const int srow = lane >> 2;
  const int sslot = (lane & 3) ^ ((srow >> 1) & 3);
  const bf16_t* aS = Ab + (long)(w * 32 + srow) * lda + sslot * 8;
  const bf16_t* bS = Bb + (long)(w * 32 + srow) * K + sslot * 8;
  const int dsto = w * 1024;  // 32 rows x 32 elems per wave

#define STAGE(bufidx, kk)                                   \
  {                                                         \
    bf16_t* a_ = &As[bufidx][dsto];                         \
    gload16(aS + (kk), a_);                                 \
    gload16(aS + (kk) + 16 * (long)lda, a_ + 512);          \
    if (BN == 128 || w < 2) {                               \
      bf16_t* b_ = &Bs[bufidx][dsto];                       \
      gload16(bS + (kk), b_);                               \
      gload16(bS + (kk) + 16 * (long)K, b_ + 512);          \
    }                                                       \
  }

  f32x4 acc[MI][4];
#pragma unroll
  for (int i = 0; i < MI; i++)
#pragma unroll
    for (int j = 0; j < 4; j++) acc[i][j] = (f32x4){0.f, 0.f, 0.f, 0.f};

  constexpr int NT = K >> 5;
  STAGE(0, 0);

#pragma unroll
  for (int tt = 0; tt < NT; ++tt) {
    asm volatile("s_waitcnt vmcnt(0)" ::: "memory");
    __builtin_amdgcn_s_barrier();
    __builtin_amdgcn_sched_barrier(0);
    if (tt + 1 < NT) STAGE((tt + 1) & 1, (tt + 1) * 32);
    const int cb = tt & 1;
    const bf16_t* Acur = As[cb];
    const bf16_t* Bcur = Bs[cb];
    const int kb = (lane >> 4) * 16;
    bf16x8 af[MI], bfr[4];
#pragma unroll
    for (int i = 0; i < MI; i++) {
      int rA = wrow + i * 16 + (lane & 15);
      af[i] = *(const bf16x8*)((const char*)Acur + rA * 64 + (kb ^ (((rA >> 1) & 3) << 4)));
    }
#pragma unroll
    for (int j = 0; j < 4; j++) {
      int rB = wcol + j * 16 + (lane & 15);
      bfr[j] = *(const bf16x8*)((const char*)Bcur + rB * 64 + (kb ^ (((rB >> 1) & 3) << 4)));
    }
    __builtin_amdgcn_s_setprio(1);
#pragma unroll
    for (int mi = 0; mi < MI; mi++)
#pragma unroll
      for (int ni = 0; ni < 4; ni++)
        acc[mi][ni] = __builtin_amdgcn_mfma_f32_16x16x32_bf16(af[mi], bfr[ni], acc[mi][ni], 0, 0, 0);
    __builtin_amdgcn_s_setprio(0);
  }
#undef STAGE

  const int colbase = n0 + wcol + (lane & 15);
  float bias_r[4], scale_r[4];
#pragma unroll
  for (int ni = 0; ni < 4; ni++) {
    int col = colbase + ni * 16;
    bias_r[ni] = bias[col];
    scale_r[ni] = (EPI == 3 || EPI == 4) ? scale[col] : 0.f;
  }
#pragma unroll
  for (int mi = 0; mi < MI; mi++) {
#pragma unroll
    for (int j = 0; j < 4; j++) {
      int row = wrow + mi * 16 + ((lane >> 4) << 2) + j;
      long s = s_base + row;
      long cro = (long)b * c_bstride + (s + c_roff) * (long)ldc;
#pragma unroll
      for (int ni = 0; ni < 4; ni++) {
        int col = colbase + ni * 16;
        float v = acc[mi][ni][j];
        if constexpr (EPI == 1) {
          v += bias_r[ni] + resid[cro + col];
          ((float*)Cout)[cro + col] = v;
        } else if constexpr (EPI == 2) {
          v = geluf(v + bias_r[ni]);
          ((bf16_t*)Cout)[cro + col] = (bf16_t)v;
        } else if constexpr (EPI == 3) {
          v = geluf(v * scale_r[ni] + bias_r[ni]) + pe[s * 256 + col];
          ((float*)Cout)[cro + col] = v;
        } else if constexpr (EPI == 4) {
          v = geluf(v * scale_r[ni] + bias_r[ni]);
          ((bf16_t*)Cout)[cro + col] = (bf16_t)v;
        } else {  // 5
          v += bias_r[ni];
          if (col < 1024) v = softplusf(v);
          ((bf16_t*)Cout)[cro + col] = (bf16_t)v;
        }
      }
    }
  }
}

// ---------------------------------------------------------------------------
// LayerNorm over D=256, fp32 in -> bf16 out. 4 rows/block (1 wave per row).
// ---------------------------------------------------------------------------
__global__ __launch_bounds__(256)
void ln_kernel(const float* __restrict__ h, const float* __restrict__ g,
               const float* __restrict__ bta, bf16_t* __restrict__ out)
{
  int t = threadIdx.x;
  int lane = t & 63;
  long row = (long)blockIdx.x * 4 + (t >> 6);
  const float* hp = h + row * 256 + lane * 4;
  float4 v = *(const float4*)hp;
  float s = v.x + v.y + v.z + v.w;
  float q = v.x * v.x + v.y * v.y + v.z * v.z + v.w * v.w;
#pragma unroll
  for (int m = 32; m >= 1; m >>= 1) {
    s += __shfl_xor(s, m);
    q += __shfl_xor(q, m);
  }
  float mean = s * 0.00390625f;
  float var = q * 0.00390625f - mean * mean;
  float rstd = rsqrtf(var + 1e-5f);
  int c = lane * 4;
  float4 gv = *(const float4*)(g + c);
  float4 bv = *(const float4*)(bta + c);
  bf16x4 o;
  o[0] = (bf16_t)((v.x - mean) * rstd * gv.x + bv.x);
  o[1] = (bf16_t)((v.y - mean) * rstd * gv.y + bv.y);
  o[2] = (bf16_t)((v.z - mean) * rstd * gv.z + bv.z);
  o[3] = (bf16_t)((v.w - mean) * rstd * gv.w + bv.w);
  *(bf16x4*)(out + row * 256 + c) = o;
}

// ---------------------------------------------------------------------------
// Embedding conv1: x[Bc,S] -> gelu(bn(conv1d k=7 pad=3)) -> h1p[Bc,S+4,128]
// ---------------------------------------------------------------------------
__global__ __launch_bounds__(256)
void conv1_kernel(const float* __restrict__ x, const float* __restrict__ w1,
                  const float* __restrict__ sc, const float* __restrict__ sb,
                  bf16_t* __restrict__ h1p)
{
  int b = blockIdx.x >> 6;
  int s0 = (blockIdx.x & 63) << 6;
  __shared__ float xs[70];
  __shared__ float ws[896];
  int t = threadIdx.x;
  if (t < 70) {
    int s = s0 + t - 3;
    xs[t] = (s >= 0 && s < 4096) ? x[(long)b * 4096 + s] : 0.f;
  }
  for (int i = t; i < 896; i += 256) ws[i] = w1[i];
  __syncthreads();
  int c = t & 127, so = t >> 7;
  float wr[7];
#pragma unroll
  for (int k = 0; k < 7; k++) wr[k] = ws[c * 7 + k];
  float scl = sc[c], sbv = sb[c];
  for (int p = 0; p < 32; p++) {
    int sl = p * 2 + so;
    float a = 0.f;
#pragma unroll
    for (int k = 0; k < 7; k++) a += xs[sl + k] * wr[k];
    a = geluf(a * scl + sbv);
    h1p[((long)b * 4100 + s0 + sl + 2) * 128 + c] = (bf16_t)a;
  }
}

// ---------------------------------------------------------------------------
// kv partial: per (b,h,chunk of 512 s): acc[f][d] += kp[s,f]*v[s,d]; +ksum.
// ---------------------------------------------------------------------------
__global__ __launch_bounds__(256)
void kv_partial(const bf16_t* __restrict__ qpkpv,
                float* __restrict__ pkv, float* __restrict__ pks)
{
  int bh = blockIdx.x >> 3, ch = blockIdx.x & 7;
  int b = bh >> 3, hh = bh & 7;
  int s0 = ch * 512;
  __shared__ float kps[32 * 64];
  __shared__ float vs[32 * 32];
  int t = threadIdx.x;
  int f = t & 63, dg = t >> 6;
  float acc[8] = {0.f, 0.f, 0.f, 0.f, 0.f, 0.f, 0.f, 0.f};
  float ks = 0.f;
  const int row = t >> 3, slot8 = (t & 7) * 8, slot4 = (t & 7) * 4;
  for (int sb = 0; sb < 512; sb += 32) {
    __syncthreads();
    {
      const bf16_t* rowp = qpkpv + ((long)b * 4096 + s0 + sb + row) * 1280;
      bf16x8 k8 = *(const bf16x8*)(rowp + 512 + hh * 64 + slot8);
#pragma unroll
      for (int j = 0; j < 8; j++) kps[row * 64 + slot8 + j] = (float)k8[j];
      bf16x4 v4 = *(const bf16x4*)(rowp + 1024 + hh * 32 + slot4);
#pragma unroll
      for (int j = 0; j < 4; j++) vs[row * 32 + slot4 + j] = (float)v4[j];
    }
    __syncthreads();
#pragma unroll 4
    for (int s = 0; s < 32; s++) {
      float kval = kps[s * 64 + f];
      float4 v0 = *(const float4*)&vs[s * 32 + dg * 8];
      float4 v1 = *(const float4*)&vs[s * 32 + dg * 8 + 4];
      acc[0] += kval * v0.x; acc[1] += kval * v0.y;
      acc[2] += kval * v0.z; acc[3] += kval * v0.w;
      acc[4] += kval * v1.x; acc[5] += kval * v1.y;
      acc[6] += kval * v1.z; acc[7] += kval * v1.w;
      ks += kval;
    }
  }
  long o = (long)blockIdx.x * 2048 + f * 32 + dg * 8;
#pragma unroll
  for (int j = 0; j < 8; j++) pkv[o + j] = acc[j];
  if (dg == 0) pks[blockIdx.x * 64 + f] = ks;
}

// ---------------------------------------------------------------------------
// combine: ao[s, h*32+d] = (qp[s,:] @ kv[:,d]) / (qp[s,:]@ksum + 1e-8)
// kv/ksum reduced from 8 chunk-partials inline (deterministic order).
// ---------------------------------------------------------------------------
__global__ __launch_bounds__(256, 2)
void combine_mfma(const bf16_t* __restrict__ qpkpv, const float* __restrict__ pkv,
                  const float* __restrict__ pks, bf16_t* __restrict__ ao)
{
  int bh = blockIdx.x >> 5;
  int s0 = (blockIdx.x & 31) << 7;
  int b = bh >> 3, hh = bh & 7;
  __shared__ bf16_t A_s[128 * 72];
  __shared__ bf16_t B_s[48 * 72];
  int t = threadIdx.x;
  for (int g = t; g < 1024; g += 256) {
    int row = g >> 3, slot = (g & 7) * 8;
    *(bf16x8*)&A_s[row * 72 + slot] =
        *(const bf16x8*)(qpkpv + ((long)b * 4096 + s0 + row) * 1280 + hh * 64 + slot);
  }
  for (int i = t; i < 2048; i += 256) {
    float s = 0.f;
#pragma unroll
    for (int ch = 0; ch < 8; ch++) s += pkv[((long)(bh * 8 + ch)) * 2048 + i];
    int f = i >> 5, d = i & 31;
    B_s[d * 72 + f] = (bf16_t)s;
  }
  if (t < 64) {
    float s = 0.f;
#pragma unroll
    for (int ch = 0; ch < 8; ch++) s += pks[(bh * 8 + ch) * 64 + t];
    B_s[32 * 72 + t] = (bf16_t)s;
  }
  for (int i = t; i < 960; i += 256) {
    int n = 33 + (i >> 6), f = i & 63;
    B_s[n * 72 + f] = (bf16_t)0.f;
  }
  __syncthreads();
  int lane = t & 63, w = t >> 6;
  f32x4 acc[2][3];
#pragma unroll
  for (int i = 0; i < 2; i++)
#pragma unroll
    for (int j = 0; j < 3; j++) acc[i][j] = (f32x4){0.f, 0.f, 0.f, 0.f};
#pragma unroll
  for (int kt = 0; kt < 2; kt++) {
    int ko = kt * 32 + (lane >> 4) * 8;
    bf16x8 a[2], bb[3];
#pragma unroll
    for (int i = 0; i < 2; i++)
      a[i] = *(const bf16x8*)&A_s[(w * 32 + i * 16 + (lane & 15)) * 72 + ko];
#pragma unroll
    for (int i = 0; i < 3; i++)
      bb[i] = *(const bf16x8*)&B_s[(i * 16 + (lane & 15)) * 72 + ko];
#pragma unroll
    for (int mi = 0; mi < 2; mi++)
#pragma unroll
      for (int ni = 0; ni < 3; ni++)
        acc[mi][ni] = __builtin_amdgcn_mfma_f32_16x16x32_bf16(a[mi], bb[ni], acc[mi][ni], 0, 0, 0);
  }
  long sbase = (long)b * 4096 + s0;
#pragma unroll
  for (int mi = 0; mi < 2; mi++)
#pragma unroll
    for (int j = 0; j < 4; j++) {
      int r = w * 32 + mi * 16 + ((lane >> 4) << 2) + j;
      float den = __shfl(acc[mi][2][j], (lane & 48)) + 1e-8f;
#pragma unroll
      for (int ni = 0; ni < 2; ni++) {
        int d = ni * 16 + (lane & 15);
        ao[(sbase + r) * 256 + hh * 32 + d] = (bf16_t)(acc[mi][ni][j] / den);
      }
    }
}

// ---------------------------------------------------------------------------
// h fp32 -> h_padded bf16 [Bc, S+4, 256] (rows offset +2)
// ---------------------------------------------------------------------------
__global__ __launch_bounds__(256)
void cast_pad(const float* __restrict__ h, bf16_t* __restrict__ hp)
{
  long i8 = ((long)blockIdx.x * 256 + threadIdx.x) * 8;
  long r = i8 >> 8;
  int c = (int)(i8 & 255);
  int b = (int)(r >> 12), s = (int)(r & 4095);
  float4 v0 = *(const float4*)(h + i8);
  float4 v1 = *(const float4*)(h + i8 + 4);
  bf16x8 o;
  o[0] = (bf16_t)v0.x; o[1] = (bf16_t)v0.y; o[2] = (bf16_t)v0.z; o[3] = (bf16_t)v0.w;
  o[4] = (bf16_t)v1.x; o[5] = (bf16_t)v1.y; o[6] = (bf16_t)v1.z; o[7] = (bf16_t)v1.w;
  *(bf16x8*)(hp + ((long)b * 4100 + s + 2) * 256 + c) = o;
}

// ---------------------------------------------------------------------------
// Final conv (DH->1, k=3, pad=1) + sigmoid -> out [Bc,S] fp32
// ---------------------------------------------------------------------------
__global__ __launch_bounds__(256)
void conv_final(const bf16_t* __restrict__ hdp, const float* __restrict__ w2,
                const float* __restrict__ b2, float* __restrict__ out)
{
  __shared__ float ws[384];
  int t = threadIdx.x;
  for (int i = t; i < 384; i += 256) ws[i] = w2[i];  // [c][k]
  __syncthreads();
  long idx = (long)blockIdx.x * 256 + t;
  int b = (int)(idx >> 12);
  const bf16_t* base = hdp + ((long)b * 4098 + (idx & 4095)) * 128;
  float a = b2[0];
#pragma unroll
  for (int k = 0; k < 3; k++) {
#pragma unroll
    for (int c8 = 0; c8 < 16; c8++) {
      bf16x8 v = *(const bf16x8*)(base + k * 128 + c8 * 8);
#pragma unroll
      for (int j = 0; j < 8; j++) a += (float)v[j] * ws[(c8 * 8 + j) * 3 + k];
    }
  }
  out[idx] = 1.f / (1.f + __expf(-a));
}

// ---------------------------------------------------------------------------
// Prep kernels (once per launch)
// ---------------------------------------------------------------------------
__global__ __launch_bounds__(256)
void prep_weff(const float* __restrict__ wq, const float* __restrict__ wk,
               const float* __restrict__ wv, const float* __restrict__ bq,
               const float* __restrict__ bk, const float* __restrict__ bv,
               const float* __restrict__ rf, bf16_t* __restrict__ weff,
               float* __restrict__ beff)
{
  long idx = (long)blockIdx.x * 256 + threadIdx.x;  // 4*1280*256
  int d = (int)(idx & 255);
  long r = idx >> 8;
  int n = (int)(r % 1280);
  int l = (int)(r / 1280);
  float val;
  if (n < 1024) {
    int qk = n >> 9;
    int h = (n >> 6) & 7;
    int f = n & 63;
    const float* w = qk ? wk : wq;
    const float* rfh = rf + ((long)(l * 8 + h) * 32) * 64 + f;
    const float* wrow = w + ((long)l * 256 + d) * 256 + h * 32;
    float s = 0.f;
#pragma unroll
    for (int hd = 0; hd < 32; hd++) s += wrow[hd] * rfh[hd * 64];
    val = s;
  } else {
    val = wv[((long)l * 256 + d) * 256 + (n - 1024)];
  }
  weff[idx] = (bf16_t)val;
  if (idx < 4 * 1280) {
    int nn = (int)(idx % 1280);
    int ll = (int)(idx / 1280);
    float bvv;
    if (nn < 1024) {
      int qk = nn >> 9;
      int h = (nn >> 6) & 7;
      int f = nn & 63;
      const float* bsrc = qk ? bk : bq;
      float s = 0.f;
      for (int hd = 0; hd < 32; hd++)
        s += bsrc[ll * 256 + h * 32 + hd] * rf[((long)(ll * 8 + h) * 32 + hd) * 64 + f];
      bvv = s;
    } else {
      bvv = bv[ll * 256 + (nn - 1024)];
    }
    beff[idx] = bvv;
  }
}

__global__ __launch_bounds__(256)
void prep_cast_t(const float* __restrict__ src, bf16_t* __restrict__ dst, int K, int N)
{
  long idx = (long)blockIdx.x * 256 + threadIdx.x;  // nmats*N*K
  int k = (int)(idx % K);
  long r = idx / K;
  int n = (int)(r % N);
  int l = (int)(r / N);
  dst[idx] = (bf16_t)src[((long)l * K + k) * N + n];
}

__global__ __launch_bounds__(256)
void prep_conv_t(const float* __restrict__ w, bf16_t* __restrict__ dst, int C, int KW)
{
  long idx = (long)blockIdx.x * 256 + threadIdx.x;  // O*C*KW
  int ckw = C * KW;
  int kk = (int)(idx % ckw);
  int o = (int)(idx / ckw);
  int kw = kk / C, c = kk % C;
  dst[idx] = (bf16_t)w[((long)o * C + c) * KW + kw];
}

__global__ __launch_bounds__(256)
void prep_bn(const float* g1, const float* b1, const float* cb1,
             const float* g2, const float* b2, const float* cb2,
             const float* g3, const float* b3, const float* cb3,
             float* sc1, float* sb1, float* sc2, float* sb2,
             float* sc3, float* sb3)
{
  int t = threadIdx.x;
  const float r = rsqrtf(1.f + 1e-5f);
  if (t < 128) { float s = g1[t] * r; sc1[t] = s; sb1[t] = cb1[t] * s + b1[t]; }
  if (t < 256) { float s = g2[t] * r; sc2[t] = s; sb2[t] = cb2[t] * s + b2[t]; }
  if (t < 128) { float s = g3[t] * r; sc3[t] = s; sb3[t] = cb3[t] * s + b3[t]; }
}

__global__ __launch_bounds__(256)
void pe_fill(float* __restrict__ pe)
{
  long idx = (long)blockIdx.x * 256 + threadIdx.x;  // 4096*256
  int dcol = (int)(idx & 255);
  int s = (int)(idx >> 8);
  int i2 = dcol >> 1;
  float freq = expf(-9.210340371976184f * (float)(2 * i2) / 256.f);
  float a = (float)s * freq;
  pe[idx] = (dcol & 1) ? cosf(a) : sinf(a);
}

// ---------------------------------------------------------------------------
extern "C" void kernel_launch(void* const* d_in, const int* in_sizes, int n_in,
                              void* d_out, int out_size, void* d_ws, size_t ws_size,
                              hipStream_t stream)
{
  (void)in_sizes; (void)n_in; (void)out_size;
  const float* x      = (const float*)d_in[0];
  const float* emb_w1 = (const float*)d_in[1];
  const float* emb_b1 = (const float*)d_in[2];
  const float* bn1_g  = (const float*)d_in[3];
  const float* bn1_b  = (const float*)d_in[4];
  const float* emb_w2 = (const float*)d_in[5];
  const float* emb_b2 = (const float*)d_in[6];
  const float* bn2_g  = (const float*)d_in[7];
  const float* bn2_b  = (const float*)d_in[8];
  const float* wq     = (const float*)d_in[9];
  const float* bq     = (const float*)d_in[10];
  const float* wk     = (const float*)d_in[11];
  const float* bk     = (const float*)d_in[12];
  const float* wv     = (const float*)d_in[13];
  const float* bv     = (const float*)d_in[14];
  const float* wo     = (const float*)d_in[15];
  const float* bo     = (const float*)d_in[16];
  const float* rf     = (const float*)d_in[17];
  const float* ln1_g  = (const float*)d_in[18];
  const float* ln1_b  = (const float*)d_in[19];
  const float* ln2_g  = (const float*)d_in[20];
  const float* ln2_b  = (const float*)d_in[21];
  const float* ff_w1  = (const float*)d_in[22];
  const float* ff_b1  = (const float*)d_in[23];
  const float* ff_w2  = (const float*)d_in[24];
  const float* ff_b2  = (const float*)d_in[25];
  const float* dec_w1 = (const float*)d_in[26];
  const float* dec_b1 = (const float*)d_in[27];
  const float* bn3_g  = (const float*)d_in[28];
  const float* bn3_b  = (const float*)d_in[29];
  const float* dec_w2 = (const float*)d_in[30];
  const float* dec_b2 = (const float*)d_in[31];

  char* W = (char*)d_ws;

  // ---- fixed region (weights, ~12.2 MB; reserve 16 MB) ----
  bf16_t* weff = (bf16_t*)(W + 0);                     // 4*1280*256*2 = 2,621,440
  float*  beff = (float*)(W + 2621440);                // 20,480
  bf16_t* wot  = (bf16_t*)(W + 2641920);               // 524,288
  bf16_t* w1t  = (bf16_t*)(W + 3166208);               // 2,097,152
  bf16_t* w2t  = (bf16_t*)(W + 5263360);               // 2,097,152
  bf16_t* c2t  = (bf16_t*)(W + 7360512);               // 327,680
  bf16_t* d1t  = (bf16_t*)(W + 7688192);               // 327,680
  float*  pe   = (float*)(W + 8015872);                // 4,194,304
  float*  sc1  = (float*)(W + 12210176);
  float*  sb1  = (float*)(W + 12211200);
  float*  sc2  = (float*)(W + 12212224);
  float*  sb2  = (float*)(W + 12213248);
  float*  sc3  = (float*)(W + 12214272);
  float*  sb3  = (float*)(W + 12215296);
  const size_t FIXED_END = 16777216;

  // ---- pick batch chunk Bc so workspace fits ws_size ----
  const size_t PER_B = 17385472;
  int Bc = 32;
  while (Bc > 1 && FIXED_END + (size_t)Bc * PER_B > ws_size) Bc >>= 1;

  char* P = W + FIXED_END;
  float*  h     = (float*)P;
  bf16_t* xa    = (bf16_t*)(P + (size_t)Bc * 4194304);
  bf16_t* ao    = xa;  // xa dead after fused qkv gemm; ao dead before ln2
  char*   big   = P + (size_t)Bc * (4194304 + 2097152);
  bf16_t* qpkpv = (bf16_t*)big;
  bf16_t* f1    = (bf16_t*)big;                               // after qpkpv dead
  bf16_t* h1p   = (bf16_t*)big;                               // pre-loop
  bf16_t* hpad  = (bf16_t*)big;                               // post-loop
  bf16_t* hdp   = (bf16_t*)(big + (size_t)Bc * 4100 * 256 * 2);
  float*  pkv   = (float*)(big + (size_t)Bc * 10485760);
  float*  pks   = (float*)((char*)pkv + (size_t)Bc * 524288);

  // ---- weight prep (once) ----
  prep_weff<<<5120, 256, 0, stream>>>(wq, wk, wv, bq, bk, bv, rf, weff, beff);
  prep_cast_t<<<1024, 256, 0, stream>>>(wo, wot, 256, 256);
  prep_cast_t<<<4096, 256, 0, stream>>>(ff_w1, w1t, 256, 1024);
  prep_cast_t<<<4096, 256, 0, stream>>>(ff_w2, w2t, 1024, 256);
  prep_conv_t<<<640, 256, 0, stream>>>(emb_w2, c2t, 128, 5);
  prep_conv_t<<<640, 256, 0, stream>>>(dec_w1, d1t, 256, 5);
  prep_bn<<<1, 256, 0, stream>>>(bn1_g, bn1_b, emb_b1, bn2_g, bn2_b, emb_b2,
                                 bn3_g, bn3_b, dec_b1, sc1, sb1, sc2, sb2, sc3, sb3);
  pe_fill<<<4096, 256, 0, stream>>>(pe);

  for (int c0 = 0; c0 < 32; c0 += Bc) {
    const float* xc = x + (size_t)c0 * 4096;

    // ---- embedding ----
    hipMemsetAsync(h1p, 0, (size_t)Bc * 4100 * 128 * 2, stream);
    conv1_kernel<<<Bc * 64, 256, 0, stream>>>(xc, emb_w1, sc1, sb1, h1p);
    gemm_bf16<3, 640, 64, 4><<<Bc * 128, 256, 0, stream>>>(
        h1p, c2t, h, sb2, sc2, nullptr, pe,
        128, 4100L * 128, 4096, 256, 256, 4096L * 256, 0);

    // ---- transformer layers ----
    for (int l = 0; l < 4; l++) {
      ln_kernel<<<Bc * 1024, 256, 0, stream>>>(h, ln1_g + l * 256, ln1_b + l * 256, xa);
      gemm_bf16<5, 256, 128, 10><<<Bc * 320, 256, 0, stream>>>(
          xa, weff + (long)l * 327680, qpkpv, beff + l * 1280, nullptr, nullptr, nullptr,
          256, 4096L * 256, 4096, 1280, 1280, 4096L * 1280, 0);
      kv_partial<<<Bc * 64, 256, 0, stream>>>(qpkpv, pkv, pks);
      combine_mfma<<<Bc * 256, 256, 0, stream>>>(qpkpv, pkv, pks, ao);
      gemm_bf16<1, 256, 64, 4><<<Bc * 128, 256, 0, stream>>>(
          ao, wot + (long)l * 65536, h, bo + l * 256, nullptr, h, nullptr,
          256, 4096L * 256, 4096, 256, 256, 4096L * 256, 0);
      ln_kernel<<<Bc * 1024, 256, 0, stream>>>(h, ln2_g + l * 256, ln2_b + l * 256, xa);
      gemm_bf16<2, 256, 128, 8><<<Bc * 256, 256, 0, stream>>>(
          xa, w1t + (long)l * 262144, f1, ff_b1 + l * 1024, nullptr, nullptr, nullptr,
          256, 4096L * 256, 4096, 1024, 1024, 4096L * 1024, 0);
      gemm_bf16<1, 1024, 64, 4><<<Bc * 128, 256, 0, stream>>>(
          f1, w2t + (long)l * 262144, h, ff_b2 + l * 256, nullptr, h, nullptr,
          1024, 4096L * 1024, 4096, 256, 256, 4096L * 256, 0);
    }

    // ---- decoder ----
    hipMemsetAsync(hpad, 0, (size_t)Bc * 4100 * 256 * 2, stream);
    cast_pad<<<Bc * 512, 256, 0, stream>>>(h, hpad);
    hipMemsetAsync(hdp, 0, (size_t)Bc * 4098 * 128 * 2, stream);
    gemm_bf16<4, 1280, 64, 2><<<Bc * 64, 256, 0, stream>>>(
        hpad, d1t, hdp, sb3, sc3, nullptr, nullptr,
        256, 4100L * 256, 4096, 128, 128, 4098L * 128, 1);
    conv_final<<<Bc * 16, 256, 0, stream>>>(hdp, dec_w2, dec_b2,
                                            (float*)d_out + (size_t)c0 * 4096);
  }
}

// Round 13
// 4225.620 us; speedup vs baseline: 1.4424x; 1.0040x over previous
//
#include <hip/hip_runtime.h>
#include <hip/hip_bf16.h>
#include <math.h>

// ============================================================================
// PPGPeakPerformer forward on MI355X (gfx950)
// B=32 S=4096 D=256 DH=128 H=8 HD=32 F=64 L=4
// GEMM: 128xBN tile (BN=128 wide, BN=64 narrow), BK=32. A-panel TRIPLE-
// buffered depth-2 with counted vmcnt(2) (A-loads get ~2 iters of slack ->
// HBM-latency tolerant); B double-buffered depth-1 (weights L2-resident).
// LDS 40KB -> 4 blocks/CU, VGPR 64 (launch_bounds(256,4); r10: 5+ spills).
// 1D grid + bijective XCD chunk-remap (n fastest) on GEMMs AND ln_kernel so
// the h->ln->xa->GEMM chain is XCD-L2-local (r12: FETCH 27->14MB was xa
// written on foreign XCDs; this removes it).
// Swizzle slot^((row>>1)&3) both-sides. Fast rational erf. Fused q/k RF
// projection GEMM. kv_reduce folded into combine_mfma.
// ============================================================================

typedef __bf16 bf16_t;
typedef __bf16 bf16x8 __attribute__((ext_vector_type(8)));
typedef __bf16 bf16x4 __attribute__((ext_vector_type(4)));
typedef float  f32x4  __attribute__((ext_vector_type(4)));

#define DEV __device__ __forceinline__

DEV float erf_fast(float x) {
  float ax = fabsf(x);
  float t = __builtin_amdgcn_rcpf(1.f + 0.3275911f * ax);
  float p = t * (0.254829592f + t * (-0.284496736f + t * (1.421413741f +
            t * (-1.453152027f + t * 1.061405429f))));
  float r = 1.f - p * __expf(-ax * ax);
  return copysignf(r, x);
}
DEV float geluf(float v) { return 0.5f * v * (1.f + erf_fast(v * 0.70710678118654752440f)); }
DEV float softplusf(float v) {
  float e = __expf(-fabsf(v));
  return fmaxf(v, 0.f) + __logf(1.f + e);
}

// Direct global->LDS 16B staging. LDS dest is wave-uniform base + lane*16.
DEV void gload16(const bf16_t* g, bf16_t* l) {
  __builtin_amdgcn_global_load_lds(
      (const __attribute__((address_space(1))) void*)g,
      (__attribute__((address_space(3))) void*)l, 16, 0, 0);
}

// ---------------------------------------------------------------------------
// GEMM: C[m,n] = sum_k A[m,k]*Bt[n,k].  A bf16 (batched rows), Bt bf16 [N][K].
// EPI: 1 = +bias +resid -> fp32; 2 = gelu(+bias) -> bf16;
//      3 = gelu(scale*x+bias)+pe -> fp32; 4 = gelu(scale*x+bias) -> bf16;
//      5 = col<1024 ? softplus(+bias) : (+bias) -> bf16
// Pipeline per iter t:
//   wait vmcnt(2)   // drains A(t),B(t); leaves A(t+1) [+A(t+2) next iters]
//   s_barrier       // LDS buffer recycle safety
//   stage B(t+1) -> Bs[(t+1)&1]   (gload_lds, issued BEFORE A so the
//   stage A(t+2) -> As[(t+2)%3]    in-order vmcnt leaves A-loads in flight)
//   ds_read As[t%3]/Bs[t&1]; MFMA.
// A slack ~2 iters (HBM-ok), B slack ~1 iter (L2-ok).
// ---------------------------------------------------------------------------
template <int EPI, int K, int BN, int NTL>
__global__ __launch_bounds__(256, 4)
void gemm_bf16(const bf16_t* __restrict__ A, const bf16_t* __restrict__ Bt,
               void* Cout, const float* __restrict__ bias,
               const float* __restrict__ scale, const float* resid,
               const float* __restrict__ pe,
               int lda, long a_bstride, int rpb,
               int N, int ldc, long c_bstride, int c_roff)
{
  constexpr int MI = (BN == 128) ? 4 : 2;   // row-fragments per wave
  __shared__ bf16_t As[3][128 * 32];
  __shared__ bf16_t Bs[2][BN * 32];
  const int t = threadIdx.x;
  const int lane = t & 63;
  const int w = t >> 6;
  const int wrow = (BN == 128) ? (w >> 1) * 64 : w * 32;
  const int wcol = (BN == 128) ? (w & 1) * 64 : 0;

  // XCD-aware bijective remap (m204): bid%8 -> XCD; XCD k gets a contiguous
  // wgid chunk (n-tile fastest) so A-tile sharers co-reside on one L2.
  const int nwg = gridDim.x;
  const int q_ = nwg >> 3, r_ = nwg & 7;
  const int xcd = blockIdx.x & 7, idx_ = blockIdx.x >> 3;
  const int wgid = (xcd < r_ ? xcd * (q_ + 1) : r_ * (q_ + 1) + (xcd - r_) * q_) + idx_;
  const long m0 = (long)(wgid / NTL) * 128;
  const int n0 = (wgid % NTL) * BN;

  const int b = (int)(m0 / rpb);
  const int s_base = (int)(m0 % rpb);
  const bf16_t* Ab = A + (long)b * a_bstride + (long)s_base * lda;
  const bf16_t* Bb = Bt + (long)n0 * K;

  // staging source (pre-swizzled): lane covers row (lane>>2) of a 16-row
  // block, 16B slot ((lane&3) ^ ((row>>1)&3)).
  const int srow = lane >> 2;
  const int sslot = (lane & 3) ^ ((srow >> 1) & 3);
  const bf16_t* aS = Ab + (long)(w * 32 + srow) * lda + sslot * 8;
  const bf16_t* bS = Bb + (long)(w * 32 + srow) * K + sslot * 8;
  const int dsto = w * 1024;  // 32 rows x 32 elems per wave

#define STAGE_A(bufidx, kk)                                 \
  {                                                         \
    bf16_t* a_ = &As[bufidx][dsto];                         \
    gload16(aS + (kk), a_);                                 \
    gload16(aS + (kk) + 16 * (long)lda, a_ + 512);          \
  }
#define STAGE_B(bufidx, kk)                                 \
  if (BN == 128 || w < 2) {                                 \
    bf16_t* b_ = &Bs[bufidx][dsto];                         \
    gload16(bS + (kk), b_);                                 \
    gload16(bS + (kk) + 16 * (long)K, b_ + 512);            \
  }

  f32x4 acc[MI][4];
#pragma unroll
  for (int i = 0; i < MI; i++)
#pragma unroll
    for (int j = 0; j < 4; j++) acc[i][j] = (f32x4){0.f, 0.f, 0.f, 0.f};

  constexpr int NT = K >> 5;
  // prologue queue order: A(0), B(0), A(1) -> wait vmcnt(2) drains A0,B0.
  STAGE_A(0, 0);
  STAGE_B(0, 0);
  if (NT > 1) STAGE_A(1, 32);

#pragma unroll
  for (int tt = 0; tt < NT; ++tt) {
    if (tt + 1 < NT) {
      asm volatile("s_waitcnt vmcnt(2)" ::: "memory");
    } else {
      asm volatile("s_waitcnt vmcnt(0)" ::: "memory");
    }
    __builtin_amdgcn_s_barrier();
    __builtin_amdgcn_sched_barrier(0);
    if (tt + 1 < NT) STAGE_B((tt + 1) & 1, (tt + 1) * 32);
    if (tt + 2 < NT) STAGE_A((tt + 2) % 3, (tt + 2) * 32);
    const bf16_t* Acur = As[tt % 3];
    const bf16_t* Bcur = Bs[tt & 1];
    const int kb = (lane >> 4) * 16;
    bf16x8 af[MI], bfr[4];
#pragma unroll
    for (int i = 0; i < MI; i++) {
      int rA = wrow + i * 16 + (lane & 15);
      af[i] = *(const bf16x8*)((const char*)Acur + rA * 64 + (kb ^ (((rA >> 1) & 3) << 4)));
    }
#pragma unroll
    for (int j = 0; j < 4; j++) {
      int rB = wcol + j * 16 + (lane & 15);
      bfr[j] = *(const bf16x8*)((const char*)Bcur + rB * 64 + (kb ^ (((rB >> 1) & 3) << 4)));
    }
    __builtin_amdgcn_s_setprio(1);
#pragma unroll
    for (int mi = 0; mi < MI; mi++)
#pragma unroll
      for (int ni = 0; ni < 4; ni++)
        acc[mi][ni] = __builtin_amdgcn_mfma_f32_16x16x32_bf16(af[mi], bfr[ni], acc[mi][ni], 0, 0, 0);
    __builtin_amdgcn_s_setprio(0);
  }
#undef STAGE_A
#undef STAGE_B

  const int colbase = n0 + wcol + (lane & 15);
  float bias_r[4], scale_r[4];
#pragma unroll
  for (int ni = 0; ni < 4; ni++) {
    int col = colbase + ni * 16;
    bias_r[ni] = bias[col];
    scale_r[ni] = (EPI == 3 || EPI == 4) ? scale[col] : 0.f;
  }
#pragma unroll
  for (int mi = 0; mi < MI; mi++) {
#pragma unroll
    for (int j = 0; j < 4; j++) {
      int row = wrow + mi * 16 + ((lane >> 4) << 2) + j;
      long s = s_base + row;
      long cro = (long)b * c_bstride + (s + c_roff) * (long)ldc;
#pragma unroll
      for (int ni = 0; ni < 4; ni++) {
        int col = colbase + ni * 16;
        float v = acc[mi][ni][j];
        if constexpr (EPI == 1) {
          v += bias_r[ni] + resid[cro + col];
          ((float*)Cout)[cro + col] = v;
        } else if constexpr (EPI == 2) {
          v = geluf(v + bias_r[ni]);
          ((bf16_t*)Cout)[cro + col] = (bf16_t)v;
        } else if constexpr (EPI == 3) {
          v = geluf(v * scale_r[ni] + bias_r[ni]) + pe[s * 256 + col];
          ((float*)Cout)[cro + col] = v;
        } else if constexpr (EPI == 4) {
          v = geluf(v * scale_r[ni] + bias_r[ni]);
          ((bf16_t*)Cout)[cro + col] = (bf16_t)v;
        } else {  // 5
          v += bias_r[ni];
          if (col < 1024) v = softplusf(v);
          ((bf16_t*)Cout)[cro + col] = (bf16_t)v;
        }
      }
    }
  }
}

// ---------------------------------------------------------------------------
// LayerNorm over D=256, fp32 in -> bf16 out. 4 rows/block (1 wave per row).
// XCD chunk-remap matches the GEMM m-tile map: XCD k owns contiguous rows.
// ---------------------------------------------------------------------------
__global__ __launch_bounds__(256)
void ln_kernel(const float* __restrict__ h, const float* __restrict__ g,
               const float* __restrict__ bta, bf16_t* __restrict__ out)
{
  int t = threadIdx.x;
  int lane = t & 63;
  const int G = gridDim.x;                 // divisible by 8
  const int wgid = (blockIdx.x & 7) * (G >> 3) + (blockIdx.x >> 3);
  long row = (long)wgid * 4 + (t >> 6);
  const float* hp = h + row * 256 + lane * 4;
  float4 v = *(const float4*)hp;
  float s = v.x + v.y + v.z + v.w;
  float q = v.x * v.x + v.y * v.y + v.z * v.z + v.w * v.w;
#pragma unroll
  for (int m = 32; m >= 1; m >>= 1) {
    s += __shfl_xor(s, m);
    q += __shfl_xor(q, m);
  }
  float mean = s * 0.00390625f;
  float var = q * 0.00390625f - mean * mean;
  float rstd = rsqrtf(var + 1e-5f);
  int c = lane * 4;
  float4 gv = *(const float4*)(g + c);
  float4 bv = *(const float4*)(bta + c);
  bf16x4 o;
  o[0] = (bf16_t)((v.x - mean) * rstd * gv.x + bv.x);
  o[1] = (bf16_t)((v.y - mean) * rstd * gv.y + bv.y);
  o[2] = (bf16_t)((v.z - mean) * rstd * gv.z + bv.z);
  o[3] = (bf16_t)((v.w - mean) * rstd * gv.w + bv.w);
  *(bf16x4*)(out + row * 256 + c) = o;
}

// ---------------------------------------------------------------------------
// Embedding conv1: x[Bc,S] -> gelu(bn(conv1d k=7 pad=3)) -> h1p[Bc,S+4,128]
// ---------------------------------------------------------------------------
__global__ __launch_bounds__(256)
void conv1_kernel(const float* __restrict__ x, const float* __restrict__ w1,
                  const float* __restrict__ sc, const float* __restrict__ sb,
                  bf16_t* __restrict__ h1p)
{
  int b = blockIdx.x >> 6;
  int s0 = (blockIdx.x & 63) << 6;
  __shared__ float xs[70];
  __shared__ float ws[896];
  int t = threadIdx.x;
  if (t < 70) {
    int s = s0 + t - 3;
    xs[t] = (s >= 0 && s < 4096) ? x[(long)b * 4096 + s] : 0.f;
  }
  for (int i = t; i < 896; i += 256) ws[i] = w1[i];
  __syncthreads();
  int c = t & 127, so = t >> 7;
  float wr[7];
#pragma unroll
  for (int k = 0; k < 7; k++) wr[k] = ws[c * 7 + k];
  float scl = sc[c], sbv = sb[c];
  for (int p = 0; p < 32; p++) {
    int sl = p * 2 + so;
    float a = 0.f;
#pragma unroll
    for (int k = 0; k < 7; k++) a += xs[sl + k] * wr[k];
    a = geluf(a * scl + sbv);
    h1p[((long)b * 4100 + s0 + sl + 2) * 128 + c] = (bf16_t)a;
  }
}

// ---------------------------------------------------------------------------
// kv partial: per (b,h,chunk of 512 s): acc[f][d] += kp[s,f]*v[s,d]; +ksum.
// ---------------------------------------------------------------------------
__global__ __launch_bounds__(256)
void kv_partial(const bf16_t* __restrict__ qpkpv,
                float* __restrict__ pkv, float* __restrict__ pks)
{
  int bh = blockIdx.x >> 3, ch = blockIdx.x & 7;
  int b = bh >> 3, hh = bh & 7;
  int s0 = ch * 512;
  __shared__ float kps[32 * 64];
  __shared__ float vs[32 * 32];
  int t = threadIdx.x;
  int f = t & 63, dg = t >> 6;
  float acc[8] = {0.f, 0.f, 0.f, 0.f, 0.f, 0.f, 0.f, 0.f};
  float ks = 0.f;
  const int row = t >> 3, slot8 = (t & 7) * 8, slot4 = (t & 7) * 4;
  for (int sb = 0; sb < 512; sb += 32) {
    __syncthreads();
    {
      const bf16_t* rowp = qpkpv + ((long)b * 4096 + s0 + sb + row) * 1280;
      bf16x8 k8 = *(const bf16x8*)(rowp + 512 + hh * 64 + slot8);
#pragma unroll
      for (int j = 0; j < 8; j++) kps[row * 64 + slot8 + j] = (float)k8[j];
      bf16x4 v4 = *(const bf16x4*)(rowp + 1024 + hh * 32 + slot4);
#pragma unroll
      for (int j = 0; j < 4; j++) vs[row * 32 + slot4 + j] = (float)v4[j];
    }
    __syncthreads();
#pragma unroll 4
    for (int s = 0; s < 32; s++) {
      float kval = kps[s * 64 + f];
      float4 v0 = *(const float4*)&vs[s * 32 + dg * 8];
      float4 v1 = *(const float4*)&vs[s * 32 + dg * 8 + 4];
      acc[0] += kval * v0.x; acc[1] += kval * v0.y;
      acc[2] += kval * v0.z; acc[3] += kval * v0.w;
      acc[4] += kval * v1.x; acc[5] += kval * v1.y;
      acc[6] += kval * v1.z; acc[7] += kval * v1.w;
      ks += kval;
    }
  }
  long o = (long)blockIdx.x * 2048 + f * 32 + dg * 8;
#pragma unroll
  for (int j = 0; j < 8; j++) pkv[o + j] = acc[j];
  if (dg == 0) pks[blockIdx.x * 64 + f] = ks;
}

// ---------------------------------------------------------------------------
// combine: ao[s, h*32+d] = (qp[s,:] @ kv[:,d]) / (qp[s,:]@ksum + 1e-8)
// kv/ksum reduced from 8 chunk-partials inline (deterministic order).
// ---------------------------------------------------------------------------
__global__ __launch_bounds__(256, 2)
void combine_mfma(const bf16_t* __restrict__ qpkpv, const float* __restrict__ pkv,
                  const float* __restrict__ pks, bf16_t* __restrict__ ao)
{
  int bh = blockIdx.x >> 5;
  int s0 = (blockIdx.x & 31) << 7;
  int b = bh >> 3, hh = bh & 7;
  __shared__ bf16_t A_s[128 * 72];
  __shared__ bf16_t B_s[48 * 72];
  int t = threadIdx.x;
  for (int g = t; g < 1024; g += 256) {
    int row = g >> 3, slot = (g & 7) * 8;
    *(bf16x8*)&A_s[row * 72 + slot] =
        *(const bf16x8*)(qpkpv + ((long)b * 4096 + s0 + row) * 1280 + hh * 64 + slot);
  }
  for (int i = t; i < 2048; i += 256) {
    float s = 0.f;
#pragma unroll
    for (int ch = 0; ch < 8; ch++) s += pkv[((long)(bh * 8 + ch)) * 2048 + i];
    int f = i >> 5, d = i & 31;
    B_s[d * 72 + f] = (bf16_t)s;
  }
  if (t < 64) {
    float s = 0.f;
#pragma unroll
    for (int ch = 0; ch < 8; ch++) s += pks[(bh * 8 + ch) * 64 + t];
    B_s[32 * 72 + t] = (bf16_t)s;
  }
  for (int i = t; i < 960; i += 256) {
    int n = 33 + (i >> 6), f = i & 63;
    B_s[n * 72 + f] = (bf16_t)0.f;
  }
  __syncthreads();
  int lane = t & 63, w = t >> 6;
  f32x4 acc[2][3];
#pragma unroll
  for (int i = 0; i < 2; i++)
#pragma unroll
    for (int j = 0; j < 3; j++) acc[i][j] = (f32x4){0.f, 0.f, 0.f, 0.f};
#pragma unroll
  for (int kt = 0; kt < 2; kt++) {
    int ko = kt * 32 + (lane >> 4) * 8;
    bf16x8 a[2], bb[3];
#pragma unroll
    for (int i = 0; i < 2; i++)
      a[i] = *(const bf16x8*)&A_s[(w * 32 + i * 16 + (lane & 15)) * 72 + ko];
#pragma unroll
    for (int i = 0; i < 3; i++)
      bb[i] = *(const bf16x8*)&B_s[(i * 16 + (lane & 15)) * 72 + ko];
#pragma unroll
    for (int mi = 0; mi < 2; mi++)
#pragma unroll
      for (int ni = 0; ni < 3; ni++)
        acc[mi][ni] = __builtin_amdgcn_mfma_f32_16x16x32_bf16(a[mi], bb[ni], acc[mi][ni], 0, 0, 0);
  }
  long sbase = (long)b * 4096 + s0;
#pragma unroll
  for (int mi = 0; mi < 2; mi++)
#pragma unroll
    for (int j = 0; j < 4; j++) {
      int r = w * 32 + mi * 16 + ((lane >> 4) << 2) + j;
      float den = __shfl(acc[mi][2][j], (lane & 48)) + 1e-8f;
#pragma unroll
      for (int ni = 0; ni < 2; ni++) {
        int d = ni * 16 + (lane & 15);
        ao[(sbase + r) * 256 + hh * 32 + d] = (bf16_t)(acc[mi][ni][j] / den);
      }
    }
}

// ---------------------------------------------------------------------------
// h fp32 -> h_padded bf16 [Bc, S+4, 256] (rows offset +2)
// ---------------------------------------------------------------------------
__global__ __launch_bounds__(256)
void cast_pad(const float* __restrict__ h, bf16_t* __restrict__ hp)
{
  long i8 = ((long)blockIdx.x * 256 + threadIdx.x) * 8;
  long r = i8 >> 8;
  int c = (int)(i8 & 255);
  int b = (int)(r >> 12), s = (int)(r & 4095);
  float4 v0 = *(const float4*)(h + i8);
  float4 v1 = *(const float4*)(h + i8 + 4);
  bf16x8 o;
  o[0] = (bf16_t)v0.x; o[1] = (bf16_t)v0.y; o[2] = (bf16_t)v0.z; o[3] = (bf16_t)v0.w;
  o[4] = (bf16_t)v1.x; o[5] = (bf16_t)v1.y; o[6] = (bf16_t)v1.z; o[7] = (bf16_t)v1.w;
  *(bf16x8*)(hp + ((long)b * 4100 + s + 2) * 256 + c) = o;
}

// ---------------------------------------------------------------------------
// Final conv (DH->1, k=3, pad=1) + sigmoid -> out [Bc,S] fp32
// ---------------------------------------------------------------------------
__global__ __launch_bounds__(256)
void conv_final(const bf16_t* __restrict__ hdp, const float* __restrict__ w2,
                const float* __restrict__ b2, float* __restrict__ out)
{
  __shared__ float ws[384];
  int t = threadIdx.x;
  for (int i = t; i < 384; i += 256) ws[i] = w2[i];  // [c][k]
  __syncthreads();
  long idx = (long)blockIdx.x * 256 + t;
  int b = (int)(idx >> 12);
  const bf16_t* base = hdp + ((long)b * 4098 + (idx & 4095)) * 128;
  float a = b2[0];
#pragma unroll
  for (int k = 0; k < 3; k++) {
#pragma unroll
    for (int c8 = 0; c8 < 16; c8++) {
      bf16x8 v = *(const bf16x8*)(base + k * 128 + c8 * 8);
#pragma unroll
      for (int j = 0; j < 8; j++) a += (float)v[j] * ws[(c8 * 8 + j) * 3 + k];
    }
  }
  out[idx] = 1.f / (1.f + __expf(-a));
}

// ---------------------------------------------------------------------------
// Prep kernels (once per launch)
// ---------------------------------------------------------------------------
__global__ __launch_bounds__(256)
void prep_weff(const float* __restrict__ wq, const float* __restrict__ wk,
               const float* __restrict__ wv, const float* __restrict__ bq,
               const float* __restrict__ bk, const float* __restrict__ bv,
               const float* __restrict__ rf, bf16_t* __restrict__ weff,
               float* __restrict__ beff)
{
  long idx = (long)blockIdx.x * 256 + threadIdx.x;  // 4*1280*256
  int d = (int)(idx & 255);
  long r = idx >> 8;
  int n = (int)(r % 1280);
  int l = (int)(r / 1280);
  float val;
  if (n < 1024) {
    int qk = n >> 9;
    int h = (n >> 6) & 7;
    int f = n & 63;
    const float* w = qk ? wk : wq;
    const float* rfh = rf + ((long)(l * 8 + h) * 32) * 64 + f;
    const float* wrow = w + ((long)l * 256 + d) * 256 + h * 32;
    float s = 0.f;
#pragma unroll
    for (int hd = 0; hd < 32; hd++) s += wrow[hd] * rfh[hd * 64];
    val = s;
  } else {
    val = wv[((long)l * 256 + d) * 256 + (n - 1024)];
  }
  weff[idx] = (bf16_t)val;
  if (idx < 4 * 1280) {
    int nn = (int)(idx % 1280);
    int ll = (int)(idx / 1280);
    float bvv;
    if (nn < 1024) {
      int qk = nn >> 9;
      int h = (nn >> 6) & 7;
      int f = nn & 63;
      const float* bsrc = qk ? bk : bq;
      float s = 0.f;
      for (int hd = 0; hd < 32; hd++)
        s += bsrc[ll * 256 + h * 32 + hd] * rf[((long)(ll * 8 + h) * 32 + hd) * 64 + f];
      bvv = s;
    } else {
      bvv = bv[ll * 256 + (nn - 1024)];
    }
    beff[idx] = bvv;
  }
}

__global__ __launch_bounds__(256)
void prep_cast_t(const float* __restrict__ src, bf16_t* __restrict__ dst, int K, int N)
{
  long idx = (long)blockIdx.x * 256 + threadIdx.x;  // nmats*N*K
  int k = (int)(idx % K);
  long r = idx / K;
  int n = (int)(r % N);
  int l = (int)(r / N);
  dst[idx] = (bf16_t)src[((long)l * K + k) * N + n];
}

__global__ __launch_bounds__(256)
void prep_conv_t(const float* __restrict__ w, bf16_t* __restrict__ dst, int C, int KW)
{
  long idx = (long)blockIdx.x * 256 + threadIdx.x;  // O*C*KW
  int ckw = C * KW;
  int kk = (int)(idx % ckw);
  int o = (int)(idx / ckw);
  int kw = kk / C, c = kk % C;
  dst[idx] = (bf16_t)w[((long)o * C + c) * KW + kw];
}

__global__ __launch_bounds__(256)
void prep_bn(const float* g1, const float* b1, const float* cb1,
             const float* g2, const float* b2, const float* cb2,
             const float* g3, const float* b3, const float* cb3,
             float* sc1, float* sb1, float* sc2, float* sb2,
             float* sc3, float* sb3)
{
  int t = threadIdx.x;
  const float r = rsqrtf(1.f + 1e-5f);
  if (t < 128) { float s = g1[t] * r; sc1[t] = s; sb1[t] = cb1[t] * s + b1[t]; }
  if (t < 256) { float s = g2[t] * r; sc2[t] = s; sb2[t] = cb2[t] * s + b2[t]; }
  if (t < 128) { float s = g3[t] * r; sc3[t] = s; sb3[t] = cb3[t] * s + b3[t]; }
}

__global__ __launch_bounds__(256)
void pe_fill(float* __restrict__ pe)
{
  long idx = (long)blockIdx.x * 256 + threadIdx.x;  // 4096*256
  int dcol = (int)(idx & 255);
  int s = (int)(idx >> 8);
  int i2 = dcol >> 1;
  float freq = expf(-9.210340371976184f * (float)(2 * i2) / 256.f);
  float a = (float)s * freq;
  pe[idx] = (dcol & 1) ? cosf(a) : sinf(a);
}

// ---------------------------------------------------------------------------
extern "C" void kernel_launch(void* const* d_in, const int* in_sizes, int n_in,
                              void* d_out, int out_size, void* d_ws, size_t ws_size,
                              hipStream_t stream)
{
  (void)in_sizes; (void)n_in; (void)out_size;
  const float* x      = (const float*)d_in[0];
  const float* emb_w1 = (const float*)d_in[1];
  const float* emb_b1 = (const float*)d_in[2];
  const float* bn1_g  = (const float*)d_in[3];
  const float* bn1_b  = (const float*)d_in[4];
  const float* emb_w2 = (const float*)d_in[5];
  const float* emb_b2 = (const float*)d_in[6];
  const float* bn2_g  = (const float*)d_in[7];
  const float* bn2_b  = (const float*)d_in[8];
  const float* wq     = (const float*)d_in[9];
  const float* bq     = (const float*)d_in[10];
  const float* wk     = (const float*)d_in[11];
  const float* bk     = (const float*)d_in[12];
  const float* wv     = (const float*)d_in[13];
  const float* bv     = (const float*)d_in[14];
  const float* wo     = (const float*)d_in[15];
  const float* bo     = (const float*)d_in[16];
  const float* rf     = (const float*)d_in[17];
  const float* ln1_g  = (const float*)d_in[18];
  const float* ln1_b  = (const float*)d_in[19];
  const float* ln2_g  = (const float*)d_in[20];
  const float* ln2_b  = (const float*)d_in[21];
  const float* ff_w1  = (const float*)d_in[22];
  const float* ff_b1  = (const float*)d_in[23];
  const float* ff_w2  = (const float*)d_in[24];
  const float* ff_b2  = (const float*)d_in[25];
  const float* dec_w1 = (const float*)d_in[26];
  const float* dec_b1 = (const float*)d_in[27];
  const float* bn3_g  = (const float*)d_in[28];
  const float* bn3_b  = (const float*)d_in[29];
  const float* dec_w2 = (const float*)d_in[30];
  const float* dec_b2 = (const float*)d_in[31];

  char* W = (char*)d_ws;

  // ---- fixed region (weights, ~12.2 MB; reserve 16 MB) ----
  bf16_t* weff = (bf16_t*)(W + 0);                     // 4*1280*256*2 = 2,621,440
  float*  beff = (float*)(W + 2621440);                // 20,480
  bf16_t* wot  = (bf16_t*)(W + 2641920);               // 524,288
  bf16_t* w1t  = (bf16_t*)(W + 3166208);               // 2,097,152
  bf16_t* w2t  = (bf16_t*)(W + 5263360);               // 2,097,152
  bf16_t* c2t  = (bf16_t*)(W + 7360512);               // 327,680
  bf16_t* d1t  = (bf16_t*)(W + 7688192);               // 327,680
  float*  pe   = (float*)(W + 8015872);                // 4,194,304
  float*  sc1  = (float*)(W + 12210176);
  float*  sb1  = (float*)(W + 12211200);
  float*  sc2  = (float*)(W + 12212224);
  float*  sb2  = (float*)(W + 12213248);
  float*  sc3  = (float*)(W + 12214272);
  float*  sb3  = (float*)(W + 12215296);
  const size_t FIXED_END = 16777216;

  // ---- pick batch chunk Bc so workspace fits ws_size ----
  const size_t PER_B = 17385472;
  int Bc = 32;
  while (Bc > 1 && FIXED_END + (size_t)Bc * PER_B > ws_size) Bc >>= 1;

  char* P = W + FIXED_END;
  float*  h     = (float*)P;
  bf16_t* xa    = (bf16_t*)(P + (size_t)Bc * 4194304);
  bf16_t* ao    = xa;  // xa dead after fused qkv gemm; ao dead before ln2
  char*   big   = P + (size_t)Bc * (4194304 + 2097152);
  bf16_t* qpkpv = (bf16_t*)big;
  bf16_t* f1    = (bf16_t*)big;                               // after qpkpv dead
  bf16_t* h1p   = (bf16_t*)big;                               // pre-loop
  bf16_t* hpad  = (bf16_t*)big;                               // post-loop
  bf16_t* hdp   = (bf16_t*)(big + (size_t)Bc * 4100 * 256 * 2);
  float*  pkv   = (float*)(big + (size_t)Bc * 10485760);
  float*  pks   = (float*)((char*)pkv + (size_t)Bc * 524288);

  // ---- weight prep (once) ----
  prep_weff<<<5120, 256, 0, stream>>>(wq, wk, wv, bq, bk, bv, rf, weff, beff);
  prep_cast_t<<<1024, 256, 0, stream>>>(wo, wot, 256, 256);
  prep_cast_t<<<4096, 256, 0, stream>>>(ff_w1, w1t, 256, 1024);
  prep_cast_t<<<4096, 256, 0, stream>>>(ff_w2, w2t, 1024, 256);
  prep_conv_t<<<640, 256, 0, stream>>>(emb_w2, c2t, 128, 5);
  prep_conv_t<<<640, 256, 0, stream>>>(dec_w1, d1t, 256, 5);
  prep_bn<<<1, 256, 0, stream>>>(bn1_g, bn1_b, emb_b1, bn2_g, bn2_b, emb_b2,
                                 bn3_g, bn3_b, dec_b1, sc1, sb1, sc2, sb2, sc3, sb3);
  pe_fill<<<4096, 256, 0, stream>>>(pe);

  for (int c0 = 0; c0 < 32; c0 += Bc) {
    const float* xc = x + (size_t)c0 * 4096;

    // ---- embedding ----
    hipMemsetAsync(h1p, 0, (size_t)Bc * 4100 * 128 * 2, stream);
    conv1_kernel<<<Bc * 64, 256, 0, stream>>>(xc, emb_w1, sc1, sb1, h1p);
    gemm_bf16<3, 640, 64, 4><<<Bc * 128, 256, 0, stream>>>(
        h1p, c2t, h, sb2, sc2, nullptr, pe,
        128, 4100L * 128, 4096, 256, 256, 4096L * 256, 0);

    // ---- transformer layers ----
    for (int l = 0; l < 4; l++) {
      ln_kernel<<<Bc * 1024, 256, 0, stream>>>(h, ln1_g + l * 256, ln1_b + l * 256, xa);
      gemm_bf16<5, 256, 128, 10><<<Bc * 320, 256, 0, stream>>>(
          xa, weff + (long)l * 327680, qpkpv, beff + l * 1280, nullptr, nullptr, nullptr,
          256, 4096L * 256, 4096, 1280, 1280, 4096L * 1280, 0);
      kv_partial<<<Bc * 64, 256, 0, stream>>>(qpkpv, pkv, pks);
      combine_mfma<<<Bc * 256, 256, 0, stream>>>(qpkpv, pkv, pks, ao);
      gemm_bf16<1, 256, 64, 4><<<Bc * 128, 256, 0, stream>>>(
          ao, wot + (long)l * 65536, h, bo + l * 256, nullptr, h, nullptr,
          256, 4096L * 256, 4096, 256, 256, 4096L * 256, 0);
      ln_kernel<<<Bc * 1024, 256, 0, stream>>>(h, ln2_g + l * 256, ln2_b + l * 256, xa);
      gemm_bf16<2, 256, 128, 8><<<Bc * 256, 256, 0, stream>>>(
          xa, w1t + (long)l * 262144, f1, ff_b1 + l * 1024, nullptr, nullptr, nullptr,
          256, 4096L * 256, 4096, 1024, 1024, 4096L * 1024, 0);
      gemm_bf16<1, 1024, 64, 4><<<Bc * 128, 256, 0, stream>>>(
          f1, w2t + (long)l * 262144, h, ff_b2 + l * 256, nullptr, h, nullptr,
          1024, 4096L * 1024, 4096, 256, 256, 4096L * 256, 0);
    }

    // ---- decoder ----
    hipMemsetAsync(hpad, 0, (size_t)Bc * 4100 * 256 * 2, stream);
    cast_pad<<<Bc * 512, 256, 0, stream>>>(h, hpad);
    hipMemsetAsync(hdp, 0, (size_t)Bc * 4098 * 128 * 2, stream);
    gemm_bf16<4, 1280, 64, 2><<<Bc * 64, 256, 0, stream>>>(
        hpad, d1t, hdp, sb3, sc3, nullptr, nullptr,
        256, 4100L * 256, 4096, 128, 128, 4098L * 128, 1);
    conv_final<<<Bc * 16, 256, 0, stream>>>(hdp, dec_w2, dec_b2,
                                            (float*)d_out + (size_t)c0 * 4096);
  }
}

// Round 16
// 4212.695 us; speedup vs baseline: 1.4468x; 1.0031x over previous
//
#include <hip/hip_runtime.h>
#include <hip/hip_bf16.h>
#include <math.h>

// ============================================================================
// PPGPeakPerformer forward on MI355X (gfx950)
// B=32 S=4096 D=256 DH=128 H=8 HD=32 F=64 L=4
// r16 = exact revert to r13 (best passing config, 4226us):
// GEMM: 128xBN tile (BN=128 wide, BN=64 narrow), BK=32. A-panel TRIPLE-
// buffered depth-2 with counted vmcnt(2); B double-buffered depth-1.
// LDS 40KB -> 4 blocks/CU, VGPR 64 (launch_bounds(256,4)).
// 1D grid + bijective XCD chunk-remap (n fastest) on GEMMs AND ln_kernel.
// Swizzle slot^((row>>1)&3) both-sides. Fast rational erf. Fused q/k RF
// projection GEMM. kv_reduce folded into combine_mfma. Separate LN pass
// (LN-GEMM fusion refuted in r14/r15: rounding re-order pushes absmax
// 0.0156 -> 0.0234 > 0.02 threshold).
// ============================================================================

typedef __bf16 bf16_t;
typedef __bf16 bf16x8 __attribute__((ext_vector_type(8)));
typedef __bf16 bf16x4 __attribute__((ext_vector_type(4)));
typedef float  f32x4  __attribute__((ext_vector_type(4)));

#define DEV __device__ __forceinline__

DEV float erf_fast(float x) {
  float ax = fabsf(x);
  float t = __builtin_amdgcn_rcpf(1.f + 0.3275911f * ax);
  float p = t * (0.254829592f + t * (-0.284496736f + t * (1.421413741f +
            t * (-1.453152027f + t * 1.061405429f))));
  float r = 1.f - p * __expf(-ax * ax);
  return copysignf(r, x);
}
DEV float geluf(float v) { return 0.5f * v * (1.f + erf_fast(v * 0.70710678118654752440f)); }
DEV float softplusf(float v) {
  float e = __expf(-fabsf(v));
  return fmaxf(v, 0.f) + __logf(1.f + e);
}

// Direct global->LDS 16B staging. LDS dest is wave-uniform base + lane*16.
DEV void gload16(const bf16_t* g, bf16_t* l) {
  __builtin_amdgcn_global_load_lds(
      (const __attribute__((address_space(1))) void*)g,
      (__attribute__((address_space(3))) void*)l, 16, 0, 0);
}

// ---------------------------------------------------------------------------
// GEMM: C[m,n] = sum_k A[m,k]*Bt[n,k].  A bf16 (batched rows), Bt bf16 [N][K].
// EPI: 1 = +bias +resid -> fp32; 2 = gelu(+bias) -> bf16;
//      3 = gelu(scale*x+bias)+pe -> fp32; 4 = gelu(scale*x+bias) -> bf16;
//      5 = col<1024 ? softplus(+bias) : (+bias) -> bf16
// Pipeline per iter t:
//   wait vmcnt(2)   // drains A(t),B(t); leaves A(t+1) [+A(t+2) next iters]
//   s_barrier       // LDS buffer recycle safety
//   stage B(t+1) -> Bs[(t+1)&1]
//   stage A(t+2) -> As[(t+2)%3]
//   ds_read As[t%3]/Bs[t&1]; MFMA.
// A slack ~2 iters (HBM-ok), B slack ~1 iter (L2-ok).
// ---------------------------------------------------------------------------
template <int EPI, int K, int BN, int NTL>
__global__ __launch_bounds__(256, 4)
void gemm_bf16(const bf16_t* __restrict__ A, const bf16_t* __restrict__ Bt,
               void* Cout, const float* __restrict__ bias,
               const float* __restrict__ scale, const float* resid,
               const float* __restrict__ pe,
               int lda, long a_bstride, int rpb,
               int N, int ldc, long c_bstride, int c_roff)
{
  constexpr int MI = (BN == 128) ? 4 : 2;   // row-fragments per wave
  __shared__ bf16_t As[3][128 * 32];
  __shared__ bf16_t Bs[2][BN * 32];
  const int t = threadIdx.x;
  const int lane = t & 63;
  const int w = t >> 6;
  const int wrow = (BN == 128) ? (w >> 1) * 64 : w * 32;
  const int wcol = (BN == 128) ? (w & 1) * 64 : 0;

  // XCD-aware bijective remap (m204): bid%8 -> XCD; XCD k gets a contiguous
  // wgid chunk (n-tile fastest) so A-tile sharers co-reside on one L2.
  const int nwg = gridDim.x;
  const int q_ = nwg >> 3, r_ = nwg & 7;
  const int xcd = blockIdx.x & 7, idx_ = blockIdx.x >> 3;
  const int wgid = (xcd < r_ ? xcd * (q_ + 1) : r_ * (q_ + 1) + (xcd - r_) * q_) + idx_;
  const long m0 = (long)(wgid / NTL) * 128;
  const int n0 = (wgid % NTL) * BN;

  const int b = (int)(m0 / rpb);
  const int s_base = (int)(m0 % rpb);
  const bf16_t* Ab = A + (long)b * a_bstride + (long)s_base * lda;
  const bf16_t* Bb = Bt + (long)n0 * K;

  // staging source (pre-swizzled): lane covers row (lane>>2) of a 16-row
  // block, 16B slot ((lane&3) ^ ((row>>1)&3)).
  const int srow = lane >> 2;
  const int sslot = (lane & 3) ^ ((srow >> 1) & 3);
  const bf16_t* aS = Ab + (long)(w * 32 + srow) * lda + sslot * 8;
  const bf16_t* bS = Bb + (long)(w * 32 + srow) * K + sslot * 8;
  const int dsto = w * 1024;  // 32 rows x 32 elems per wave

#define STAGE_A(bufidx, kk)                                 \
  {                                                         \
    bf16_t* a_ = &As[bufidx][dsto];                         \
    gload16(aS + (kk), a_);                                 \
    gload16(aS + (kk) + 16 * (long)lda, a_ + 512);          \
  }
#define STAGE_B(bufidx, kk)                                 \
  if (BN == 128 || w < 2) {                                 \
    bf16_t* b_ = &Bs[bufidx][dsto];                         \
    gload16(bS + (kk), b_);                                 \
    gload16(bS + (kk) + 16 * (long)K, b_ + 512);            \
  }

  f32x4 acc[MI][4];
#pragma unroll
  for (int i = 0; i < MI; i++)
#pragma unroll
    for (int j = 0; j < 4; j++) acc[i][j] = (f32x4){0.f, 0.f, 0.f, 0.f};

  constexpr int NT = K >> 5;
  // prologue queue order: A(0), B(0), A(1) -> wait vmcnt(2) drains A0,B0.
  STAGE_A(0, 0);
  STAGE_B(0, 0);
  if (NT > 1) STAGE_A(1, 32);

#pragma unroll
  for (int tt = 0; tt < NT; ++tt) {
    if (tt + 1 < NT) {
      asm volatile("s_waitcnt vmcnt(2)" ::: "memory");
    } else {
      asm volatile("s_waitcnt vmcnt(0)" ::: "memory");
    }
    __builtin_amdgcn_s_barrier();
    __builtin_amdgcn_sched_barrier(0);
    if (tt + 1 < NT) STAGE_B((tt + 1) & 1, (tt + 1) * 32);
    if (tt + 2 < NT) STAGE_A((tt + 2) % 3, (tt + 2) * 32);
    const bf16_t* Acur = As[tt % 3];
    const bf16_t* Bcur = Bs[tt & 1];
    const int kb = (lane >> 4) * 16;
    bf16x8 af[MI], bfr[4];
#pragma unroll
    for (int i = 0; i < MI; i++) {
      int rA = wrow + i * 16 + (lane & 15);
      af[i] = *(const bf16x8*)((const char*)Acur + rA * 64 + (kb ^ (((rA >> 1) & 3) << 4)));
    }
#pragma unroll
    for (int j = 0; j < 4; j++) {
      int rB = wcol + j * 16 + (lane & 15);
      bfr[j] = *(const bf16x8*)((const char*)Bcur + rB * 64 + (kb ^ (((rB >> 1) & 3) << 4)));
    }
    __builtin_amdgcn_s_setprio(1);
#pragma unroll
    for (int mi = 0; mi < MI; mi++)
#pragma unroll
      for (int ni = 0; ni < 4; ni++)
        acc[mi][ni] = __builtin_amdgcn_mfma_f32_16x16x32_bf16(af[mi], bfr[ni], acc[mi][ni], 0, 0, 0);
    __builtin_amdgcn_s_setprio(0);
  }
#undef STAGE_A
#undef STAGE_B

  const int colbase = n0 + wcol + (lane & 15);
  float bias_r[4], scale_r[4];
#pragma unroll
  for (int ni = 0; ni < 4; ni++) {
    int col = colbase + ni * 16;
    bias_r[ni] = bias[col];
    scale_r[ni] = (EPI == 3 || EPI == 4) ? scale[col] : 0.f;
  }
#pragma unroll
  for (int mi = 0; mi < MI; mi++) {
#pragma unroll
    for (int j = 0; j < 4; j++) {
      int row = wrow + mi * 16 + ((lane >> 4) << 2) + j;
      long s = s_base + row;
      long cro = (long)b * c_bstride + (s + c_roff) * (long)ldc;
#pragma unroll
      for (int ni = 0; ni < 4; ni++) {
        int col = colbase + ni * 16;
        float v = acc[mi][ni][j];
        if constexpr (EPI == 1) {
          v += bias_r[ni] + resid[cro + col];
          ((float*)Cout)[cro + col] = v;
        } else if constexpr (EPI == 2) {
          v = geluf(v + bias_r[ni]);
          ((bf16_t*)Cout)[cro + col] = (bf16_t)v;
        } else if constexpr (EPI == 3) {
          v = geluf(v * scale_r[ni] + bias_r[ni]) + pe[s * 256 + col];
          ((float*)Cout)[cro + col] = v;
        } else if constexpr (EPI == 4) {
          v = geluf(v * scale_r[ni] + bias_r[ni]);
          ((bf16_t*)Cout)[cro + col] = (bf16_t)v;
        } else {  // 5
          v += bias_r[ni];
          if (col < 1024) v = softplusf(v);
          ((bf16_t*)Cout)[cro + col] = (bf16_t)v;
        }
      }
    }
  }
}

// ---------------------------------------------------------------------------
// LayerNorm over D=256, fp32 in -> bf16 out. 4 rows/block (1 wave per row).
// XCD chunk-remap matches the GEMM m-tile map: XCD k owns contiguous rows.
// ---------------------------------------------------------------------------
__global__ __launch_bounds__(256)
void ln_kernel(const float* __restrict__ h, const float* __restrict__ g,
               const float* __restrict__ bta, bf16_t* __restrict__ out)
{
  int t = threadIdx.x;
  int lane = t & 63;
  const int G = gridDim.x;                 // divisible by 8
  const int wgid = (blockIdx.x & 7) * (G >> 3) + (blockIdx.x >> 3);
  long row = (long)wgid * 4 + (t >> 6);
  const float* hp = h + row * 256 + lane * 4;
  float4 v = *(const float4*)hp;
  float s = v.x + v.y + v.z + v.w;
  float q = v.x * v.x + v.y * v.y + v.z * v.z + v.w * v.w;
#pragma unroll
  for (int m = 32; m >= 1; m >>= 1) {
    s += __shfl_xor(s, m);
    q += __shfl_xor(q, m);
  }
  float mean = s * 0.00390625f;
  float var = q * 0.00390625f - mean * mean;
  float rstd = rsqrtf(var + 1e-5f);
  int c = lane * 4;
  float4 gv = *(const float4*)(g + c);
  float4 bv = *(const float4*)(bta + c);
  bf16x4 o;
  o[0] = (bf16_t)((v.x - mean) * rstd * gv.x + bv.x);
  o[1] = (bf16_t)((v.y - mean) * rstd * gv.y + bv.y);
  o[2] = (bf16_t)((v.z - mean) * rstd * gv.z + bv.z);
  o[3] = (bf16_t)((v.w - mean) * rstd * gv.w + bv.w);
  *(bf16x4*)(out + row * 256 + c) = o;
}

// ---------------------------------------------------------------------------
// Embedding conv1: x[Bc,S] -> gelu(bn(conv1d k=7 pad=3)) -> h1p[Bc,S+4,128]
// ---------------------------------------------------------------------------
__global__ __launch_bounds__(256)
void conv1_kernel(const float* __restrict__ x, const float* __restrict__ w1,
                  const float* __restrict__ sc, const float* __restrict__ sb,
                  bf16_t* __restrict__ h1p)
{
  int b = blockIdx.x >> 6;
  int s0 = (blockIdx.x & 63) << 6;
  __shared__ float xs[70];
  __shared__ float ws[896];
  int t = threadIdx.x;
  if (t < 70) {
    int s = s0 + t - 3;
    xs[t] = (s >= 0 && s < 4096) ? x[(long)b * 4096 + s] : 0.f;
  }
  for (int i = t; i < 896; i += 256) ws[i] = w1[i];
  __syncthreads();
  int c = t & 127, so = t >> 7;
  float wr[7];
#pragma unroll
  for (int k = 0; k < 7; k++) wr[k] = ws[c * 7 + k];
  float scl = sc[c], sbv = sb[c];
  for (int p = 0; p < 32; p++) {
    int sl = p * 2 + so;
    float a = 0.f;
#pragma unroll
    for (int k = 0; k < 7; k++) a += xs[sl + k] * wr[k];
    a = geluf(a * scl + sbv);
    h1p[((long)b * 4100 + s0 + sl + 2) * 128 + c] = (bf16_t)a;
  }
}

// ---------------------------------------------------------------------------
// kv partial: per (b,h,chunk of 512 s): acc[f][d] += kp[s,f]*v[s,d]; +ksum.
// ---------------------------------------------------------------------------
__global__ __launch_bounds__(256)
void kv_partial(const bf16_t* __restrict__ qpkpv,
                float* __restrict__ pkv, float* __restrict__ pks)
{
  int bh = blockIdx.x >> 3, ch = blockIdx.x & 7;
  int b = bh >> 3, hh = bh & 7;
  int s0 = ch * 512;
  __shared__ float kps[32 * 64];
  __shared__ float vs[32 * 32];
  int t = threadIdx.x;
  int f = t & 63, dg = t >> 6;
  float acc[8] = {0.f, 0.f, 0.f, 0.f, 0.f, 0.f, 0.f, 0.f};
  float ks = 0.f;
  const int row = t >> 3, slot8 = (t & 7) * 8, slot4 = (t & 7) * 4;
  for (int sb = 0; sb < 512; sb += 32) {
    __syncthreads();
    {
      const bf16_t* rowp = qpkpv + ((long)b * 4096 + s0 + sb + row) * 1280;
      bf16x8 k8 = *(const bf16x8*)(rowp + 512 + hh * 64 + slot8);
#pragma unroll
      for (int j = 0; j < 8; j++) kps[row * 64 + slot8 + j] = (float)k8[j];
      bf16x4 v4 = *(const bf16x4*)(rowp + 1024 + hh * 32 + slot4);
#pragma unroll
      for (int j = 0; j < 4; j++) vs[row * 32 + slot4 + j] = (float)v4[j];
    }
    __syncthreads();
#pragma unroll 4
    for (int s = 0; s < 32; s++) {
      float kval = kps[s * 64 + f];
      float4 v0 = *(const float4*)&vs[s * 32 + dg * 8];
      float4 v1 = *(const float4*)&vs[s * 32 + dg * 8 + 4];
      acc[0] += kval * v0.x; acc[1] += kval * v0.y;
      acc[2] += kval * v0.z; acc[3] += kval * v0.w;
      acc[4] += kval * v1.x; acc[5] += kval * v1.y;
      acc[6] += kval * v1.z; acc[7] += kval * v1.w;
      ks += kval;
    }
  }
  long o = (long)blockIdx.x * 2048 + f * 32 + dg * 8;
#pragma unroll
  for (int j = 0; j < 8; j++) pkv[o + j] = acc[j];
  if (dg == 0) pks[blockIdx.x * 64 + f] = ks;
}

// ---------------------------------------------------------------------------
// combine: ao[s, h*32+d] = (qp[s,:] @ kv[:,d]) / (qp[s,:]@ksum + 1e-8)
// kv/ksum reduced from 8 chunk-partials inline (deterministic order).
// ---------------------------------------------------------------------------
__global__ __launch_bounds__(256, 2)
void combine_mfma(const bf16_t* __restrict__ qpkpv, const float* __restrict__ pkv,
                  const float* __restrict__ pks, bf16_t* __restrict__ ao)
{
  int bh = blockIdx.x >> 5;
  int s0 = (blockIdx.x & 31) << 7;
  int b = bh >> 3, hh = bh & 7;
  __shared__ bf16_t A_s[128 * 72];
  __shared__ bf16_t B_s[48 * 72];
  int t = threadIdx.x;
  for (int g = t; g < 1024; g += 256) {
    int row = g >> 3, slot = (g & 7) * 8;
    *(bf16x8*)&A_s[row * 72 + slot] =
        *(const bf16x8*)(qpkpv + ((long)b * 4096 + s0 + row) * 1280 + hh * 64 + slot);
  }
  for (int i = t; i < 2048; i += 256) {
    float s = 0.f;
#pragma unroll
    for (int ch = 0; ch < 8; ch++) s += pkv[((long)(bh * 8 + ch)) * 2048 + i];
    int f = i >> 5, d = i & 31;
    B_s[d * 72 + f] = (bf16_t)s;
  }
  if (t < 64) {
    float s = 0.f;
#pragma unroll
    for (int ch = 0; ch < 8; ch++) s += pks[(bh * 8 + ch) * 64 + t];
    B_s[32 * 72 + t] = (bf16_t)s;
  }
  for (int i = t; i < 960; i += 256) {
    int n = 33 + (i >> 6), f = i & 63;
    B_s[n * 72 + f] = (bf16_t)0.f;
  }
  __syncthreads();
  int lane = t & 63, w = t >> 6;
  f32x4 acc[2][3];
#pragma unroll
  for (int i = 0; i < 2; i++)
#pragma unroll
    for (int j = 0; j < 3; j++) acc[i][j] = (f32x4){0.f, 0.f, 0.f, 0.f};
#pragma unroll
  for (int kt = 0; kt < 2; kt++) {
    int ko = kt * 32 + (lane >> 4) * 8;
    bf16x8 a[2], bb[3];
#pragma unroll
    for (int i = 0; i < 2; i++)
      a[i] = *(const bf16x8*)&A_s[(w * 32 + i * 16 + (lane & 15)) * 72 + ko];
#pragma unroll
    for (int i = 0; i < 3; i++)
      bb[i] = *(const bf16x8*)&B_s[(i * 16 + (lane & 15)) * 72 + ko];
#pragma unroll
    for (int mi = 0; mi < 2; mi++)
#pragma unroll
      for (int ni = 0; ni < 3; ni++)
        acc[mi][ni] = __builtin_amdgcn_mfma_f32_16x16x32_bf16(a[mi], bb[ni], acc[mi][ni], 0, 0, 0);
  }
  long sbase = (long)b * 4096 + s0;
#pragma unroll
  for (int mi = 0; mi < 2; mi++)
#pragma unroll
    for (int j = 0; j < 4; j++) {
      int r = w * 32 + mi * 16 + ((lane >> 4) << 2) + j;
      float den = __shfl(acc[mi][2][j], (lane & 48)) + 1e-8f;
#pragma unroll
      for (int ni = 0; ni < 2; ni++) {
        int d = ni * 16 + (lane & 15);
        ao[(sbase + r) * 256 + hh * 32 + d] = (bf16_t)(acc[mi][ni][j] / den);
      }
    }
}

// ---------------------------------------------------------------------------
// h fp32 -> h_padded bf16 [Bc, S+4, 256] (rows offset +2)
// ---------------------------------------------------------------------------
__global__ __launch_bounds__(256)
void cast_pad(const float* __restrict__ h, bf16_t* __restrict__ hp)
{
  long i8 = ((long)blockIdx.x * 256 + threadIdx.x) * 8;
  long r = i8 >> 8;
  int c = (int)(i8 & 255);
  int b = (int)(r >> 12), s = (int)(r & 4095);
  float4 v0 = *(const float4*)(h + i8);
  float4 v1 = *(const float4*)(h + i8 + 4);
  bf16x8 o;
  o[0] = (bf16_t)v0.x; o[1] = (bf16_t)v0.y; o[2] = (bf16_t)v0.z; o[3] = (bf16_t)v0.w;
  o[4] = (bf16_t)v1.x; o[5] = (bf16_t)v1.y; o[6] = (bf16_t)v1.z; o[7] = (bf16_t)v1.w;
  *(bf16x8*)(hp + ((long)b * 4100 + s + 2) * 256 + c) = o;
}

// ---------------------------------------------------------------------------
// Final conv (DH->1, k=3, pad=1) + sigmoid -> out [Bc,S] fp32
// ---------------------------------------------------------------------------
__global__ __launch_bounds__(256)
void conv_final(const bf16_t* __restrict__ hdp, const float* __restrict__ w2,
                const float* __restrict__ b2, float* __restrict__ out)
{
  __shared__ float ws[384];
  int t = threadIdx.x;
  for (int i = t; i < 384; i += 256) ws[i] = w2[i];  // [c][k]
  __syncthreads();
  long idx = (long)blockIdx.x * 256 + t;
  int b = (int)(idx >> 12);
  const bf16_t* base = hdp + ((long)b * 4098 + (idx & 4095)) * 128;
  float a = b2[0];
#pragma unroll
  for (int k = 0; k < 3; k++) {
#pragma unroll
    for (int c8 = 0; c8 < 16; c8++) {
      bf16x8 v = *(const bf16x8*)(base + k * 128 + c8 * 8);
#pragma unroll
      for (int j = 0; j < 8; j++) a += (float)v[j] * ws[(c8 * 8 + j) * 3 + k];
    }
  }
  out[idx] = 1.f / (1.f + __expf(-a));
}

// ---------------------------------------------------------------------------
// Prep kernels (once per launch)
// ---------------------------------------------------------------------------
__global__ __launch_bounds__(256)
void prep_weff(const float* __restrict__ wq, const float* __restrict__ wk,
               const float* __restrict__ wv, const float* __restrict__ bq,
               const float* __restrict__ bk, const float* __restrict__ bv,
               const float* __restrict__ rf, bf16_t* __restrict__ weff,
               float* __restrict__ beff)
{
  long idx = (long)blockIdx.x * 256 + threadIdx.x;  // 4*1280*256
  int d = (int)(idx & 255);
  long r = idx >> 8;
  int n = (int)(r % 1280);
  int l = (int)(r / 1280);
  float val;
  if (n < 1024) {
    int qk = n >> 9;
    int h = (n >> 6) & 7;
    int f = n & 63;
    const float* w = qk ? wk : wq;
    const float* rfh = rf + ((long)(l * 8 + h) * 32) * 64 + f;
    const float* wrow = w + ((long)l * 256 + d) * 256 + h * 32;
    float s = 0.f;
#pragma unroll
    for (int hd = 0; hd < 32; hd++) s += wrow[hd] * rfh[hd * 64];
    val = s;
  } else {
    val = wv[((long)l * 256 + d) * 256 + (n - 1024)];
  }
  weff[idx] = (bf16_t)val;
  if (idx < 4 * 1280) {
    int nn = (int)(idx % 1280);
    int ll = (int)(idx / 1280);
    float bvv;
    if (nn < 1024) {
      int qk = nn >> 9;
      int h = (nn >> 6) & 7;
      int f = nn & 63;
      const float* bsrc = qk ? bk : bq;
      float s = 0.f;
      for (int hd = 0; hd < 32; hd++)
        s += bsrc[ll * 256 + h * 32 + hd] * rf[((long)(ll * 8 + h) * 32 + hd) * 64 + f];
      bvv = s;
    } else {
      bvv = bv[ll * 256 + (nn - 1024)];
    }
    beff[idx] = bvv;
  }
}

__global__ __launch_bounds__(256)
void prep_cast_t(const float* __restrict__ src, bf16_t* __restrict__ dst, int K, int N)
{
  long idx = (long)blockIdx.x * 256 + threadIdx.x;  // nmats*N*K
  int k = (int)(idx % K);
  long r = idx / K;
  int n = (int)(r % N);
  int l = (int)(r / N);
  dst[idx] = (bf16_t)src[((long)l * K + k) * N + n];
}

__global__ __launch_bounds__(256)
void prep_conv_t(const float* __restrict__ w, bf16_t* __restrict__ dst, int C, int KW)
{
  long idx = (long)blockIdx.x * 256 + threadIdx.x;  // O*C*KW
  int ckw = C * KW;
  int kk = (int)(idx % ckw);
  int o = (int)(idx / ckw);
  int kw = kk / C, c = kk % C;
  dst[idx] = (bf16_t)w[((long)o * C + c) * KW + kw];
}

__global__ __launch_bounds__(256)
void prep_bn(const float* g1, const float* b1, const float* cb1,
             const float* g2, const float* b2, const float* cb2,
             const float* g3, const float* b3, const float* cb3,
             float* sc1, float* sb1, float* sc2, float* sb2,
             float* sc3, float* sb3)
{
  int t = threadIdx.x;
  const float r = rsqrtf(1.f + 1e-5f);
  if (t < 128) { float s = g1[t] * r; sc1[t] = s; sb1[t] = cb1[t] * s + b1[t]; }
  if (t < 256) { float s = g2[t] * r; sc2[t] = s; sb2[t] = cb2[t] * s + b2[t]; }
  if (t < 128) { float s = g3[t] * r; sc3[t] = s; sb3[t] = cb3[t] * s + b3[t]; }
}

__global__ __launch_bounds__(256)
void pe_fill(float* __restrict__ pe)
{
  long idx = (long)blockIdx.x * 256 + threadIdx.x;  // 4096*256
  int dcol = (int)(idx & 255);
  int s = (int)(idx >> 8);
  int i2 = dcol >> 1;
  float freq = expf(-9.210340371976184f * (float)(2 * i2) / 256.f);
  float a = (float)s * freq;
  pe[idx] = (dcol & 1) ? cosf(a) : sinf(a);
}

// ---------------------------------------------------------------------------
extern "C" void kernel_launch(void* const* d_in, const int* in_sizes, int n_in,
                              void* d_out, int out_size, void* d_ws, size_t ws_size,
                              hipStream_t stream)
{
  (void)in_sizes; (void)n_in; (void)out_size;
  const float* x      = (const float*)d_in[0];
  const float* emb_w1 = (const float*)d_in[1];
  const float* emb_b1 = (const float*)d_in[2];
  const float* bn1_g  = (const float*)d_in[3];
  const float* bn1_b  = (const float*)d_in[4];
  const float* emb_w2 = (const float*)d_in[5];
  const float* emb_b2 = (const float*)d_in[6];
  const float* bn2_g  = (const float*)d_in[7];
  const float* bn2_b  = (const float*)d_in[8];
  const float* wq     = (const float*)d_in[9];
  const float* bq     = (const float*)d_in[10];
  const float* wk     = (const float*)d_in[11];
  const float* bk     = (const float*)d_in[12];
  const float* wv     = (const float*)d_in[13];
  const float* bv     = (const float*)d_in[14];
  const float* wo     = (const float*)d_in[15];
  const float* bo     = (const float*)d_in[16];
  const float* rf     = (const float*)d_in[17];
  const float* ln1_g  = (const float*)d_in[18];
  const float* ln1_b  = (const float*)d_in[19];
  const float* ln2_g  = (const float*)d_in[20];
  const float* ln2_b  = (const float*)d_in[21];
  const float* ff_w1  = (const float*)d_in[22];
  const float* ff_b1  = (const float*)d_in[23];
  const float* ff_w2  = (const float*)d_in[24];
  const float* ff_b2  = (const float*)d_in[25];
  const float* dec_w1 = (const float*)d_in[26];
  const float* dec_b1 = (const float*)d_in[27];
  const float* bn3_g  = (const float*)d_in[28];
  const float* bn3_b  = (const float*)d_in[29];
  const float* dec_w2 = (const float*)d_in[30];
  const float* dec_b2 = (const float*)d_in[31];

  char* W = (char*)d_ws;

  // ---- fixed region (weights, ~12.2 MB; reserve 16 MB) ----
  bf16_t* weff = (bf16_t*)(W + 0);                     // 4*1280*256*2 = 2,621,440
  float*  beff = (float*)(W + 2621440);                // 20,480
  bf16_t* wot  = (bf16_t*)(W + 2641920);               // 524,288
  bf16_t* w1t  = (bf16_t*)(W + 3166208);               // 2,097,152
  bf16_t* w2t  = (bf16_t*)(W + 5263360);               // 2,097,152
  bf16_t* c2t  = (bf16_t*)(W + 7360512);               // 327,680
  bf16_t* d1t  = (bf16_t*)(W + 7688192);               // 327,680
  float*  pe   = (float*)(W + 8015872);                // 4,194,304
  float*  sc1  = (float*)(W + 12210176);
  float*  sb1  = (float*)(W + 12211200);
  float*  sc2  = (float*)(W + 12212224);
  float*  sb2  = (float*)(W + 12213248);
  float*  sc3  = (float*)(W + 12214272);
  float*  sb3  = (float*)(W + 12215296);
  const size_t FIXED_END = 16777216;

  // ---- pick batch chunk Bc so workspace fits ws_size ----
  const size_t PER_B = 17385472;
  int Bc = 32;
  while (Bc > 1 && FIXED_END + (size_t)Bc * PER_B > ws_size) Bc >>= 1;

  char* P = W + FIXED_END;
  float*  h     = (float*)P;
  bf16_t* xa    = (bf16_t*)(P + (size_t)Bc * 4194304);
  bf16_t* ao    = xa;  // xa dead after fused qkv gemm; ao dead before ln2
  char*   big   = P + (size_t)Bc * (4194304 + 2097152);
  bf16_t* qpkpv = (bf16_t*)big;
  bf16_t* f1    = (bf16_t*)big;                               // after qpkpv dead
  bf16_t* h1p   = (bf16_t*)big;                               // pre-loop
  bf16_t* hpad  = (bf16_t*)big;                               // post-loop
  bf16_t* hdp   = (bf16_t*)(big + (size_t)Bc * 4100 * 256 * 2);
  float*  pkv   = (float*)(big + (size_t)Bc * 10485760);
  float*  pks   = (float*)((char*)pkv + (size_t)Bc * 524288);

  // ---- weight prep (once) ----
  prep_weff<<<5120, 256, 0, stream>>>(wq, wk, wv, bq, bk, bv, rf, weff, beff);
  prep_cast_t<<<1024, 256, 0, stream>>>(wo, wot, 256, 256);
  prep_cast_t<<<4096, 256, 0, stream>>>(ff_w1, w1t, 256, 1024);
  prep_cast_t<<<4096, 256, 0, stream>>>(ff_w2, w2t, 1024, 256);
  prep_conv_t<<<640, 256, 0, stream>>>(emb_w2, c2t, 128, 5);
  prep_conv_t<<<640, 256, 0, stream>>>(dec_w1, d1t, 256, 5);
  prep_bn<<<1, 256, 0, stream>>>(bn1_g, bn1_b, emb_b1, bn2_g, bn2_b, emb_b2,
                                 bn3_g, bn3_b, dec_b1, sc1, sb1, sc2, sb2, sc3, sb3);
  pe_fill<<<4096, 256, 0, stream>>>(pe);

  for (int c0 = 0; c0 < 32; c0 += Bc) {
    const float* xc = x + (size_t)c0 * 4096;

    // ---- embedding ----
    hipMemsetAsync(h1p, 0, (size_t)Bc * 4100 * 128 * 2, stream);
    conv1_kernel<<<Bc * 64, 256, 0, stream>>>(xc, emb_w1, sc1, sb1, h1p);
    gemm_bf16<3, 640, 64, 4><<<Bc * 128, 256, 0, stream>>>(
        h1p, c2t, h, sb2, sc2, nullptr, pe,
        128, 4100L * 128, 4096, 256, 256, 4096L * 256, 0);

    // ---- transformer layers ----
    for (int l = 0; l < 4; l++) {
      ln_kernel<<<Bc * 1024, 256, 0, stream>>>(h, ln1_g + l * 256, ln1_b + l * 256, xa);
      gemm_bf16<5, 256, 128, 10><<<Bc * 320, 256, 0, stream>>>(
          xa, weff + (long)l * 327680, qpkpv, beff + l * 1280, nullptr, nullptr, nullptr,
          256, 4096L * 256, 4096, 1280, 1280, 4096L * 1280, 0);
      kv_partial<<<Bc * 64, 256, 0, stream>>>(qpkpv, pkv, pks);
      combine_mfma<<<Bc * 256, 256, 0, stream>>>(qpkpv, pkv, pks, ao);
      gemm_bf16<1, 256, 64, 4><<<Bc * 128, 256, 0, stream>>>(
          ao, wot + (long)l * 65536, h, bo + l * 256, nullptr, h, nullptr,
          256, 4096L * 256, 4096, 256, 256, 4096L * 256, 0);
      ln_kernel<<<Bc * 1024, 256, 0, stream>>>(h, ln2_g + l * 256, ln2_b + l * 256, xa);
      gemm_bf16<2, 256, 128, 8><<<Bc * 256, 256, 0, stream>>>(
          xa, w1t + (long)l * 262144, f1, ff_b1 + l * 1024, nullptr, nullptr, nullptr,
          256, 4096L * 256, 4096, 1024, 1024, 4096L * 1024, 0);
      gemm_bf16<1, 1024, 64, 4><<<Bc * 128, 256, 0, stream>>>(
          f1, w2t + (long)l * 262144, h, ff_b2 + l * 256, nullptr, h, nullptr,
          1024, 4096L * 1024, 4096, 256, 256, 4096L * 256, 0);
    }

    // ---- decoder ----
    hipMemsetAsync(hpad, 0, (size_t)Bc * 4100 * 256 * 2, stream);
    cast_pad<<<Bc * 512, 256, 0, stream>>>(h, hpad);
    hipMemsetAsync(hdp, 0, (size_t)Bc * 4098 * 128 * 2, stream);
    gemm_bf16<4, 1280, 64, 2><<<Bc * 64, 256, 0, stream>>>(
        hpad, d1t, hdp, sb3, sc3, nullptr, nullptr,
        256, 4100L * 256, 4096, 128, 128, 4098L * 128, 1);
    conv_final<<<Bc * 16, 256, 0, stream>>>(hdp, dec_w2, dec_b2,
                                            (float*)d_out + (size_t)c0 * 4096);
  }
}

// Round 17
// 4146.794 us; speedup vs baseline: 1.4698x; 1.0159x over previous
//
#include <hip/hip_runtime.h>
#include <hip/hip_bf16.h>
#include <math.h>

// ============================================================================
// PPGPeakPerformer forward on MI355X (gfx950)
// B=32 S=4096 D=256 DH=128 H=8 HD=32 F=64 L=4
// r17 = r16/r13 base (best passing, 4213us) + low-risk overhead bundle:
//  - no memset dispatches: conv1 zeroes h1p pad rows; cast_pad zeroes
//    hpad/hdp pad rows (stream-ordered before their consumers)
//  - QKV epilogue softplus predicate made block-uniform ((n0+wcol)<1024)
//  - conv_final 4 lanes/output (shfl reduce), grid x4 -> full-GPU
// Core GEMM unchanged: 128xBN tile (BN=128 wide, BN=64 narrow), BK=32,
// A triple-buffer depth-2 + counted vmcnt(2), B double-buffer; 40KB LDS,
// 4 blocks/CU; bijective XCD chunk-remap on GEMMs and ln_kernel; swizzle
// slot^((row>>1)&3) both-sides; fast rational erf; fused q/k RF projection;
// kv_reduce folded into combine_mfma. LN stays a separate pass (fusion
// refuted numerically in r14/r15).
// ============================================================================

typedef __bf16 bf16_t;
typedef __bf16 bf16x8 __attribute__((ext_vector_type(8)));
typedef __bf16 bf16x4 __attribute__((ext_vector_type(4)));
typedef float  f32x4  __attribute__((ext_vector_type(4)));

#define DEV __device__ __forceinline__

DEV float erf_fast(float x) {
  float ax = fabsf(x);
  float t = __builtin_amdgcn_rcpf(1.f + 0.3275911f * ax);
  float p = t * (0.254829592f + t * (-0.284496736f + t * (1.421413741f +
            t * (-1.453152027f + t * 1.061405429f))));
  float r = 1.f - p * __expf(-ax * ax);
  return copysignf(r, x);
}
DEV float geluf(float v) { return 0.5f * v * (1.f + erf_fast(v * 0.70710678118654752440f)); }
DEV float softplusf(float v) {
  float e = __expf(-fabsf(v));
  return fmaxf(v, 0.f) + __logf(1.f + e);
}

// Direct global->LDS 16B staging. LDS dest is wave-uniform base + lane*16.
DEV void gload16(const bf16_t* g, bf16_t* l) {
  __builtin_amdgcn_global_load_lds(
      (const __attribute__((address_space(1))) void*)g,
      (__attribute__((address_space(3))) void*)l, 16, 0, 0);
}

// ---------------------------------------------------------------------------
// GEMM: C[m,n] = sum_k A[m,k]*Bt[n,k].  A bf16 (batched rows), Bt bf16 [N][K].
// EPI: 1 = +bias +resid -> fp32; 2 = gelu(+bias) -> bf16;
//      3 = gelu(scale*x+bias)+pe -> fp32; 4 = gelu(scale*x+bias) -> bf16;
//      5 = tile<1024 ? softplus(+bias) : (+bias) -> bf16 (block-uniform)
// Pipeline per iter t:
//   wait vmcnt(2); s_barrier; stage B(t+1); stage A(t+2); ds_read; MFMA.
// A slack ~2 iters (HBM-ok), B slack ~1 iter (L2-ok).
// ---------------------------------------------------------------------------
template <int EPI, int K, int BN, int NTL>
__global__ __launch_bounds__(256, 4)
void gemm_bf16(const bf16_t* __restrict__ A, const bf16_t* __restrict__ Bt,
               void* Cout, const float* __restrict__ bias,
               const float* __restrict__ scale, const float* resid,
               const float* __restrict__ pe,
               int lda, long a_bstride, int rpb,
               int N, int ldc, long c_bstride, int c_roff)
{
  constexpr int MI = (BN == 128) ? 4 : 2;   // row-fragments per wave
  __shared__ bf16_t As[3][128 * 32];
  __shared__ bf16_t Bs[2][BN * 32];
  const int t = threadIdx.x;
  const int lane = t & 63;
  const int w = t >> 6;
  const int wrow = (BN == 128) ? (w >> 1) * 64 : w * 32;
  const int wcol = (BN == 128) ? (w & 1) * 64 : 0;

  // XCD-aware bijective remap (m204): bid%8 -> XCD; XCD k gets a contiguous
  // wgid chunk (n-tile fastest) so A-tile sharers co-reside on one L2.
  const int nwg = gridDim.x;
  const int q_ = nwg >> 3, r_ = nwg & 7;
  const int xcd = blockIdx.x & 7, idx_ = blockIdx.x >> 3;
  const int wgid = (xcd < r_ ? xcd * (q_ + 1) : r_ * (q_ + 1) + (xcd - r_) * q_) + idx_;
  const long m0 = (long)(wgid / NTL) * 128;
  const int n0 = (wgid % NTL) * BN;

  const int b = (int)(m0 / rpb);
  const int s_base = (int)(m0 % rpb);
  const bf16_t* Ab = A + (long)b * a_bstride + (long)s_base * lda;
  const bf16_t* Bb = Bt + (long)n0 * K;

  // staging source (pre-swizzled): lane covers row (lane>>2) of a 16-row
  // block, 16B slot ((lane&3) ^ ((row>>1)&3)).
  const int srow = lane >> 2;
  const int sslot = (lane & 3) ^ ((srow >> 1) & 3);
  const bf16_t* aS = Ab + (long)(w * 32 + srow) * lda + sslot * 8;
  const bf16_t* bS = Bb + (long)(w * 32 + srow) * K + sslot * 8;
  const int dsto = w * 1024;  // 32 rows x 32 elems per wave

#define STAGE_A(bufidx, kk)                                 \
  {                                                         \
    bf16_t* a_ = &As[bufidx][dsto];                         \
    gload16(aS + (kk), a_);                                 \
    gload16(aS + (kk) + 16 * (long)lda, a_ + 512);          \
  }
#define STAGE_B(bufidx, kk)                                 \
  if (BN == 128 || w < 2) {                                 \
    bf16_t* b_ = &Bs[bufidx][dsto];                         \
    gload16(bS + (kk), b_);                                 \
    gload16(bS + (kk) + 16 * (long)K, b_ + 512);            \
  }

  f32x4 acc[MI][4];
#pragma unroll
  for (int i = 0; i < MI; i++)
#pragma unroll
    for (int j = 0; j < 4; j++) acc[i][j] = (f32x4){0.f, 0.f, 0.f, 0.f};

  constexpr int NT = K >> 5;
  // prologue queue order: A(0), B(0), A(1) -> wait vmcnt(2) drains A0,B0.
  STAGE_A(0, 0);
  STAGE_B(0, 0);
  if (NT > 1) STAGE_A(1, 32);

#pragma unroll
  for (int tt = 0; tt < NT; ++tt) {
    if (tt + 1 < NT) {
      asm volatile("s_waitcnt vmcnt(2)" ::: "memory");
    } else {
      asm volatile("s_waitcnt vmcnt(0)" ::: "memory");
    }
    __builtin_amdgcn_s_barrier();
    __builtin_amdgcn_sched_barrier(0);
    if (tt + 1 < NT) STAGE_B((tt + 1) & 1, (tt + 1) * 32);
    if (tt + 2 < NT) STAGE_A((tt + 2) % 3, (tt + 2) * 32);
    const bf16_t* Acur = As[tt % 3];
    const bf16_t* Bcur = Bs[tt & 1];
    const int kb = (lane >> 4) * 16;
    bf16x8 af[MI], bfr[4];
#pragma unroll
    for (int i = 0; i < MI; i++) {
      int rA = wrow + i * 16 + (lane & 15);
      af[i] = *(const bf16x8*)((const char*)Acur + rA * 64 + (kb ^ (((rA >> 1) & 3) << 4)));
    }
#pragma unroll
    for (int j = 0; j < 4; j++) {
      int rB = wcol + j * 16 + (lane & 15);
      bfr[j] = *(const bf16x8*)((const char*)Bcur + rB * 64 + (kb ^ (((rB >> 1) & 3) << 4)));
    }
    __builtin_amdgcn_s_setprio(1);
#pragma unroll
    for (int mi = 0; mi < MI; mi++)
#pragma unroll
      for (int ni = 0; ni < 4; ni++)
        acc[mi][ni] = __builtin_amdgcn_mfma_f32_16x16x32_bf16(af[mi], bfr[ni], acc[mi][ni], 0, 0, 0);
    __builtin_amdgcn_s_setprio(0);
  }
#undef STAGE_A
#undef STAGE_B

  const int colbase = n0 + wcol + (lane & 15);
  float bias_r[4], scale_r[4];
#pragma unroll
  for (int ni = 0; ni < 4; ni++) {
    int col = colbase + ni * 16;
    bias_r[ni] = bias[col];
    scale_r[ni] = (EPI == 3 || EPI == 4) ? scale[col] : 0.f;
  }
  // EPI 5: softplus applies to the whole 64-col warp-tile or none of it
  // (tile boundary at col 1024 is 64-aligned) -> wave-uniform branch.
  const bool spAll = (EPI == 5) && ((n0 + wcol) < 1024);
#pragma unroll
  for (int mi = 0; mi < MI; mi++) {
#pragma unroll
    for (int j = 0; j < 4; j++) {
      int row = wrow + mi * 16 + ((lane >> 4) << 2) + j;
      long s = s_base + row;
      long cro = (long)b * c_bstride + (s + c_roff) * (long)ldc;
#pragma unroll
      for (int ni = 0; ni < 4; ni++) {
        int col = colbase + ni * 16;
        float v = acc[mi][ni][j];
        if constexpr (EPI == 1) {
          v += bias_r[ni] + resid[cro + col];
          ((float*)Cout)[cro + col] = v;
        } else if constexpr (EPI == 2) {
          v = geluf(v + bias_r[ni]);
          ((bf16_t*)Cout)[cro + col] = (bf16_t)v;
        } else if constexpr (EPI == 3) {
          v = geluf(v * scale_r[ni] + bias_r[ni]) + pe[s * 256 + col];
          ((float*)Cout)[cro + col] = v;
        } else if constexpr (EPI == 4) {
          v = geluf(v * scale_r[ni] + bias_r[ni]);
          ((bf16_t*)Cout)[cro + col] = (bf16_t)v;
        } else {  // 5
          v += bias_r[ni];
          if (spAll) v = softplusf(v);
          ((bf16_t*)Cout)[cro + col] = (bf16_t)v;
        }
      }
    }
  }
}

// ---------------------------------------------------------------------------
// LayerNorm over D=256, fp32 in -> bf16 out. 4 rows/block (1 wave per row).
// XCD chunk-remap matches the GEMM m-tile map: XCD k owns contiguous rows.
// ---------------------------------------------------------------------------
__global__ __launch_bounds__(256)
void ln_kernel(const float* __restrict__ h, const float* __restrict__ g,
               const float* __restrict__ bta, bf16_t* __restrict__ out)
{
  int t = threadIdx.x;
  int lane = t & 63;
  const int G = gridDim.x;                 // divisible by 8
  const int wgid = (blockIdx.x & 7) * (G >> 3) + (blockIdx.x >> 3);
  long row = (long)wgid * 4 + (t >> 6);
  const float* hp = h + row * 256 + lane * 4;
  float4 v = *(const float4*)hp;
  float s = v.x + v.y + v.z + v.w;
  float q = v.x * v.x + v.y * v.y + v.z * v.z + v.w * v.w;
#pragma unroll
  for (int m = 32; m >= 1; m >>= 1) {
    s += __shfl_xor(s, m);
    q += __shfl_xor(q, m);
  }
  float mean = s * 0.00390625f;
  float var = q * 0.00390625f - mean * mean;
  float rstd = rsqrtf(var + 1e-5f);
  int c = lane * 4;
  float4 gv = *(const float4*)(g + c);
  float4 bv = *(const float4*)(bta + c);
  bf16x4 o;
  o[0] = (bf16_t)((v.x - mean) * rstd * gv.x + bv.x);
  o[1] = (bf16_t)((v.y - mean) * rstd * gv.y + bv.y);
  o[2] = (bf16_t)((v.z - mean) * rstd * gv.z + bv.z);
  o[3] = (bf16_t)((v.w - mean) * rstd * gv.w + bv.w);
  *(bf16x4*)(out + row * 256 + c) = o;
}

// ---------------------------------------------------------------------------
// Embedding conv1: x[Bc,S] -> gelu(bn(conv1d k=7 pad=3)) -> h1p[Bc,S+4,128]
// Also zeroes h1p pad rows (0,1 at s0==0; 4098,4099 at s0==4032) so no
// separate memset dispatch is needed.
// ---------------------------------------------------------------------------
__global__ __launch_bounds__(256)
void conv1_kernel(const float* __restrict__ x, const float* __restrict__ w1,
                  const float* __restrict__ sc, const float* __restrict__ sb,
                  bf16_t* __restrict__ h1p)
{
  int b = blockIdx.x >> 6;
  int s0 = (blockIdx.x & 63) << 6;
  __shared__ float xs[70];
  __shared__ float ws[896];
  int t = threadIdx.x;
  if (t < 70) {
    int s = s0 + t - 3;
    xs[t] = (s >= 0 && s < 4096) ? x[(long)b * 4096 + s] : 0.f;
  }
  for (int i = t; i < 896; i += 256) ws[i] = w1[i];
  // zero pad rows (disjoint from data rows 2..4097)
  if (s0 == 0)
    h1p[((long)b * 4100 + (t >> 7)) * 128 + (t & 127)] = (bf16_t)0.f;
  if (s0 == 4032)
    h1p[((long)b * 4100 + 4098 + (t >> 7)) * 128 + (t & 127)] = (bf16_t)0.f;
  __syncthreads();
  int c = t & 127, so = t >> 7;
  float wr[7];
#pragma unroll
  for (int k = 0; k < 7; k++) wr[k] = ws[c * 7 + k];
  float scl = sc[c], sbv = sb[c];
  for (int p = 0; p < 32; p++) {
    int sl = p * 2 + so;
    float a = 0.f;
#pragma unroll
    for (int k = 0; k < 7; k++) a += xs[sl + k] * wr[k];
    a = geluf(a * scl + sbv);
    h1p[((long)b * 4100 + s0 + sl + 2) * 128 + c] = (bf16_t)a;
  }
}

// ---------------------------------------------------------------------------
// kv partial: per (b,h,chunk of 512 s): acc[f][d] += kp[s,f]*v[s,d]; +ksum.
// ---------------------------------------------------------------------------
__global__ __launch_bounds__(256)
void kv_partial(const bf16_t* __restrict__ qpkpv,
                float* __restrict__ pkv, float* __restrict__ pks)
{
  int bh = blockIdx.x >> 3, ch = blockIdx.x & 7;
  int b = bh >> 3, hh = bh & 7;
  int s0 = ch * 512;
  __shared__ float kps[32 * 64];
  __shared__ float vs[32 * 32];
  int t = threadIdx.x;
  int f = t & 63, dg = t >> 6;
  float acc[8] = {0.f, 0.f, 0.f, 0.f, 0.f, 0.f, 0.f, 0.f};
  float ks = 0.f;
  const int row = t >> 3, slot8 = (t & 7) * 8, slot4 = (t & 7) * 4;
  for (int sb = 0; sb < 512; sb += 32) {
    __syncthreads();
    {
      const bf16_t* rowp = qpkpv + ((long)b * 4096 + s0 + sb + row) * 1280;
      bf16x8 k8 = *(const bf16x8*)(rowp + 512 + hh * 64 + slot8);
#pragma unroll
      for (int j = 0; j < 8; j++) kps[row * 64 + slot8 + j] = (float)k8[j];
      bf16x4 v4 = *(const bf16x4*)(rowp + 1024 + hh * 32 + slot4);
#pragma unroll
      for (int j = 0; j < 4; j++) vs[row * 32 + slot4 + j] = (float)v4[j];
    }
    __syncthreads();
#pragma unroll 4
    for (int s = 0; s < 32; s++) {
      float kval = kps[s * 64 + f];
      float4 v0 = *(const float4*)&vs[s * 32 + dg * 8];
      float4 v1 = *(const float4*)&vs[s * 32 + dg * 8 + 4];
      acc[0] += kval * v0.x; acc[1] += kval * v0.y;
      acc[2] += kval * v0.z; acc[3] += kval * v0.w;
      acc[4] += kval * v1.x; acc[5] += kval * v1.y;
      acc[6] += kval * v1.z; acc[7] += kval * v1.w;
      ks += kval;
    }
  }
  long o = (long)blockIdx.x * 2048 + f * 32 + dg * 8;
#pragma unroll
  for (int j = 0; j < 8; j++) pkv[o + j] = acc[j];
  if (dg == 0) pks[blockIdx.x * 64 + f] = ks;
}

// ---------------------------------------------------------------------------
// combine: ao[s, h*32+d] = (qp[s,:] @ kv[:,d]) / (qp[s,:]@ksum + 1e-8)
// kv/ksum reduced from 8 chunk-partials inline (deterministic order).
// ---------------------------------------------------------------------------
__global__ __launch_bounds__(256, 2)
void combine_mfma(const bf16_t* __restrict__ qpkpv, const float* __restrict__ pkv,
                  const float* __restrict__ pks, bf16_t* __restrict__ ao)
{
  int bh = blockIdx.x >> 5;
  int s0 = (blockIdx.x & 31) << 7;
  int b = bh >> 3, hh = bh & 7;
  __shared__ bf16_t A_s[128 * 72];
  __shared__ bf16_t B_s[48 * 72];
  int t = threadIdx.x;
  for (int g = t; g < 1024; g += 256) {
    int row = g >> 3, slot = (g & 7) * 8;
    *(bf16x8*)&A_s[row * 72 + slot] =
        *(const bf16x8*)(qpkpv + ((long)b * 4096 + s0 + row) * 1280 + hh * 64 + slot);
  }
  for (int i = t; i < 2048; i += 256) {
    float s = 0.f;
#pragma unroll
    for (int ch = 0; ch < 8; ch++) s += pkv[((long)(bh * 8 + ch)) * 2048 + i];
    int f = i >> 5, d = i & 31;
    B_s[d * 72 + f] = (bf16_t)s;
  }
  if (t < 64) {
    float s = 0.f;
#pragma unroll
    for (int ch = 0; ch < 8; ch++) s += pks[(bh * 8 + ch) * 64 + t];
    B_s[32 * 72 + t] = (bf16_t)s;
  }
  for (int i = t; i < 960; i += 256) {
    int n = 33 + (i >> 6), f = i & 63;
    B_s[n * 72 + f] = (bf16_t)0.f;
  }
  __syncthreads();
  int lane = t & 63, w = t >> 6;
  f32x4 acc[2][3];
#pragma unroll
  for (int i = 0; i < 2; i++)
#pragma unroll
    for (int j = 0; j < 3; j++) acc[i][j] = (f32x4){0.f, 0.f, 0.f, 0.f};
#pragma unroll
  for (int kt = 0; kt < 2; kt++) {
    int ko = kt * 32 + (lane >> 4) * 8;
    bf16x8 a[2], bb[3];
#pragma unroll
    for (int i = 0; i < 2; i++)
      a[i] = *(const bf16x8*)&A_s[(w * 32 + i * 16 + (lane & 15)) * 72 + ko];
#pragma unroll
    for (int i = 0; i < 3; i++)
      bb[i] = *(const bf16x8*)&B_s[(i * 16 + (lane & 15)) * 72 + ko];
#pragma unroll
    for (int mi = 0; mi < 2; mi++)
#pragma unroll
      for (int ni = 0; ni < 3; ni++)
        acc[mi][ni] = __builtin_amdgcn_mfma_f32_16x16x32_bf16(a[mi], bb[ni], acc[mi][ni], 0, 0, 0);
  }
  long sbase = (long)b * 4096 + s0;
#pragma unroll
  for (int mi = 0; mi < 2; mi++)
#pragma unroll
    for (int j = 0; j < 4; j++) {
      int r = w * 32 + mi * 16 + ((lane >> 4) << 2) + j;
      float den = __shfl(acc[mi][2][j], (lane & 48)) + 1e-8f;
#pragma unroll
      for (int ni = 0; ni < 2; ni++) {
        int d = ni * 16 + (lane & 15);
        ao[(sbase + r) * 256 + hh * 32 + d] = (bf16_t)(acc[mi][ni][j] / den);
      }
    }
}

// ---------------------------------------------------------------------------
// h fp32 -> h_padded bf16 [Bc, S+4, 256] (rows offset +2). Also zeroes the
// hpad pad rows (0,1,4098,4099) and hdp pad rows (0,4097) per batch, so the
// decoder path needs no memset dispatches.
// ---------------------------------------------------------------------------
__global__ __launch_bounds__(256)
void cast_pad(const float* __restrict__ h, bf16_t* __restrict__ hp,
              bf16_t* __restrict__ hdp)
{
  long gid = (long)blockIdx.x * 256 + threadIdx.x;
  const int Bc = gridDim.x >> 9;           // grid = Bc*512
  if (gid < (long)Bc * 160) {
    int b = (int)(gid / 160);
    int r = (int)(gid % 160);
    bf16x8 z;
#pragma unroll
    for (int j = 0; j < 8; j++) z[j] = (bf16_t)0.f;
    if (r < 128) {
      int rr = r >> 5;                     // 0..3
      int row = (rr < 2) ? rr : 4096 + rr; // 0,1,4098,4099
      *(bf16x8*)(hp + ((long)b * 4100 + row) * 256 + (r & 31) * 8) = z;
    } else {
      int r2 = r - 128;                    // 0..31
      int row = (r2 >> 4) ? 4097 : 0;      // 0,4097
      *(bf16x8*)(hdp + ((long)b * 4098 + row) * 128 + (r2 & 15) * 8) = z;
    }
  }
  long i8 = gid * 8;
  long r = i8 >> 8;
  int c = (int)(i8 & 255);
  int b = (int)(r >> 12), s = (int)(r & 4095);
  float4 v0 = *(const float4*)(h + i8);
  float4 v1 = *(const float4*)(h + i8 + 4);
  bf16x8 o;
  o[0] = (bf16_t)v0.x; o[1] = (bf16_t)v0.y; o[2] = (bf16_t)v0.z; o[3] = (bf16_t)v0.w;
  o[4] = (bf16_t)v1.x; o[5] = (bf16_t)v1.y; o[6] = (bf16_t)v1.z; o[7] = (bf16_t)v1.w;
  *(bf16x8*)(hp + ((long)b * 4100 + s + 2) * 256 + c) = o;
}

// ---------------------------------------------------------------------------
// Final conv (DH->1, k=3, pad=1) + sigmoid -> out [Bc,S] fp32.
// 4 lanes per output (partial sums over channel quarters + shfl reduce);
// grid Bc*64 blocks -> full-GPU occupancy (was Bc*16).
// ---------------------------------------------------------------------------
__global__ __launch_bounds__(256)
void conv_final(const bf16_t* __restrict__ hdp, const float* __restrict__ w2,
                const float* __restrict__ b2, float* __restrict__ out)
{
  __shared__ float ws[384];
  int t = threadIdx.x;
  for (int i = t; i < 384; i += 256) ws[i] = w2[i];  // [c][k]
  __syncthreads();
  int part = t & 3;
  long idx = (long)blockIdx.x * 64 + (t >> 2);
  int b = (int)(idx >> 12);
  const bf16_t* base = hdp + ((long)b * 4098 + (idx & 4095)) * 128;
  float a = 0.f;
#pragma unroll
  for (int k = 0; k < 3; k++) {
#pragma unroll
    for (int cc = 0; cc < 4; cc++) {
      int c8 = part + cc * 4;
      bf16x8 v = *(const bf16x8*)(base + k * 128 + c8 * 8);
#pragma unroll
      for (int j = 0; j < 8; j++) a += (float)v[j] * ws[(c8 * 8 + j) * 3 + k];
    }
  }
  a += __shfl_xor(a, 1);
  a += __shfl_xor(a, 2);
  if (part == 0) out[idx] = 1.f / (1.f + __expf(-(a + b2[0])));
}

// ---------------------------------------------------------------------------
// Prep kernels (once per launch)
// ---------------------------------------------------------------------------
__global__ __launch_bounds__(256)
void prep_weff(const float* __restrict__ wq, const float* __restrict__ wk,
               const float* __restrict__ wv, const float* __restrict__ bq,
               const float* __restrict__ bk, const float* __restrict__ bv,
               const float* __restrict__ rf, bf16_t* __restrict__ weff,
               float* __restrict__ beff)
{
  long idx = (long)blockIdx.x * 256 + threadIdx.x;  // 4*1280*256
  int d = (int)(idx & 255);
  long r = idx >> 8;
  int n = (int)(r % 1280);
  int l = (int)(r / 1280);
  float val;
  if (n < 1024) {
    int qk = n >> 9;
    int h = (n >> 6) & 7;
    int f = n & 63;
    const float* w = qk ? wk : wq;
    const float* rfh = rf + ((long)(l * 8 + h) * 32) * 64 + f;
    const float* wrow = w + ((long)l * 256 + d) * 256 + h * 32;
    float s = 0.f;
#pragma unroll
    for (int hd = 0; hd < 32; hd++) s += wrow[hd] * rfh[hd * 64];
    val = s;
  } else {
    val = wv[((long)l * 256 + d) * 256 + (n - 1024)];
  }
  weff[idx] = (bf16_t)val;
  if (idx < 4 * 1280) {
    int nn = (int)(idx % 1280);
    int ll = (int)(idx / 1280);
    float bvv;
    if (nn < 1024) {
      int qk = nn >> 9;
      int h = (nn >> 6) & 7;
      int f = nn & 63;
      const float* bsrc = qk ? bk : bq;
      float s = 0.f;
      for (int hd = 0; hd < 32; hd++)
        s += bsrc[ll * 256 + h * 32 + hd] * rf[((long)(ll * 8 + h) * 32 + hd) * 64 + f];
      bvv = s;
    } else {
      bvv = bv[ll * 256 + (nn - 1024)];
    }
    beff[idx] = bvv;
  }
}

__global__ __launch_bounds__(256)
void prep_cast_t(const float* __restrict__ src, bf16_t* __restrict__ dst, int K, int N)
{
  long idx = (long)blockIdx.x * 256 + threadIdx.x;  // nmats*N*K
  int k = (int)(idx % K);
  long r = idx / K;
  int n = (int)(r % N);
  int l = (int)(r / N);
  dst[idx] = (bf16_t)src[((long)l * K + k) * N + n];
}

__global__ __launch_bounds__(256)
void prep_conv_t(const float* __restrict__ w, bf16_t* __restrict__ dst, int C, int KW)
{
  long idx = (long)blockIdx.x * 256 + threadIdx.x;  // O*C*KW
  int ckw = C * KW;
  int kk = (int)(idx % ckw);
  int o = (int)(idx / ckw);
  int kw = kk / C, c = kk % C;
  dst[idx] = (bf16_t)w[((long)o * C + c) * KW + kw];
}

__global__ __launch_bounds__(256)
void prep_bn(const float* g1, const float* b1, const float* cb1,
             const float* g2, const float* b2, const float* cb2,
             const float* g3, const float* b3, const float* cb3,
             float* sc1, float* sb1, float* sc2, float* sb2,
             float* sc3, float* sb3)
{
  int t = threadIdx.x;
  const float r = rsqrtf(1.f + 1e-5f);
  if (t < 128) { float s = g1[t] * r; sc1[t] = s; sb1[t] = cb1[t] * s + b1[t]; }
  if (t < 256) { float s = g2[t] * r; sc2[t] = s; sb2[t] = cb2[t] * s + b2[t]; }
  if (t < 128) { float s = g3[t] * r; sc3[t] = s; sb3[t] = cb3[t] * s + b3[t]; }
}

__global__ __launch_bounds__(256)
void pe_fill(float* __restrict__ pe)
{
  long idx = (long)blockIdx.x * 256 + threadIdx.x;  // 4096*256
  int dcol = (int)(idx & 255);
  int s = (int)(idx >> 8);
  int i2 = dcol >> 1;
  float freq = expf(-9.210340371976184f * (float)(2 * i2) / 256.f);
  float a = (float)s * freq;
  pe[idx] = (dcol & 1) ? cosf(a) : sinf(a);
}

// ---------------------------------------------------------------------------
extern "C" void kernel_launch(void* const* d_in, const int* in_sizes, int n_in,
                              void* d_out, int out_size, void* d_ws, size_t ws_size,
                              hipStream_t stream)
{
  (void)in_sizes; (void)n_in; (void)out_size;
  const float* x      = (const float*)d_in[0];
  const float* emb_w1 = (const float*)d_in[1];
  const float* emb_b1 = (const float*)d_in[2];
  const float* bn1_g  = (const float*)d_in[3];
  const float* bn1_b  = (const float*)d_in[4];
  const float* emb_w2 = (const float*)d_in[5];
  const float* emb_b2 = (const float*)d_in[6];
  const float* bn2_g  = (const float*)d_in[7];
  const float* bn2_b  = (const float*)d_in[8];
  const float* wq     = (const float*)d_in[9];
  const float* bq     = (const float*)d_in[10];
  const float* wk     = (const float*)d_in[11];
  const float* bk     = (const float*)d_in[12];
  const float* wv     = (const float*)d_in[13];
  const float* bv     = (const float*)d_in[14];
  const float* wo     = (const float*)d_in[15];
  const float* bo     = (const float*)d_in[16];
  const float* rf     = (const float*)d_in[17];
  const float* ln1_g  = (const float*)d_in[18];
  const float* ln1_b  = (const float*)d_in[19];
  const float* ln2_g  = (const float*)d_in[20];
  const float* ln2_b  = (const float*)d_in[21];
  const float* ff_w1  = (const float*)d_in[22];
  const float* ff_b1  = (const float*)d_in[23];
  const float* ff_w2  = (const float*)d_in[24];
  const float* ff_b2  = (const float*)d_in[25];
  const float* dec_w1 = (const float*)d_in[26];
  const float* dec_b1 = (const float*)d_in[27];
  const float* bn3_g  = (const float*)d_in[28];
  const float* bn3_b  = (const float*)d_in[29];
  const float* dec_w2 = (const float*)d_in[30];
  const float* dec_b2 = (const float*)d_in[31];

  char* W = (char*)d_ws;

  // ---- fixed region (weights, ~12.2 MB; reserve 16 MB) ----
  bf16_t* weff = (bf16_t*)(W + 0);                     // 4*1280*256*2 = 2,621,440
  float*  beff = (float*)(W + 2621440);                // 20,480
  bf16_t* wot  = (bf16_t*)(W + 2641920);               // 524,288
  bf16_t* w1t  = (bf16_t*)(W + 3166208);               // 2,097,152
  bf16_t* w2t  = (bf16_t*)(W + 5263360);               // 2,097,152
  bf16_t* c2t  = (bf16_t*)(W + 7360512);               // 327,680
  bf16_t* d1t  = (bf16_t*)(W + 7688192);               // 327,680
  float*  pe   = (float*)(W + 8015872);                // 4,194,304
  float*  sc1  = (float*)(W + 12210176);
  float*  sb1  = (float*)(W + 12211200);
  float*  sc2  = (float*)(W + 12212224);
  float*  sb2  = (float*)(W + 12213248);
  float*  sc3  = (float*)(W + 12214272);
  float*  sb3  = (float*)(W + 12215296);
  const size_t FIXED_END = 16777216;

  // ---- pick batch chunk Bc so workspace fits ws_size ----
  const size_t PER_B = 17385472;
  int Bc = 32;
  while (Bc > 1 && FIXED_END + (size_t)Bc * PER_B > ws_size) Bc >>= 1;

  char* P = W + FIXED_END;
  float*  h     = (float*)P;
  bf16_t* xa    = (bf16_t*)(P + (size_t)Bc * 4194304);
  bf16_t* ao    = xa;  // xa dead after fused qkv gemm; ao dead before ln2
  char*   big   = P + (size_t)Bc * (4194304 + 2097152);
  bf16_t* qpkpv = (bf16_t*)big;
  bf16_t* f1    = (bf16_t*)big;                               // after qpkpv dead
  bf16_t* h1p   = (bf16_t*)big;                               // pre-loop
  bf16_t* hpad  = (bf16_t*)big;                               // post-loop
  bf16_t* hdp   = (bf16_t*)(big + (size_t)Bc * 4100 * 256 * 2);
  float*  pkv   = (float*)(big + (size_t)Bc * 10485760);
  float*  pks   = (float*)((char*)pkv + (size_t)Bc * 524288);

  // ---- weight prep (once) ----
  prep_weff<<<5120, 256, 0, stream>>>(wq, wk, wv, bq, bk, bv, rf, weff, beff);
  prep_cast_t<<<1024, 256, 0, stream>>>(wo, wot, 256, 256);
  prep_cast_t<<<4096, 256, 0, stream>>>(ff_w1, w1t, 256, 1024);
  prep_cast_t<<<4096, 256, 0, stream>>>(ff_w2, w2t, 1024, 256);
  prep_conv_t<<<640, 256, 0, stream>>>(emb_w2, c2t, 128, 5);
  prep_conv_t<<<640, 256, 0, stream>>>(dec_w1, d1t, 256, 5);
  prep_bn<<<1, 256, 0, stream>>>(bn1_g, bn1_b, emb_b1, bn2_g, bn2_b, emb_b2,
                                 bn3_g, bn3_b, dec_b1, sc1, sb1, sc2, sb2, sc3, sb3);
  pe_fill<<<4096, 256, 0, stream>>>(pe);

  for (int c0 = 0; c0 < 32; c0 += Bc) {
    const float* xc = x + (size_t)c0 * 4096;

    // ---- embedding (conv1 zeroes its own pad rows) ----
    conv1_kernel<<<Bc * 64, 256, 0, stream>>>(xc, emb_w1, sc1, sb1, h1p);
    gemm_bf16<3, 640, 64, 4><<<Bc * 128, 256, 0, stream>>>(
        h1p, c2t, h, sb2, sc2, nullptr, pe,
        128, 4100L * 128, 4096, 256, 256, 4096L * 256, 0);

    // ---- transformer layers ----
    for (int l = 0; l < 4; l++) {
      ln_kernel<<<Bc * 1024, 256, 0, stream>>>(h, ln1_g + l * 256, ln1_b + l * 256, xa);
      gemm_bf16<5, 256, 128, 10><<<Bc * 320, 256, 0, stream>>>(
          xa, weff + (long)l * 327680, qpkpv, beff + l * 1280, nullptr, nullptr, nullptr,
          256, 4096L * 256, 4096, 1280, 1280, 4096L * 1280, 0);
      kv_partial<<<Bc * 64, 256, 0, stream>>>(qpkpv, pkv, pks);
      combine_mfma<<<Bc * 256, 256, 0, stream>>>(qpkpv, pkv, pks, ao);
      gemm_bf16<1, 256, 64, 4><<<Bc * 128, 256, 0, stream>>>(
          ao, wot + (long)l * 65536, h, bo + l * 256, nullptr, h, nullptr,
          256, 4096L * 256, 4096, 256, 256, 4096L * 256, 0);
      ln_kernel<<<Bc * 1024, 256, 0, stream>>>(h, ln2_g + l * 256, ln2_b + l * 256, xa);
      gemm_bf16<2, 256, 128, 8><<<Bc * 256, 256, 0, stream>>>(
          xa, w1t + (long)l * 262144, f1, ff_b1 + l * 1024, nullptr, nullptr, nullptr,
          256, 4096L * 256, 4096, 1024, 1024, 4096L * 1024, 0);
      gemm_bf16<1, 1024, 64, 4><<<Bc * 128, 256, 0, stream>>>(
          f1, w2t + (long)l * 262144, h, ff_b2 + l * 256, nullptr, h, nullptr,
          1024, 4096L * 1024, 4096, 256, 256, 4096L * 256, 0);
    }

    // ---- decoder (cast_pad zeroes hpad + hdp pad rows) ----
    cast_pad<<<Bc * 512, 256, 0, stream>>>(h, hpad, hdp);
    gemm_bf16<4, 1280, 64, 2><<<Bc * 64, 256, 0, stream>>>(
        hpad, d1t, hdp, sb3, sc3, nullptr, nullptr,
        256, 4100L * 256, 4096, 128, 128, 4098L * 128, 1);
    conv_final<<<Bc * 64, 256, 0, stream>>>(hdp, dec_w2, dec_b2,
                                            (float*)d_out + (size_t)c0 * 4096);
  }
}

// Round 18
// 4138.628 us; speedup vs baseline: 1.4727x; 1.0020x over previous
//
#include <hip/hip_runtime.h>
#include <hip/hip_bf16.h>
#include <math.h>

// ============================================================================
// PPGPeakPerformer forward on MI355X (gfx950)
// B=32 S=4096 D=256 DH=128 H=8 HD=32 F=64 L=4
// r18 = r17 (best passing, 4147us) + final low-risk bundle:
//  - combine_mfma occupancy 2 -> 4 blocks/CU (LDS 25.6KB, VGPR 40 allow it)
//  - prep_cast_t -> 32x32 LDS-tiled transpose (coalesced both sides,
//    stride-33 tile = conflict-free); bit-identical output values
// Core unchanged: 128xBN GEMM (BN=128 wide, BN=64 narrow), BK=32, A triple-
// buffer depth-2 + counted vmcnt(2), B double-buffer, 40KB LDS, 4 blocks/CU,
// bijective XCD chunk-remap (GEMMs + ln), both-sides swizzle, fast erf,
// fused q/k RF projection, kv_reduce folded into combine. LN separate pass
// (fusion numerically refuted r14/r15). No memsets (pads zeroed in-kernel).
// ============================================================================

typedef __bf16 bf16_t;
typedef __bf16 bf16x8 __attribute__((ext_vector_type(8)));
typedef __bf16 bf16x4 __attribute__((ext_vector_type(4)));
typedef float  f32x4  __attribute__((ext_vector_type(4)));

#define DEV __device__ __forceinline__

DEV float erf_fast(float x) {
  float ax = fabsf(x);
  float t = __builtin_amdgcn_rcpf(1.f + 0.3275911f * ax);
  float p = t * (0.254829592f + t * (-0.284496736f + t * (1.421413741f +
            t * (-1.453152027f + t * 1.061405429f))));
  float r = 1.f - p * __expf(-ax * ax);
  return copysignf(r, x);
}
DEV float geluf(float v) { return 0.5f * v * (1.f + erf_fast(v * 0.70710678118654752440f)); }
DEV float softplusf(float v) {
  float e = __expf(-fabsf(v));
  return fmaxf(v, 0.f) + __logf(1.f + e);
}

// Direct global->LDS 16B staging. LDS dest is wave-uniform base + lane*16.
DEV void gload16(const bf16_t* g, bf16_t* l) {
  __builtin_amdgcn_global_load_lds(
      (const __attribute__((address_space(1))) void*)g,
      (__attribute__((address_space(3))) void*)l, 16, 0, 0);
}

// ---------------------------------------------------------------------------
// GEMM: C[m,n] = sum_k A[m,k]*Bt[n,k].  A bf16 (batched rows), Bt bf16 [N][K].
// EPI: 1 = +bias +resid -> fp32; 2 = gelu(+bias) -> bf16;
//      3 = gelu(scale*x+bias)+pe -> fp32; 4 = gelu(scale*x+bias) -> bf16;
//      5 = tile<1024 ? softplus(+bias) : (+bias) -> bf16 (block-uniform)
// Pipeline per iter t:
//   wait vmcnt(2); s_barrier; stage B(t+1); stage A(t+2); ds_read; MFMA.
// A slack ~2 iters (HBM-ok), B slack ~1 iter (L2-ok).
// ---------------------------------------------------------------------------
template <int EPI, int K, int BN, int NTL>
__global__ __launch_bounds__(256, 4)
void gemm_bf16(const bf16_t* __restrict__ A, const bf16_t* __restrict__ Bt,
               void* Cout, const float* __restrict__ bias,
               const float* __restrict__ scale, const float* resid,
               const float* __restrict__ pe,
               int lda, long a_bstride, int rpb,
               int N, int ldc, long c_bstride, int c_roff)
{
  constexpr int MI = (BN == 128) ? 4 : 2;   // row-fragments per wave
  __shared__ bf16_t As[3][128 * 32];
  __shared__ bf16_t Bs[2][BN * 32];
  const int t = threadIdx.x;
  const int lane = t & 63;
  const int w = t >> 6;
  const int wrow = (BN == 128) ? (w >> 1) * 64 : w * 32;
  const int wcol = (BN == 128) ? (w & 1) * 64 : 0;

  // XCD-aware bijective remap (m204): bid%8 -> XCD; XCD k gets a contiguous
  // wgid chunk (n-tile fastest) so A-tile sharers co-reside on one L2.
  const int nwg = gridDim.x;
  const int q_ = nwg >> 3, r_ = nwg & 7;
  const int xcd = blockIdx.x & 7, idx_ = blockIdx.x >> 3;
  const int wgid = (xcd < r_ ? xcd * (q_ + 1) : r_ * (q_ + 1) + (xcd - r_) * q_) + idx_;
  const long m0 = (long)(wgid / NTL) * 128;
  const int n0 = (wgid % NTL) * BN;

  const int b = (int)(m0 / rpb);
  const int s_base = (int)(m0 % rpb);
  const bf16_t* Ab = A + (long)b * a_bstride + (long)s_base * lda;
  const bf16_t* Bb = Bt + (long)n0 * K;

  // staging source (pre-swizzled): lane covers row (lane>>2) of a 16-row
  // block, 16B slot ((lane&3) ^ ((row>>1)&3)).
  const int srow = lane >> 2;
  const int sslot = (lane & 3) ^ ((srow >> 1) & 3);
  const bf16_t* aS = Ab + (long)(w * 32 + srow) * lda + sslot * 8;
  const bf16_t* bS = Bb + (long)(w * 32 + srow) * K + sslot * 8;
  const int dsto = w * 1024;  // 32 rows x 32 elems per wave

#define STAGE_A(bufidx, kk)                                 \
  {                                                         \
    bf16_t* a_ = &As[bufidx][dsto];                         \
    gload16(aS + (kk), a_);                                 \
    gload16(aS + (kk) + 16 * (long)lda, a_ + 512);          \
  }
#define STAGE_B(bufidx, kk)                                 \
  if (BN == 128 || w < 2) {                                 \
    bf16_t* b_ = &Bs[bufidx][dsto];                         \
    gload16(bS + (kk), b_);                                 \
    gload16(bS + (kk) + 16 * (long)K, b_ + 512);            \
  }

  f32x4 acc[MI][4];
#pragma unroll
  for (int i = 0; i < MI; i++)
#pragma unroll
    for (int j = 0; j < 4; j++) acc[i][j] = (f32x4){0.f, 0.f, 0.f, 0.f};

  constexpr int NT = K >> 5;
  // prologue queue order: A(0), B(0), A(1) -> wait vmcnt(2) drains A0,B0.
  STAGE_A(0, 0);
  STAGE_B(0, 0);
  if (NT > 1) STAGE_A(1, 32);

#pragma unroll
  for (int tt = 0; tt < NT; ++tt) {
    if (tt + 1 < NT) {
      asm volatile("s_waitcnt vmcnt(2)" ::: "memory");
    } else {
      asm volatile("s_waitcnt vmcnt(0)" ::: "memory");
    }
    __builtin_amdgcn_s_barrier();
    __builtin_amdgcn_sched_barrier(0);
    if (tt + 1 < NT) STAGE_B((tt + 1) & 1, (tt + 1) * 32);
    if (tt + 2 < NT) STAGE_A((tt + 2) % 3, (tt + 2) * 32);
    const bf16_t* Acur = As[tt % 3];
    const bf16_t* Bcur = Bs[tt & 1];
    const int kb = (lane >> 4) * 16;
    bf16x8 af[MI], bfr[4];
#pragma unroll
    for (int i = 0; i < MI; i++) {
      int rA = wrow + i * 16 + (lane & 15);
      af[i] = *(const bf16x8*)((const char*)Acur + rA * 64 + (kb ^ (((rA >> 1) & 3) << 4)));
    }
#pragma unroll
    for (int j = 0; j < 4; j++) {
      int rB = wcol + j * 16 + (lane & 15);
      bfr[j] = *(const bf16x8*)((const char*)Bcur + rB * 64 + (kb ^ (((rB >> 1) & 3) << 4)));
    }
    __builtin_amdgcn_s_setprio(1);
#pragma unroll
    for (int mi = 0; mi < MI; mi++)
#pragma unroll
      for (int ni = 0; ni < 4; ni++)
        acc[mi][ni] = __builtin_amdgcn_mfma_f32_16x16x32_bf16(af[mi], bfr[ni], acc[mi][ni], 0, 0, 0);
    __builtin_amdgcn_s_setprio(0);
  }
#undef STAGE_A
#undef STAGE_B

  const int colbase = n0 + wcol + (lane & 15);
  float bias_r[4], scale_r[4];
#pragma unroll
  for (int ni = 0; ni < 4; ni++) {
    int col = colbase + ni * 16;
    bias_r[ni] = bias[col];
    scale_r[ni] = (EPI == 3 || EPI == 4) ? scale[col] : 0.f;
  }
  // EPI 5: softplus applies to the whole 64-col warp-tile or none of it
  // (tile boundary at col 1024 is 64-aligned) -> wave-uniform branch.
  const bool spAll = (EPI == 5) && ((n0 + wcol) < 1024);
#pragma unroll
  for (int mi = 0; mi < MI; mi++) {
#pragma unroll
    for (int j = 0; j < 4; j++) {
      int row = wrow + mi * 16 + ((lane >> 4) << 2) + j;
      long s = s_base + row;
      long cro = (long)b * c_bstride + (s + c_roff) * (long)ldc;
#pragma unroll
      for (int ni = 0; ni < 4; ni++) {
        int col = colbase + ni * 16;
        float v = acc[mi][ni][j];
        if constexpr (EPI == 1) {
          v += bias_r[ni] + resid[cro + col];
          ((float*)Cout)[cro + col] = v;
        } else if constexpr (EPI == 2) {
          v = geluf(v + bias_r[ni]);
          ((bf16_t*)Cout)[cro + col] = (bf16_t)v;
        } else if constexpr (EPI == 3) {
          v = geluf(v * scale_r[ni] + bias_r[ni]) + pe[s * 256 + col];
          ((float*)Cout)[cro + col] = v;
        } else if constexpr (EPI == 4) {
          v = geluf(v * scale_r[ni] + bias_r[ni]);
          ((bf16_t*)Cout)[cro + col] = (bf16_t)v;
        } else {  // 5
          v += bias_r[ni];
          if (spAll) v = softplusf(v);
          ((bf16_t*)Cout)[cro + col] = (bf16_t)v;
        }
      }
    }
  }
}

// ---------------------------------------------------------------------------
// LayerNorm over D=256, fp32 in -> bf16 out. 4 rows/block (1 wave per row).
// XCD chunk-remap matches the GEMM m-tile map: XCD k owns contiguous rows.
// ---------------------------------------------------------------------------
__global__ __launch_bounds__(256)
void ln_kernel(const float* __restrict__ h, const float* __restrict__ g,
               const float* __restrict__ bta, bf16_t* __restrict__ out)
{
  int t = threadIdx.x;
  int lane = t & 63;
  const int G = gridDim.x;                 // divisible by 8
  const int wgid = (blockIdx.x & 7) * (G >> 3) + (blockIdx.x >> 3);
  long row = (long)wgid * 4 + (t >> 6);
  const float* hp = h + row * 256 + lane * 4;
  float4 v = *(const float4*)hp;
  float s = v.x + v.y + v.z + v.w;
  float q = v.x * v.x + v.y * v.y + v.z * v.z + v.w * v.w;
#pragma unroll
  for (int m = 32; m >= 1; m >>= 1) {
    s += __shfl_xor(s, m);
    q += __shfl_xor(q, m);
  }
  float mean = s * 0.00390625f;
  float var = q * 0.00390625f - mean * mean;
  float rstd = rsqrtf(var + 1e-5f);
  int c = lane * 4;
  float4 gv = *(const float4*)(g + c);
  float4 bv = *(const float4*)(bta + c);
  bf16x4 o;
  o[0] = (bf16_t)((v.x - mean) * rstd * gv.x + bv.x);
  o[1] = (bf16_t)((v.y - mean) * rstd * gv.y + bv.y);
  o[2] = (bf16_t)((v.z - mean) * rstd * gv.z + bv.z);
  o[3] = (bf16_t)((v.w - mean) * rstd * gv.w + bv.w);
  *(bf16x4*)(out + row * 256 + c) = o;
}

// ---------------------------------------------------------------------------
// Embedding conv1: x[Bc,S] -> gelu(bn(conv1d k=7 pad=3)) -> h1p[Bc,S+4,128]
// Also zeroes h1p pad rows (0,1 at s0==0; 4098,4099 at s0==4032).
// ---------------------------------------------------------------------------
__global__ __launch_bounds__(256)
void conv1_kernel(const float* __restrict__ x, const float* __restrict__ w1,
                  const float* __restrict__ sc, const float* __restrict__ sb,
                  bf16_t* __restrict__ h1p)
{
  int b = blockIdx.x >> 6;
  int s0 = (blockIdx.x & 63) << 6;
  __shared__ float xs[70];
  __shared__ float ws[896];
  int t = threadIdx.x;
  if (t < 70) {
    int s = s0 + t - 3;
    xs[t] = (s >= 0 && s < 4096) ? x[(long)b * 4096 + s] : 0.f;
  }
  for (int i = t; i < 896; i += 256) ws[i] = w1[i];
  // zero pad rows (disjoint from data rows 2..4097)
  if (s0 == 0)
    h1p[((long)b * 4100 + (t >> 7)) * 128 + (t & 127)] = (bf16_t)0.f;
  if (s0 == 4032)
    h1p[((long)b * 4100 + 4098 + (t >> 7)) * 128 + (t & 127)] = (bf16_t)0.f;
  __syncthreads();
  int c = t & 127, so = t >> 7;
  float wr[7];
#pragma unroll
  for (int k = 0; k < 7; k++) wr[k] = ws[c * 7 + k];
  float scl = sc[c], sbv = sb[c];
  for (int p = 0; p < 32; p++) {
    int sl = p * 2 + so;
    float a = 0.f;
#pragma unroll
    for (int k = 0; k < 7; k++) a += xs[sl + k] * wr[k];
    a = geluf(a * scl + sbv);
    h1p[((long)b * 4100 + s0 + sl + 2) * 128 + c] = (bf16_t)a;
  }
}

// ---------------------------------------------------------------------------
// kv partial: per (b,h,chunk of 512 s): acc[f][d] += kp[s,f]*v[s,d]; +ksum.
// ---------------------------------------------------------------------------
__global__ __launch_bounds__(256)
void kv_partial(const bf16_t* __restrict__ qpkpv,
                float* __restrict__ pkv, float* __restrict__ pks)
{
  int bh = blockIdx.x >> 3, ch = blockIdx.x & 7;
  int b = bh >> 3, hh = bh & 7;
  int s0 = ch * 512;
  __shared__ float kps[32 * 64];
  __shared__ float vs[32 * 32];
  int t = threadIdx.x;
  int f = t & 63, dg = t >> 6;
  float acc[8] = {0.f, 0.f, 0.f, 0.f, 0.f, 0.f, 0.f, 0.f};
  float ks = 0.f;
  const int row = t >> 3, slot8 = (t & 7) * 8, slot4 = (t & 7) * 4;
  for (int sb = 0; sb < 512; sb += 32) {
    __syncthreads();
    {
      const bf16_t* rowp = qpkpv + ((long)b * 4096 + s0 + sb + row) * 1280;
      bf16x8 k8 = *(const bf16x8*)(rowp + 512 + hh * 64 + slot8);
#pragma unroll
      for (int j = 0; j < 8; j++) kps[row * 64 + slot8 + j] = (float)k8[j];
      bf16x4 v4 = *(const bf16x4*)(rowp + 1024 + hh * 32 + slot4);
#pragma unroll
      for (int j = 0; j < 4; j++) vs[row * 32 + slot4 + j] = (float)v4[j];
    }
    __syncthreads();
#pragma unroll 4
    for (int s = 0; s < 32; s++) {
      float kval = kps[s * 64 + f];
      float4 v0 = *(const float4*)&vs[s * 32 + dg * 8];
      float4 v1 = *(const float4*)&vs[s * 32 + dg * 8 + 4];
      acc[0] += kval * v0.x; acc[1] += kval * v0.y;
      acc[2] += kval * v0.z; acc[3] += kval * v0.w;
      acc[4] += kval * v1.x; acc[5] += kval * v1.y;
      acc[6] += kval * v1.z; acc[7] += kval * v1.w;
      ks += kval;
    }
  }
  long o = (long)blockIdx.x * 2048 + f * 32 + dg * 8;
#pragma unroll
  for (int j = 0; j < 8; j++) pkv[o + j] = acc[j];
  if (dg == 0) pks[blockIdx.x * 64 + f] = ks;
}

// ---------------------------------------------------------------------------
// combine: ao[s, h*32+d] = (qp[s,:] @ kv[:,d]) / (qp[s,:]@ksum + 1e-8)
// kv/ksum reduced from 8 chunk-partials inline (deterministic order).
// Occupancy 4 blocks/CU (LDS 25.6KB, VGPR 40 -> safe).
// ---------------------------------------------------------------------------
__global__ __launch_bounds__(256, 4)
void combine_mfma(const bf16_t* __restrict__ qpkpv, const float* __restrict__ pkv,
                  const float* __restrict__ pks, bf16_t* __restrict__ ao)
{
  int bh = blockIdx.x >> 5;
  int s0 = (blockIdx.x & 31) << 7;
  int b = bh >> 3, hh = bh & 7;
  __shared__ bf16_t A_s[128 * 72];
  __shared__ bf16_t B_s[48 * 72];
  int t = threadIdx.x;
  for (int g = t; g < 1024; g += 256) {
    int row = g >> 3, slot = (g & 7) * 8;
    *(bf16x8*)&A_s[row * 72 + slot] =
        *(const bf16x8*)(qpkpv + ((long)b * 4096 + s0 + row) * 1280 + hh * 64 + slot);
  }
  for (int i = t; i < 2048; i += 256) {
    float s = 0.f;
#pragma unroll
    for (int ch = 0; ch < 8; ch++) s += pkv[((long)(bh * 8 + ch)) * 2048 + i];
    int f = i >> 5, d = i & 31;
    B_s[d * 72 + f] = (bf16_t)s;
  }
  if (t < 64) {
    float s = 0.f;
#pragma unroll
    for (int ch = 0; ch < 8; ch++) s += pks[(bh * 8 + ch) * 64 + t];
    B_s[32 * 72 + t] = (bf16_t)s;
  }
  for (int i = t; i < 960; i += 256) {
    int n = 33 + (i >> 6), f = i & 63;
    B_s[n * 72 + f] = (bf16_t)0.f;
  }
  __syncthreads();
  int lane = t & 63, w = t >> 6;
  f32x4 acc[2][3];
#pragma unroll
  for (int i = 0; i < 2; i++)
#pragma unroll
    for (int j = 0; j < 3; j++) acc[i][j] = (f32x4){0.f, 0.f, 0.f, 0.f};
#pragma unroll
  for (int kt = 0; kt < 2; kt++) {
    int ko = kt * 32 + (lane >> 4) * 8;
    bf16x8 a[2], bb[3];
#pragma unroll
    for (int i = 0; i < 2; i++)
      a[i] = *(const bf16x8*)&A_s[(w * 32 + i * 16 + (lane & 15)) * 72 + ko];
#pragma unroll
    for (int i = 0; i < 3; i++)
      bb[i] = *(const bf16x8*)&B_s[(i * 16 + (lane & 15)) * 72 + ko];
#pragma unroll
    for (int mi = 0; mi < 2; mi++)
#pragma unroll
      for (int ni = 0; ni < 3; ni++)
        acc[mi][ni] = __builtin_amdgcn_mfma_f32_16x16x32_bf16(a[mi], bb[ni], acc[mi][ni], 0, 0, 0);
  }
  long sbase = (long)b * 4096 + s0;
#pragma unroll
  for (int mi = 0; mi < 2; mi++)
#pragma unroll
    for (int j = 0; j < 4; j++) {
      int r = w * 32 + mi * 16 + ((lane >> 4) << 2) + j;
      float den = __shfl(acc[mi][2][j], (lane & 48)) + 1e-8f;
#pragma unroll
      for (int ni = 0; ni < 2; ni++) {
        int d = ni * 16 + (lane & 15);
        ao[(sbase + r) * 256 + hh * 32 + d] = (bf16_t)(acc[mi][ni][j] / den);
      }
    }
}

// ---------------------------------------------------------------------------
// h fp32 -> h_padded bf16 [Bc, S+4, 256] (rows offset +2). Also zeroes the
// hpad pad rows (0,1,4098,4099) and hdp pad rows (0,4097) per batch.
// ---------------------------------------------------------------------------
__global__ __launch_bounds__(256)
void cast_pad(const float* __restrict__ h, bf16_t* __restrict__ hp,
              bf16_t* __restrict__ hdp)
{
  long gid = (long)blockIdx.x * 256 + threadIdx.x;
  const int Bc = gridDim.x >> 9;           // grid = Bc*512
  if (gid < (long)Bc * 160) {
    int b = (int)(gid / 160);
    int r = (int)(gid % 160);
    bf16x8 z;
#pragma unroll
    for (int j = 0; j < 8; j++) z[j] = (bf16_t)0.f;
    if (r < 128) {
      int rr = r >> 5;                     // 0..3
      int row = (rr < 2) ? rr : 4096 + rr; // 0,1,4098,4099
      *(bf16x8*)(hp + ((long)b * 4100 + row) * 256 + (r & 31) * 8) = z;
    } else {
      int r2 = r - 128;                    // 0..31
      int row = (r2 >> 4) ? 4097 : 0;      // 0,4097
      *(bf16x8*)(hdp + ((long)b * 4098 + row) * 128 + (r2 & 15) * 8) = z;
    }
  }
  long i8 = gid * 8;
  long r = i8 >> 8;
  int c = (int)(i8 & 255);
  int b = (int)(r >> 12), s = (int)(r & 4095);
  float4 v0 = *(const float4*)(h + i8);
  float4 v1 = *(const float4*)(h + i8 + 4);
  bf16x8 o;
  o[0] = (bf16_t)v0.x; o[1] = (bf16_t)v0.y; o[2] = (bf16_t)v0.z; o[3] = (bf16_t)v0.w;
  o[4] = (bf16_t)v1.x; o[5] = (bf16_t)v1.y; o[6] = (bf16_t)v1.z; o[7] = (bf16_t)v1.w;
  *(bf16x8*)(hp + ((long)b * 4100 + s + 2) * 256 + c) = o;
}

// ---------------------------------------------------------------------------
// Final conv (DH->1, k=3, pad=1) + sigmoid -> out [Bc,S] fp32.
// 4 lanes per output (partial sums + shfl reduce); grid Bc*64 blocks.
// ---------------------------------------------------------------------------
__global__ __launch_bounds__(256)
void conv_final(const bf16_t* __restrict__ hdp, const float* __restrict__ w2,
                const float* __restrict__ b2, float* __restrict__ out)
{
  __shared__ float ws[384];
  int t = threadIdx.x;
  for (int i = t; i < 384; i += 256) ws[i] = w2[i];  // [c][k]
  __syncthreads();
  int part = t & 3;
  long idx = (long)blockIdx.x * 64 + (t >> 2);
  int b = (int)(idx >> 12);
  const bf16_t* base = hdp + ((long)b * 4098 + (idx & 4095)) * 128;
  float a = 0.f;
#pragma unroll
  for (int k = 0; k < 3; k++) {
#pragma unroll
    for (int cc = 0; cc < 4; cc++) {
      int c8 = part + cc * 4;
      bf16x8 v = *(const bf16x8*)(base + k * 128 + c8 * 8);
#pragma unroll
      for (int j = 0; j < 8; j++) a += (float)v[j] * ws[(c8 * 8 + j) * 3 + k];
    }
  }
  a += __shfl_xor(a, 1);
  a += __shfl_xor(a, 2);
  if (part == 0) out[idx] = 1.f / (1.f + __expf(-(a + b2[0])));
}

// ---------------------------------------------------------------------------
// Prep kernels (once per launch)
// ---------------------------------------------------------------------------
__global__ __launch_bounds__(256)
void prep_weff(const float* __restrict__ wq, const float* __restrict__ wk,
               const float* __restrict__ wv, const float* __restrict__ bq,
               const float* __restrict__ bk, const float* __restrict__ bv,
               const float* __restrict__ rf, bf16_t* __restrict__ weff,
               float* __restrict__ beff)
{
  long idx = (long)blockIdx.x * 256 + threadIdx.x;  // 4*1280*256
  int d = (int)(idx & 255);
  long r = idx >> 8;
  int n = (int)(r % 1280);
  int l = (int)(r / 1280);
  float val;
  if (n < 1024) {
    int qk = n >> 9;
    int h = (n >> 6) & 7;
    int f = n & 63;
    const float* w = qk ? wk : wq;
    const float* rfh = rf + ((long)(l * 8 + h) * 32) * 64 + f;
    const float* wrow = w + ((long)l * 256 + d) * 256 + h * 32;
    float s = 0.f;
#pragma unroll
    for (int hd = 0; hd < 32; hd++) s += wrow[hd] * rfh[hd * 64];
    val = s;
  } else {
    val = wv[((long)l * 256 + d) * 256 + (n - 1024)];
  }
  weff[idx] = (bf16_t)val;
  if (idx < 4 * 1280) {
    int nn = (int)(idx % 1280);
    int ll = (int)(idx / 1280);
    float bvv;
    if (nn < 1024) {
      int qk = nn >> 9;
      int h = (nn >> 6) & 7;
      int f = nn & 63;
      const float* bsrc = qk ? bk : bq;
      float s = 0.f;
      for (int hd = 0; hd < 32; hd++)
        s += bsrc[ll * 256 + h * 32 + hd] * rf[((long)(ll * 8 + h) * 32 + hd) * 64 + f];
      bvv = s;
    } else {
      bvv = bv[ll * 256 + (nn - 1024)];
    }
    beff[idx] = bvv;
  }
}

// 32x32 LDS-tiled transpose+cast: src fp32 [l][K][N] -> dst bf16 [l][N][K].
// Coalesced loads and stores; tile stride 33 -> bank-conflict-free.
// grid = nm * (N/32) * (K/32) blocks, 256 threads.
__global__ __launch_bounds__(256)
void prep_cast_t32(const float* __restrict__ src, bf16_t* __restrict__ dst,
                   int K, int N)
{
  __shared__ float tile[32][33];
  const int kt = K >> 5, nt = N >> 5;
  int bid = blockIdx.x;
  int l = bid / (kt * nt);
  int rem = bid % (kt * nt);
  int ntile = rem / kt;          // n-tile index
  int ktile = rem % kt;          // k-tile index
  int n0 = ntile * 32, k0 = ktile * 32;
  int t = threadIdx.x;
  int c = t & 31, rbase = t >> 5;  // 8 rows per pass
#pragma unroll
  for (int i = 0; i < 4; i++) {
    int r = rbase + i * 8;
    tile[r][c] = src[((long)l * K + k0 + r) * N + n0 + c];
  }
  __syncthreads();
#pragma unroll
  for (int i = 0; i < 4; i++) {
    int r = rbase + i * 8;
    dst[((long)l * N + n0 + r) * K + k0 + c] = (bf16_t)tile[c][r];
  }
}

__global__ __launch_bounds__(256)
void prep_conv_t(const float* __restrict__ w, bf16_t* __restrict__ dst, int C, int KW)
{
  long idx = (long)blockIdx.x * 256 + threadIdx.x;  // O*C*KW
  int ckw = C * KW;
  int kk = (int)(idx % ckw);
  int o = (int)(idx / ckw);
  int kw = kk / C, c = kk % C;
  dst[idx] = (bf16_t)w[((long)o * C + c) * KW + kw];
}

__global__ __launch_bounds__(256)
void prep_bn(const float* g1, const float* b1, const float* cb1,
             const float* g2, const float* b2, const float* cb2,
             const float* g3, const float* b3, const float* cb3,
             float* sc1, float* sb1, float* sc2, float* sb2,
             float* sc3, float* sb3)
{
  int t = threadIdx.x;
  const float r = rsqrtf(1.f + 1e-5f);
  if (t < 128) { float s = g1[t] * r; sc1[t] = s; sb1[t] = cb1[t] * s + b1[t]; }
  if (t < 256) { float s = g2[t] * r; sc2[t] = s; sb2[t] = cb2[t] * s + b2[t]; }
  if (t < 128) { float s = g3[t] * r; sc3[t] = s; sb3[t] = cb3[t] * s + b3[t]; }
}

__global__ __launch_bounds__(256)
void pe_fill(float* __restrict__ pe)
{
  long idx = (long)blockIdx.x * 256 + threadIdx.x;  // 4096*256
  int dcol = (int)(idx & 255);
  int s = (int)(idx >> 8);
  int i2 = dcol >> 1;
  float freq = expf(-9.210340371976184f * (float)(2 * i2) / 256.f);
  float a = (float)s * freq;
  pe[idx] = (dcol & 1) ? cosf(a) : sinf(a);
}

// ---------------------------------------------------------------------------
extern "C" void kernel_launch(void* const* d_in, const int* in_sizes, int n_in,
                              void* d_out, int out_size, void* d_ws, size_t ws_size,
                              hipStream_t stream)
{
  (void)in_sizes; (void)n_in; (void)out_size;
  const float* x      = (const float*)d_in[0];
  const float* emb_w1 = (const float*)d_in[1];
  const float* emb_b1 = (const float*)d_in[2];
  const float* bn1_g  = (const float*)d_in[3];
  const float* bn1_b  = (const float*)d_in[4];
  const float* emb_w2 = (const float*)d_in[5];
  const float* emb_b2 = (const float*)d_in[6];
  const float* bn2_g  = (const float*)d_in[7];
  const float* bn2_b  = (const float*)d_in[8];
  const float* wq     = (const float*)d_in[9];
  const float* bq     = (const float*)d_in[10];
  const float* wk     = (const float*)d_in[11];
  const float* bk     = (const float*)d_in[12];
  const float* wv     = (const float*)d_in[13];
  const float* bv     = (const float*)d_in[14];
  const float* wo     = (const float*)d_in[15];
  const float* bo     = (const float*)d_in[16];
  const float* rf     = (const float*)d_in[17];
  const float* ln1_g  = (const float*)d_in[18];
  const float* ln1_b  = (const float*)d_in[19];
  const float* ln2_g  = (const float*)d_in[20];
  const float* ln2_b  = (const float*)d_in[21];
  const float* ff_w1  = (const float*)d_in[22];
  const float* ff_b1  = (const float*)d_in[23];
  const float* ff_w2  = (const float*)d_in[24];
  const float* ff_b2  = (const float*)d_in[25];
  const float* dec_w1 = (const float*)d_in[26];
  const float* dec_b1 = (const float*)d_in[27];
  const float* bn3_g  = (const float*)d_in[28];
  const float* bn3_b  = (const float*)d_in[29];
  const float* dec_w2 = (const float*)d_in[30];
  const float* dec_b2 = (const float*)d_in[31];

  char* W = (char*)d_ws;

  // ---- fixed region (weights, ~12.2 MB; reserve 16 MB) ----
  bf16_t* weff = (bf16_t*)(W + 0);                     // 4*1280*256*2 = 2,621,440
  float*  beff = (float*)(W + 2621440);                // 20,480
  bf16_t* wot  = (bf16_t*)(W + 2641920);               // 524,288
  bf16_t* w1t  = (bf16_t*)(W + 3166208);               // 2,097,152
  bf16_t* w2t  = (bf16_t*)(W + 5263360);               // 2,097,152
  bf16_t* c2t  = (bf16_t*)(W + 7360512);               // 327,680
  bf16_t* d1t  = (bf16_t*)(W + 7688192);               // 327,680
  float*  pe   = (float*)(W + 8015872);                // 4,194,304
  float*  sc1  = (float*)(W + 12210176);
  float*  sb1  = (float*)(W + 12211200);
  float*  sc2  = (float*)(W + 12212224);
  float*  sb2  = (float*)(W + 12213248);
  float*  sc3  = (float*)(W + 12214272);
  float*  sb3  = (float*)(W + 12215296);
  const size_t FIXED_END = 16777216;

  // ---- pick batch chunk Bc so workspace fits ws_size ----
  const size_t PER_B = 17385472;
  int Bc = 32;
  while (Bc > 1 && FIXED_END + (size_t)Bc * PER_B > ws_size) Bc >>= 1;

  char* P = W + FIXED_END;
  float*  h     = (float*)P;
  bf16_t* xa    = (bf16_t*)(P + (size_t)Bc * 4194304);
  bf16_t* ao    = xa;  // xa dead after fused qkv gemm; ao dead before ln2
  char*   big   = P + (size_t)Bc * (4194304 + 2097152);
  bf16_t* qpkpv = (bf16_t*)big;
  bf16_t* f1    = (bf16_t*)big;                               // after qpkpv dead
  bf16_t* h1p   = (bf16_t*)big;                               // pre-loop
  bf16_t* hpad  = (bf16_t*)big;                               // post-loop
  bf16_t* hdp   = (bf16_t*)(big + (size_t)Bc * 4100 * 256 * 2);
  float*  pkv   = (float*)(big + (size_t)Bc * 10485760);
  float*  pks   = (float*)((char*)pkv + (size_t)Bc * 524288);

  // ---- weight prep (once) ----
  prep_weff<<<5120, 256, 0, stream>>>(wq, wk, wv, bq, bk, bv, rf, weff, beff);
  prep_cast_t32<<<256, 256, 0, stream>>>(wo, wot, 256, 256);
  prep_cast_t32<<<1024, 256, 0, stream>>>(ff_w1, w1t, 256, 1024);
  prep_cast_t32<<<1024, 256, 0, stream>>>(ff_w2, w2t, 1024, 256);
  prep_conv_t<<<640, 256, 0, stream>>>(emb_w2, c2t, 128, 5);
  prep_conv_t<<<640, 256, 0, stream>>>(dec_w1, d1t, 256, 5);
  prep_bn<<<1, 256, 0, stream>>>(bn1_g, bn1_b, emb_b1, bn2_g, bn2_b, emb_b2,
                                 bn3_g, bn3_b, dec_b1, sc1, sb1, sc2, sb2, sc3, sb3);
  pe_fill<<<4096, 256, 0, stream>>>(pe);

  for (int c0 = 0; c0 < 32; c0 += Bc) {
    const float* xc = x + (size_t)c0 * 4096;

    // ---- embedding (conv1 zeroes its own pad rows) ----
    conv1_kernel<<<Bc * 64, 256, 0, stream>>>(xc, emb_w1, sc1, sb1, h1p);
    gemm_bf16<3, 640, 64, 4><<<Bc * 128, 256, 0, stream>>>(
        h1p, c2t, h, sb2, sc2, nullptr, pe,
        128, 4100L * 128, 4096, 256, 256, 4096L * 256, 0);

    // ---- transformer layers ----
    for (int l = 0; l < 4; l++) {
      ln_kernel<<<Bc * 1024, 256, 0, stream>>>(h, ln1_g + l * 256, ln1_b + l * 256, xa);
      gemm_bf16<5, 256, 128, 10><<<Bc * 320, 256, 0, stream>>>(
          xa, weff + (long)l * 327680, qpkpv, beff + l * 1280, nullptr, nullptr, nullptr,
          256, 4096L * 256, 4096, 1280, 1280, 4096L * 1280, 0);
      kv_partial<<<Bc * 64, 256, 0, stream>>>(qpkpv, pkv, pks);
      combine_mfma<<<Bc * 256, 256, 0, stream>>>(qpkpv, pkv, pks, ao);
      gemm_bf16<1, 256, 64, 4><<<Bc * 128, 256, 0, stream>>>(
          ao, wot + (long)l * 65536, h, bo + l * 256, nullptr, h, nullptr,
          256, 4096L * 256, 4096, 256, 256, 4096L * 256, 0);
      ln_kernel<<<Bc * 1024, 256, 0, stream>>>(h, ln2_g + l * 256, ln2_b + l * 256, xa);
      gemm_bf16<2, 256, 128, 8><<<Bc * 256, 256, 0, stream>>>(
          xa, w1t + (long)l * 262144, f1, ff_b1 + l * 1024, nullptr, nullptr, nullptr,
          256, 4096L * 256, 4096, 1024, 1024, 4096L * 1024, 0);
      gemm_bf16<1, 1024, 64, 4><<<Bc * 128, 256, 0, stream>>>(
          f1, w2t + (long)l * 262144, h, ff_b2 + l * 256, nullptr, h, nullptr,
          1024, 4096L * 1024, 4096, 256, 256, 4096L * 256, 0);
    }

    // ---- decoder (cast_pad zeroes hpad + hdp pad rows) ----
    cast_pad<<<Bc * 512, 256, 0, stream>>>(h, hpad, hdp);
    gemm_bf16<4, 1280, 64, 2><<<Bc * 64, 256, 0, stream>>>(
        hpad, d1t, hdp, sb3, sc3, nullptr, nullptr,
        256, 4100L * 256, 4096, 128, 128, 4098L * 128, 1);
    conv_final<<<Bc * 64, 256, 0, stream>>>(hdp, dec_w2, dec_b2,
                                            (float*)d_out + (size_t)c0 * 4096);
  }
}

// Round 19
// 4108.837 us; speedup vs baseline: 1.4833x; 1.0073x over previous
//
#include <hip/hip_runtime.h>
#include <hip/hip_bf16.h>
#include <math.h>

// ============================================================================
// PPGPeakPerformer forward on MI355X (gfx950)
// B=32 S=4096 D=256 DH=128 H=8 HD=32 F=64 L=4
// r19 = r18 (best passing, 4139us) + kv_reduce un-fold:
//   r7 folded the 8-chunk pkv reduction into combine_mfma, but 32 combine
//   blocks share each bh -> 32x duplicated reduction (64KB L2 reads + 2048
//   reduces + 960 pad-zero writes per block). Restore a tiny kv_reduce_b
//   (once per bh) writing the exact [48][72] bf16 B-panel layout with the
//   SAME fp32 summation order (bit-identical values); combine's LDS build
//   becomes a straight vector copy.
// Core unchanged: 128xBN GEMM (BN=128 wide, BN=64 narrow), BK=32, A triple-
// buffer depth-2 + counted vmcnt(2), B double-buffer, 40KB LDS, 4 blocks/CU,
// bijective XCD chunk-remap (GEMMs + ln), both-sides swizzle, fast erf,
// fused q/k RF projection GEMM, no memsets, tiled weight transposes,
// conv_final 4-lane reduce. LN separate pass (fusion refuted r14/r15).
// ============================================================================

typedef __bf16 bf16_t;
typedef __bf16 bf16x8 __attribute__((ext_vector_type(8)));
typedef __bf16 bf16x4 __attribute__((ext_vector_type(4)));
typedef float  f32x4  __attribute__((ext_vector_type(4)));

#define DEV __device__ __forceinline__

DEV float erf_fast(float x) {
  float ax = fabsf(x);
  float t = __builtin_amdgcn_rcpf(1.f + 0.3275911f * ax);
  float p = t * (0.254829592f + t * (-0.284496736f + t * (1.421413741f +
            t * (-1.453152027f + t * 1.061405429f))));
  float r = 1.f - p * __expf(-ax * ax);
  return copysignf(r, x);
}
DEV float geluf(float v) { return 0.5f * v * (1.f + erf_fast(v * 0.70710678118654752440f)); }
DEV float softplusf(float v) {
  float e = __expf(-fabsf(v));
  return fmaxf(v, 0.f) + __logf(1.f + e);
}

// Direct global->LDS 16B staging. LDS dest is wave-uniform base + lane*16.
DEV void gload16(const bf16_t* g, bf16_t* l) {
  __builtin_amdgcn_global_load_lds(
      (const __attribute__((address_space(1))) void*)g,
      (__attribute__((address_space(3))) void*)l, 16, 0, 0);
}

// ---------------------------------------------------------------------------
// GEMM: C[m,n] = sum_k A[m,k]*Bt[n,k].  A bf16 (batched rows), Bt bf16 [N][K].
// EPI: 1 = +bias +resid -> fp32; 2 = gelu(+bias) -> bf16;
//      3 = gelu(scale*x+bias)+pe -> fp32; 4 = gelu(scale*x+bias) -> bf16;
//      5 = tile<1024 ? softplus(+bias) : (+bias) -> bf16 (block-uniform)
// Pipeline per iter t:
//   wait vmcnt(2); s_barrier; stage B(t+1); stage A(t+2); ds_read; MFMA.
// A slack ~2 iters (HBM-ok), B slack ~1 iter (L2-ok).
// ---------------------------------------------------------------------------
template <int EPI, int K, int BN, int NTL>
__global__ __launch_bounds__(256, 4)
void gemm_bf16(const bf16_t* __restrict__ A, const bf16_t* __restrict__ Bt,
               void* Cout, const float* __restrict__ bias,
               const float* __restrict__ scale, const float* resid,
               const float* __restrict__ pe,
               int lda, long a_bstride, int rpb,
               int N, int ldc, long c_bstride, int c_roff)
{
  constexpr int MI = (BN == 128) ? 4 : 2;   // row-fragments per wave
  __shared__ bf16_t As[3][128 * 32];
  __shared__ bf16_t Bs[2][BN * 32];
  const int t = threadIdx.x;
  const int lane = t & 63;
  const int w = t >> 6;
  const int wrow = (BN == 128) ? (w >> 1) * 64 : w * 32;
  const int wcol = (BN == 128) ? (w & 1) * 64 : 0;

  // XCD-aware bijective remap (m204): bid%8 -> XCD; XCD k gets a contiguous
  // wgid chunk (n-tile fastest) so A-tile sharers co-reside on one L2.
  const int nwg = gridDim.x;
  const int q_ = nwg >> 3, r_ = nwg & 7;
  const int xcd = blockIdx.x & 7, idx_ = blockIdx.x >> 3;
  const int wgid = (xcd < r_ ? xcd * (q_ + 1) : r_ * (q_ + 1) + (xcd - r_) * q_) + idx_;
  const long m0 = (long)(wgid / NTL) * 128;
  const int n0 = (wgid % NTL) * BN;

  const int b = (int)(m0 / rpb);
  const int s_base = (int)(m0 % rpb);
  const bf16_t* Ab = A + (long)b * a_bstride + (long)s_base * lda;
  const bf16_t* Bb = Bt + (long)n0 * K;

  // staging source (pre-swizzled): lane covers row (lane>>2) of a 16-row
  // block, 16B slot ((lane&3) ^ ((row>>1)&3)).
  const int srow = lane >> 2;
  const int sslot = (lane & 3) ^ ((srow >> 1) & 3);
  const bf16_t* aS = Ab + (long)(w * 32 + srow) * lda + sslot * 8;
  const bf16_t* bS = Bb + (long)(w * 32 + srow) * K + sslot * 8;
  const int dsto = w * 1024;  // 32 rows x 32 elems per wave

#define STAGE_A(bufidx, kk)                                 \
  {                                                         \
    bf16_t* a_ = &As[bufidx][dsto];                         \
    gload16(aS + (kk), a_);                                 \
    gload16(aS + (kk) + 16 * (long)lda, a_ + 512);          \
  }
#define STAGE_B(bufidx, kk)                                 \
  if (BN == 128 || w < 2) {                                 \
    bf16_t* b_ = &Bs[bufidx][dsto];                         \
    gload16(bS + (kk), b_);                                 \
    gload16(bS + (kk) + 16 * (long)K, b_ + 512);            \
  }

  f32x4 acc[MI][4];
#pragma unroll
  for (int i = 0; i < MI; i++)
#pragma unroll
    for (int j = 0; j < 4; j++) acc[i][j] = (f32x4){0.f, 0.f, 0.f, 0.f};

  constexpr int NT = K >> 5;
  // prologue queue order: A(0), B(0), A(1) -> wait vmcnt(2) drains A0,B0.
  STAGE_A(0, 0);
  STAGE_B(0, 0);
  if (NT > 1) STAGE_A(1, 32);

#pragma unroll
  for (int tt = 0; tt < NT; ++tt) {
    if (tt + 1 < NT) {
      asm volatile("s_waitcnt vmcnt(2)" ::: "memory");
    } else {
      asm volatile("s_waitcnt vmcnt(0)" ::: "memory");
    }
    __builtin_amdgcn_s_barrier();
    __builtin_amdgcn_sched_barrier(0);
    if (tt + 1 < NT) STAGE_B((tt + 1) & 1, (tt + 1) * 32);
    if (tt + 2 < NT) STAGE_A((tt + 2) % 3, (tt + 2) * 32);
    const bf16_t* Acur = As[tt % 3];
    const bf16_t* Bcur = Bs[tt & 1];
    const int kb = (lane >> 4) * 16;
    bf16x8 af[MI], bfr[4];
#pragma unroll
    for (int i = 0; i < MI; i++) {
      int rA = wrow + i * 16 + (lane & 15);
      af[i] = *(const bf16x8*)((const char*)Acur + rA * 64 + (kb ^ (((rA >> 1) & 3) << 4)));
    }
#pragma unroll
    for (int j = 0; j < 4; j++) {
      int rB = wcol + j * 16 + (lane & 15);
      bfr[j] = *(const bf16x8*)((const char*)Bcur + rB * 64 + (kb ^ (((rB >> 1) & 3) << 4)));
    }
    __builtin_amdgcn_s_setprio(1);
#pragma unroll
    for (int mi = 0; mi < MI; mi++)
#pragma unroll
      for (int ni = 0; ni < 4; ni++)
        acc[mi][ni] = __builtin_amdgcn_mfma_f32_16x16x32_bf16(af[mi], bfr[ni], acc[mi][ni], 0, 0, 0);
    __builtin_amdgcn_s_setprio(0);
  }
#undef STAGE_A
#undef STAGE_B

  const int colbase = n0 + wcol + (lane & 15);
  float bias_r[4], scale_r[4];
#pragma unroll
  for (int ni = 0; ni < 4; ni++) {
    int col = colbase + ni * 16;
    bias_r[ni] = bias[col];
    scale_r[ni] = (EPI == 3 || EPI == 4) ? scale[col] : 0.f;
  }
  // EPI 5: softplus applies to the whole 64-col warp-tile or none of it
  // (tile boundary at col 1024 is 64-aligned) -> wave-uniform branch.
  const bool spAll = (EPI == 5) && ((n0 + wcol) < 1024);
#pragma unroll
  for (int mi = 0; mi < MI; mi++) {
#pragma unroll
    for (int j = 0; j < 4; j++) {
      int row = wrow + mi * 16 + ((lane >> 4) << 2) + j;
      long s = s_base + row;
      long cro = (long)b * c_bstride + (s + c_roff) * (long)ldc;
#pragma unroll
      for (int ni = 0; ni < 4; ni++) {
        int col = colbase + ni * 16;
        float v = acc[mi][ni][j];
        if constexpr (EPI == 1) {
          v += bias_r[ni] + resid[cro + col];
          ((float*)Cout)[cro + col] = v;
        } else if constexpr (EPI == 2) {
          v = geluf(v + bias_r[ni]);
          ((bf16_t*)Cout)[cro + col] = (bf16_t)v;
        } else if constexpr (EPI == 3) {
          v = geluf(v * scale_r[ni] + bias_r[ni]) + pe[s * 256 + col];
          ((float*)Cout)[cro + col] = v;
        } else if constexpr (EPI == 4) {
          v = geluf(v * scale_r[ni] + bias_r[ni]);
          ((bf16_t*)Cout)[cro + col] = (bf16_t)v;
        } else {  // 5
          v += bias_r[ni];
          if (spAll) v = softplusf(v);
          ((bf16_t*)Cout)[cro + col] = (bf16_t)v;
        }
      }
    }
  }
}

// ---------------------------------------------------------------------------
// LayerNorm over D=256, fp32 in -> bf16 out. 4 rows/block (1 wave per row).
// XCD chunk-remap matches the GEMM m-tile map: XCD k owns contiguous rows.
// ---------------------------------------------------------------------------
__global__ __launch_bounds__(256)
void ln_kernel(const float* __restrict__ h, const float* __restrict__ g,
               const float* __restrict__ bta, bf16_t* __restrict__ out)
{
  int t = threadIdx.x;
  int lane = t & 63;
  const int G = gridDim.x;                 // divisible by 8
  const int wgid = (blockIdx.x & 7) * (G >> 3) + (blockIdx.x >> 3);
  long row = (long)wgid * 4 + (t >> 6);
  const float* hp = h + row * 256 + lane * 4;
  float4 v = *(const float4*)hp;
  float s = v.x + v.y + v.z + v.w;
  float q = v.x * v.x + v.y * v.y + v.z * v.z + v.w * v.w;
#pragma unroll
  for (int m = 32; m >= 1; m >>= 1) {
    s += __shfl_xor(s, m);
    q += __shfl_xor(q, m);
  }
  float mean = s * 0.00390625f;
  float var = q * 0.00390625f - mean * mean;
  float rstd = rsqrtf(var + 1e-5f);
  int c = lane * 4;
  float4 gv = *(const float4*)(g + c);
  float4 bv = *(const float4*)(bta + c);
  bf16x4 o;
  o[0] = (bf16_t)((v.x - mean) * rstd * gv.x + bv.x);
  o[1] = (bf16_t)((v.y - mean) * rstd * gv.y + bv.y);
  o[2] = (bf16_t)((v.z - mean) * rstd * gv.z + bv.z);
  o[3] = (bf16_t)((v.w - mean) * rstd * gv.w + bv.w);
  *(bf16x4*)(out + row * 256 + c) = o;
}

// ---------------------------------------------------------------------------
// Embedding conv1: x[Bc,S] -> gelu(bn(conv1d k=7 pad=3)) -> h1p[Bc,S+4,128]
// Also zeroes h1p pad rows (0,1 at s0==0; 4098,4099 at s0==4032).
// ---------------------------------------------------------------------------
__global__ __launch_bounds__(256)
void conv1_kernel(const float* __restrict__ x, const float* __restrict__ w1,
                  const float* __restrict__ sc, const float* __restrict__ sb,
                  bf16_t* __restrict__ h1p)
{
  int b = blockIdx.x >> 6;
  int s0 = (blockIdx.x & 63) << 6;
  __shared__ float xs[70];
  __shared__ float ws[896];
  int t = threadIdx.x;
  if (t < 70) {
    int s = s0 + t - 3;
    xs[t] = (s >= 0 && s < 4096) ? x[(long)b * 4096 + s] : 0.f;
  }
  for (int i = t; i < 896; i += 256) ws[i] = w1[i];
  // zero pad rows (disjoint from data rows 2..4097)
  if (s0 == 0)
    h1p[((long)b * 4100 + (t >> 7)) * 128 + (t & 127)] = (bf16_t)0.f;
  if (s0 == 4032)
    h1p[((long)b * 4100 + 4098 + (t >> 7)) * 128 + (t & 127)] = (bf16_t)0.f;
  __syncthreads();
  int c = t & 127, so = t >> 7;
  float wr[7];
#pragma unroll
  for (int k = 0; k < 7; k++) wr[k] = ws[c * 7 + k];
  float scl = sc[c], sbv = sb[c];
  for (int p = 0; p < 32; p++) {
    int sl = p * 2 + so;
    float a = 0.f;
#pragma unroll
    for (int k = 0; k < 7; k++) a += xs[sl + k] * wr[k];
    a = geluf(a * scl + sbv);
    h1p[((long)b * 4100 + s0 + sl + 2) * 128 + c] = (bf16_t)a;
  }
}

// ---------------------------------------------------------------------------
// kv partial: per (b,h,chunk of 512 s): acc[f][d] += kp[s,f]*v[s,d]; +ksum.
// ---------------------------------------------------------------------------
__global__ __launch_bounds__(256)
void kv_partial(const bf16_t* __restrict__ qpkpv,
                float* __restrict__ pkv, float* __restrict__ pks)
{
  int bh = blockIdx.x >> 3, ch = blockIdx.x & 7;
  int b = bh >> 3, hh = bh & 7;
  int s0 = ch * 512;
  __shared__ float kps[32 * 64];
  __shared__ float vs[32 * 32];
  int t = threadIdx.x;
  int f = t & 63, dg = t >> 6;
  float acc[8] = {0.f, 0.f, 0.f, 0.f, 0.f, 0.f, 0.f, 0.f};
  float ks = 0.f;
  const int row = t >> 3, slot8 = (t & 7) * 8, slot4 = (t & 7) * 4;
  for (int sb = 0; sb < 512; sb += 32) {
    __syncthreads();
    {
      const bf16_t* rowp = qpkpv + ((long)b * 4096 + s0 + sb + row) * 1280;
      bf16x8 k8 = *(const bf16x8*)(rowp + 512 + hh * 64 + slot8);
#pragma unroll
      for (int j = 0; j < 8; j++) kps[row * 64 + slot8 + j] = (float)k8[j];
      bf16x4 v4 = *(const bf16x4*)(rowp + 1024 + hh * 32 + slot4);
#pragma unroll
      for (int j = 0; j < 4; j++) vs[row * 32 + slot4 + j] = (float)v4[j];
    }
    __syncthreads();
#pragma unroll 4
    for (int s = 0; s < 32; s++) {
      float kval = kps[s * 64 + f];
      float4 v0 = *(const float4*)&vs[s * 32 + dg * 8];
      float4 v1 = *(const float4*)&vs[s * 32 + dg * 8 + 4];
      acc[0] += kval * v0.x; acc[1] += kval * v0.y;
      acc[2] += kval * v0.z; acc[3] += kval * v0.w;
      acc[4] += kval * v1.x; acc[5] += kval * v1.y;
      acc[6] += kval * v1.z; acc[7] += kval * v1.w;
      ks += kval;
    }
  }
  long o = (long)blockIdx.x * 2048 + f * 32 + dg * 8;
#pragma unroll
  for (int j = 0; j < 8; j++) pkv[o + j] = acc[j];
  if (dg == 0) pks[blockIdx.x * 64 + f] = ks;
}

// ---------------------------------------------------------------------------
// kv_reduce_b: once per bh, reduce the 8 chunk-partials into the exact
// [48][72] bf16 B-panel layout combine_mfma stages (rows 0..31 = kv^T,
// row 32 = ksum, rows 33..47 + pad cols = 0). Same fp32 summation order
// as the old in-combine reduction -> bit-identical values.
// ---------------------------------------------------------------------------
__global__ __launch_bounds__(256)
void kv_reduce_b(const float* __restrict__ pkv, const float* __restrict__ pks,
                 bf16_t* __restrict__ kvb)
{
  int bh = blockIdx.x;
  int t = threadIdx.x;
  for (int i = t; i < 3456; i += 256) {
    int n = i / 72, f = i % 72;
    float s = 0.f;
    if (f < 64) {
      if (n < 32) {
#pragma unroll
        for (int ch = 0; ch < 8; ch++)
          s += pkv[((long)(bh * 8 + ch)) * 2048 + f * 32 + n];
      } else if (n == 32) {
#pragma unroll
        for (int ch = 0; ch < 8; ch++)
          s += pks[(bh * 8 + ch) * 64 + f];
      }
    }
    kvb[(long)bh * 3456 + i] = (bf16_t)s;
  }
}

// ---------------------------------------------------------------------------
// combine: ao[s, h*32+d] = (qp[s,:] @ kv[:,d]) / (qp[s,:]@ksum + 1e-8)
// B-panel comes precomputed from kv_reduce_b (straight vector copy to LDS).
// ---------------------------------------------------------------------------
__global__ __launch_bounds__(256, 4)
void combine_mfma(const bf16_t* __restrict__ qpkpv, const bf16_t* __restrict__ kvb,
                  bf16_t* __restrict__ ao)
{
  int bh = blockIdx.x >> 5;
  int s0 = (blockIdx.x & 31) << 7;
  int b = bh >> 3, hh = bh & 7;
  __shared__ bf16_t A_s[128 * 72];
  __shared__ bf16_t B_s[48 * 72];
  int t = threadIdx.x;
  for (int g = t; g < 1024; g += 256) {
    int row = g >> 3, slot = (g & 7) * 8;
    *(bf16x8*)&A_s[row * 72 + slot] =
        *(const bf16x8*)(qpkpv + ((long)b * 4096 + s0 + row) * 1280 + hh * 64 + slot);
  }
  {
    const bf16x8* kv8 = (const bf16x8*)(kvb + (long)bh * 3456);
    for (int i = t; i < 432; i += 256)
      ((bf16x8*)B_s)[i] = kv8[i];
  }
  __syncthreads();
  int lane = t & 63, w = t >> 6;
  f32x4 acc[2][3];
#pragma unroll
  for (int i = 0; i < 2; i++)
#pragma unroll
    for (int j = 0; j < 3; j++) acc[i][j] = (f32x4){0.f, 0.f, 0.f, 0.f};
#pragma unroll
  for (int kt = 0; kt < 2; kt++) {
    int ko = kt * 32 + (lane >> 4) * 8;
    bf16x8 a[2], bb[3];
#pragma unroll
    for (int i = 0; i < 2; i++)
      a[i] = *(const bf16x8*)&A_s[(w * 32 + i * 16 + (lane & 15)) * 72 + ko];
#pragma unroll
    for (int i = 0; i < 3; i++)
      bb[i] = *(const bf16x8*)&B_s[(i * 16 + (lane & 15)) * 72 + ko];
#pragma unroll
    for (int mi = 0; mi < 2; mi++)
#pragma unroll
      for (int ni = 0; ni < 3; ni++)
        acc[mi][ni] = __builtin_amdgcn_mfma_f32_16x16x32_bf16(a[mi], bb[ni], acc[mi][ni], 0, 0, 0);
  }
  long sbase = (long)b * 4096 + s0;
#pragma unroll
  for (int mi = 0; mi < 2; mi++)
#pragma unroll
    for (int j = 0; j < 4; j++) {
      int r = w * 32 + mi * 16 + ((lane >> 4) << 2) + j;
      float den = __shfl(acc[mi][2][j], (lane & 48)) + 1e-8f;
#pragma unroll
      for (int ni = 0; ni < 2; ni++) {
        int d = ni * 16 + (lane & 15);
        ao[(sbase + r) * 256 + hh * 32 + d] = (bf16_t)(acc[mi][ni][j] / den);
      }
    }
}

// ---------------------------------------------------------------------------
// h fp32 -> h_padded bf16 [Bc, S+4, 256] (rows offset +2). Also zeroes the
// hpad pad rows (0,1,4098,4099) and hdp pad rows (0,4097) per batch.
// ---------------------------------------------------------------------------
__global__ __launch_bounds__(256)
void cast_pad(const float* __restrict__ h, bf16_t* __restrict__ hp,
              bf16_t* __restrict__ hdp)
{
  long gid = (long)blockIdx.x * 256 + threadIdx.x;
  const int Bc = gridDim.x >> 9;           // grid = Bc*512
  if (gid < (long)Bc * 160) {
    int b = (int)(gid / 160);
    int r = (int)(gid % 160);
    bf16x8 z;
#pragma unroll
    for (int j = 0; j < 8; j++) z[j] = (bf16_t)0.f;
    if (r < 128) {
      int rr = r >> 5;                     // 0..3
      int row = (rr < 2) ? rr : 4096 + rr; // 0,1,4098,4099
      *(bf16x8*)(hp + ((long)b * 4100 + row) * 256 + (r & 31) * 8) = z;
    } else {
      int r2 = r - 128;                    // 0..31
      int row = (r2 >> 4) ? 4097 : 0;      // 0,4097
      *(bf16x8*)(hdp + ((long)b * 4098 + row) * 128 + (r2 & 15) * 8) = z;
    }
  }
  long i8 = gid * 8;
  long r = i8 >> 8;
  int c = (int)(i8 & 255);
  int b = (int)(r >> 12), s = (int)(r & 4095);
  float4 v0 = *(const float4*)(h + i8);
  float4 v1 = *(const float4*)(h + i8 + 4);
  bf16x8 o;
  o[0] = (bf16_t)v0.x; o[1] = (bf16_t)v0.y; o[2] = (bf16_t)v0.z; o[3] = (bf16_t)v0.w;
  o[4] = (bf16_t)v1.x; o[5] = (bf16_t)v1.y; o[6] = (bf16_t)v1.z; o[7] = (bf16_t)v1.w;
  *(bf16x8*)(hp + ((long)b * 4100 + s + 2) * 256 + c) = o;
}

// ---------------------------------------------------------------------------
// Final conv (DH->1, k=3, pad=1) + sigmoid -> out [Bc,S] fp32.
// 4 lanes per output (partial sums + shfl reduce); grid Bc*64 blocks.
// ---------------------------------------------------------------------------
__global__ __launch_bounds__(256)
void conv_final(const bf16_t* __restrict__ hdp, const float* __restrict__ w2,
                const float* __restrict__ b2, float* __restrict__ out)
{
  __shared__ float ws[384];
  int t = threadIdx.x;
  for (int i = t; i < 384; i += 256) ws[i] = w2[i];  // [c][k]
  __syncthreads();
  int part = t & 3;
  long idx = (long)blockIdx.x * 64 + (t >> 2);
  int b = (int)(idx >> 12);
  const bf16_t* base = hdp + ((long)b * 4098 + (idx & 4095)) * 128;
  float a = 0.f;
#pragma unroll
  for (int k = 0; k < 3; k++) {
#pragma unroll
    for (int cc = 0; cc < 4; cc++) {
      int c8 = part + cc * 4;
      bf16x8 v = *(const bf16x8*)(base + k * 128 + c8 * 8);
#pragma unroll
      for (int j = 0; j < 8; j++) a += (float)v[j] * ws[(c8 * 8 + j) * 3 + k];
    }
  }
  a += __shfl_xor(a, 1);
  a += __shfl_xor(a, 2);
  if (part == 0) out[idx] = 1.f / (1.f + __expf(-(a + b2[0])));
}

// ---------------------------------------------------------------------------
// Prep kernels (once per launch)
// ---------------------------------------------------------------------------
__global__ __launch_bounds__(256)
void prep_weff(const float* __restrict__ wq, const float* __restrict__ wk,
               const float* __restrict__ wv, const float* __restrict__ bq,
               const float* __restrict__ bk, const float* __restrict__ bv,
               const float* __restrict__ rf, bf16_t* __restrict__ weff,
               float* __restrict__ beff)
{
  long idx = (long)blockIdx.x * 256 + threadIdx.x;  // 4*1280*256
  int d = (int)(idx & 255);
  long r = idx >> 8;
  int n = (int)(r % 1280);
  int l = (int)(r / 1280);
  float val;
  if (n < 1024) {
    int qk = n >> 9;
    int h = (n >> 6) & 7;
    int f = n & 63;
    const float* w = qk ? wk : wq;
    const float* rfh = rf + ((long)(l * 8 + h) * 32) * 64 + f;
    const float* wrow = w + ((long)l * 256 + d) * 256 + h * 32;
    float s = 0.f;
#pragma unroll
    for (int hd = 0; hd < 32; hd++) s += wrow[hd] * rfh[hd * 64];
    val = s;
  } else {
    val = wv[((long)l * 256 + d) * 256 + (n - 1024)];
  }
  weff[idx] = (bf16_t)val;
  if (idx < 4 * 1280) {
    int nn = (int)(idx % 1280);
    int ll = (int)(idx / 1280);
    float bvv;
    if (nn < 1024) {
      int qk = nn >> 9;
      int h = (nn >> 6) & 7;
      int f = nn & 63;
      const float* bsrc = qk ? bk : bq;
      float s = 0.f;
      for (int hd = 0; hd < 32; hd++)
        s += bsrc[ll * 256 + h * 32 + hd] * rf[((long)(ll * 8 + h) * 32 + hd) * 64 + f];
      bvv = s;
    } else {
      bvv = bv[ll * 256 + (nn - 1024)];
    }
    beff[idx] = bvv;
  }
}

// 32x32 LDS-tiled transpose+cast: src fp32 [l][K][N] -> dst bf16 [l][N][K].
__global__ __launch_bounds__(256)
void prep_cast_t32(const float* __restrict__ src, bf16_t* __restrict__ dst,
                   int K, int N)
{
  __shared__ float tile[32][33];
  const int kt = K >> 5, nt = N >> 5;
  int bid = blockIdx.x;
  int l = bid / (kt * nt);
  int rem = bid % (kt * nt);
  int ntile = rem / kt;          // n-tile index
  int ktile = rem % kt;          // k-tile index
  int n0 = ntile * 32, k0 = ktile * 32;
  int t = threadIdx.x;
  int c = t & 31, rbase = t >> 5;  // 8 rows per pass
#pragma unroll
  for (int i = 0; i < 4; i++) {
    int r = rbase + i * 8;
    tile[r][c] = src[((long)l * K + k0 + r) * N + n0 + c];
  }
  __syncthreads();
#pragma unroll
  for (int i = 0; i < 4; i++) {
    int r = rbase + i * 8;
    dst[((long)l * N + n0 + r) * K + k0 + c] = (bf16_t)tile[c][r];
  }
}

__global__ __launch_bounds__(256)
void prep_conv_t(const float* __restrict__ w, bf16_t* __restrict__ dst, int C, int KW)
{
  long idx = (long)blockIdx.x * 256 + threadIdx.x;  // O*C*KW
  int ckw = C * KW;
  int kk = (int)(idx % ckw);
  int o = (int)(idx / ckw);
  int kw = kk / C, c = kk % C;
  dst[idx] = (bf16_t)w[((long)o * C + c) * KW + kw];
}

__global__ __launch_bounds__(256)
void prep_bn(const float* g1, const float* b1, const float* cb1,
             const float* g2, const float* b2, const float* cb2,
             const float* g3, const float* b3, const float* cb3,
             float* sc1, float* sb1, float* sc2, float* sb2,
             float* sc3, float* sb3)
{
  int t = threadIdx.x;
  const float r = rsqrtf(1.f + 1e-5f);
  if (t < 128) { float s = g1[t] * r; sc1[t] = s; sb1[t] = cb1[t] * s + b1[t]; }
  if (t < 256) { float s = g2[t] * r; sc2[t] = s; sb2[t] = cb2[t] * s + b2[t]; }
  if (t < 128) { float s = g3[t] * r; sc3[t] = s; sb3[t] = cb3[t] * s + b3[t]; }
}

__global__ __launch_bounds__(256)
void pe_fill(float* __restrict__ pe)
{
  long idx = (long)blockIdx.x * 256 + threadIdx.x;  // 4096*256
  int dcol = (int)(idx & 255);
  int s = (int)(idx >> 8);
  int i2 = dcol >> 1;
  float freq = expf(-9.210340371976184f * (float)(2 * i2) / 256.f);
  float a = (float)s * freq;
  pe[idx] = (dcol & 1) ? cosf(a) : sinf(a);
}

// ---------------------------------------------------------------------------
extern "C" void kernel_launch(void* const* d_in, const int* in_sizes, int n_in,
                              void* d_out, int out_size, void* d_ws, size_t ws_size,
                              hipStream_t stream)
{
  (void)in_sizes; (void)n_in; (void)out_size;
  const float* x      = (const float*)d_in[0];
  const float* emb_w1 = (const float*)d_in[1];
  const float* emb_b1 = (const float*)d_in[2];
  const float* bn1_g  = (const float*)d_in[3];
  const float* bn1_b  = (const float*)d_in[4];
  const float* emb_w2 = (const float*)d_in[5];
  const float* emb_b2 = (const float*)d_in[6];
  const float* bn2_g  = (const float*)d_in[7];
  const float* bn2_b  = (const float*)d_in[8];
  const float* wq     = (const float*)d_in[9];
  const float* bq     = (const float*)d_in[10];
  const float* wk     = (const float*)d_in[11];
  const float* bk     = (const float*)d_in[12];
  const float* wv     = (const float*)d_in[13];
  const float* bv     = (const float*)d_in[14];
  const float* wo     = (const float*)d_in[15];
  const float* bo     = (const float*)d_in[16];
  const float* rf     = (const float*)d_in[17];
  const float* ln1_g  = (const float*)d_in[18];
  const float* ln1_b  = (const float*)d_in[19];
  const float* ln2_g  = (const float*)d_in[20];
  const float* ln2_b  = (const float*)d_in[21];
  const float* ff_w1  = (const float*)d_in[22];
  const float* ff_b1  = (const float*)d_in[23];
  const float* ff_w2  = (const float*)d_in[24];
  const float* ff_b2  = (const float*)d_in[25];
  const float* dec_w1 = (const float*)d_in[26];
  const float* dec_b1 = (const float*)d_in[27];
  const float* bn3_g  = (const float*)d_in[28];
  const float* bn3_b  = (const float*)d_in[29];
  const float* dec_w2 = (const float*)d_in[30];
  const float* dec_b2 = (const float*)d_in[31];

  char* W = (char*)d_ws;

  // ---- fixed region (weights, ~12.2 MB; reserve 16 MB) ----
  bf16_t* weff = (bf16_t*)(W + 0);                     // 4*1280*256*2 = 2,621,440
  float*  beff = (float*)(W + 2621440);                // 20,480
  bf16_t* wot  = (bf16_t*)(W + 2641920);               // 524,288
  bf16_t* w1t  = (bf16_t*)(W + 3166208);               // 2,097,152
  bf16_t* w2t  = (bf16_t*)(W + 5263360);               // 2,097,152
  bf16_t* c2t  = (bf16_t*)(W + 7360512);               // 327,680
  bf16_t* d1t  = (bf16_t*)(W + 7688192);               // 327,680
  float*  pe   = (float*)(W + 8015872);                // 4,194,304
  float*  sc1  = (float*)(W + 12210176);
  float*  sb1  = (float*)(W + 12211200);
  float*  sc2  = (float*)(W + 12212224);
  float*  sb2  = (float*)(W + 12213248);
  float*  sc3  = (float*)(W + 12214272);
  float*  sb3  = (float*)(W + 12215296);
  const size_t FIXED_END = 16777216;

  // ---- pick batch chunk Bc so workspace fits ws_size ----
  // per-B: h 4MB + ao 2MB + big 10MB + pkv 512K + pks 16K + kvb 54K
  const size_t PER_B = 17440768;
  int Bc = 32;
  while (Bc > 1 && FIXED_END + (size_t)Bc * PER_B > ws_size) Bc >>= 1;

  char* P = W + FIXED_END;
  float*  h     = (float*)P;
  bf16_t* xa    = (bf16_t*)(P + (size_t)Bc * 4194304);
  bf16_t* ao    = xa;  // xa dead after fused qkv gemm; ao dead before ln2
  char*   big   = P + (size_t)Bc * (4194304 + 2097152);
  bf16_t* qpkpv = (bf16_t*)big;
  bf16_t* f1    = (bf16_t*)big;                               // after qpkpv dead
  bf16_t* h1p   = (bf16_t*)big;                               // pre-loop
  bf16_t* hpad  = (bf16_t*)big;                               // post-loop
  bf16_t* hdp   = (bf16_t*)(big + (size_t)Bc * 4100 * 256 * 2);
  float*  pkv   = (float*)(big + (size_t)Bc * 10485760);
  float*  pks   = (float*)((char*)pkv + (size_t)Bc * 524288);
  bf16_t* kvb   = (bf16_t*)((char*)pks + (size_t)Bc * 16384);

  // ---- weight prep (once) ----
  prep_weff<<<5120, 256, 0, stream>>>(wq, wk, wv, bq, bk, bv, rf, weff, beff);
  prep_cast_t32<<<256, 256, 0, stream>>>(wo, wot, 256, 256);
  prep_cast_t32<<<1024, 256, 0, stream>>>(ff_w1, w1t, 256, 1024);
  prep_cast_t32<<<1024, 256, 0, stream>>>(ff_w2, w2t, 1024, 256);
  prep_conv_t<<<640, 256, 0, stream>>>(emb_w2, c2t, 128, 5);
  prep_conv_t<<<640, 256, 0, stream>>>(dec_w1, d1t, 256, 5);
  prep_bn<<<1, 256, 0, stream>>>(bn1_g, bn1_b, emb_b1, bn2_g, bn2_b, emb_b2,
                                 bn3_g, bn3_b, dec_b1, sc1, sb1, sc2, sb2, sc3, sb3);
  pe_fill<<<4096, 256, 0, stream>>>(pe);

  for (int c0 = 0; c0 < 32; c0 += Bc) {
    const float* xc = x + (size_t)c0 * 4096;

    // ---- embedding (conv1 zeroes its own pad rows) ----
    conv1_kernel<<<Bc * 64, 256, 0, stream>>>(xc, emb_w1, sc1, sb1, h1p);
    gemm_bf16<3, 640, 64, 4><<<Bc * 128, 256, 0, stream>>>(
        h1p, c2t, h, sb2, sc2, nullptr, pe,
        128, 4100L * 128, 4096, 256, 256, 4096L * 256, 0);

    // ---- transformer layers ----
    for (int l = 0; l < 4; l++) {
      ln_kernel<<<Bc * 1024, 256, 0, stream>>>(h, ln1_g + l * 256, ln1_b + l * 256, xa);
      gemm_bf16<5, 256, 128, 10><<<Bc * 320, 256, 0, stream>>>(
          xa, weff + (long)l * 327680, qpkpv, beff + l * 1280, nullptr, nullptr, nullptr,
          256, 4096L * 256, 4096, 1280, 1280, 4096L * 1280, 0);
      kv_partial<<<Bc * 64, 256, 0, stream>>>(qpkpv, pkv, pks);
      kv_reduce_b<<<Bc * 8, 256, 0, stream>>>(pkv, pks, kvb);
      combine_mfma<<<Bc * 256, 256, 0, stream>>>(qpkpv, kvb, ao);
      gemm_bf16<1, 256, 64, 4><<<Bc * 128, 256, 0, stream>>>(
          ao, wot + (long)l * 65536, h, bo + l * 256, nullptr, h, nullptr,
          256, 4096L * 256, 4096, 256, 256, 4096L * 256, 0);
      ln_kernel<<<Bc * 1024, 256, 0, stream>>>(h, ln2_g + l * 256, ln2_b + l * 256, xa);
      gemm_bf16<2, 256, 128, 8><<<Bc * 256, 256, 0, stream>>>(
          xa, w1t + (long)l * 262144, f1, ff_b1 + l * 1024, nullptr, nullptr, nullptr,
          256, 4096L * 256, 4096, 1024, 1024, 4096L * 1024, 0);
      gemm_bf16<1, 1024, 64, 4><<<Bc * 128, 256, 0, stream>>>(
          f1, w2t + (long)l * 262144, h, ff_b2 + l * 256, nullptr, h, nullptr,
          1024, 4096L * 1024, 4096, 256, 256, 4096L * 256, 0);
    }

    // ---- decoder (cast_pad zeroes hpad + hdp pad rows) ----
    cast_pad<<<Bc * 512, 256, 0, stream>>>(h, hpad, hdp);
    gemm_bf16<4, 1280, 64, 2><<<Bc * 64, 256, 0, stream>>>(
        hpad, d1t, hdp, sb3, sc3, nullptr, nullptr,
        256, 4100L * 256, 4096, 128, 128, 4098L * 128, 1);
    conv_final<<<Bc * 64, 256, 0, stream>>>(hdp, dec_w2, dec_b2,
                                            (float*)d_out + (size_t)c0 * 4096);
  }
}

// Round 20
// 4061.603 us; speedup vs baseline: 1.5006x; 1.0116x over previous
//
#include <hip/hip_runtime.h>
#include <hip/hip_bf16.h>
#include <math.h>

// ============================================================================
// PPGPeakPerformer forward on MI355X (gfx950)
// B=32 S=4096 D=256 DH=128 H=8 HD=32 F=64 L=4
// r20 = r19 (best passing, 4109us) + two zero-risk granularity fixes:
//  - ln_kernel: 16 rows/block (grid /4), gamma/beta hoisted; same per-row
//    math, same XCD row-chunk map (matches QKV m-chunk map exactly)
//  - kv_reduce_b: 4x finer grid (quarter-panel per block), same summation
// Core unchanged: 128xBN GEMM (BN=128 wide, BN=64 narrow), BK=32, A triple-
// buffer depth-2 + counted vmcnt(2), B double-buffer, 40KB LDS, 4 blocks/CU,
// bijective XCD chunk-remap, both-sides swizzle, fast erf, fused q/k RF
// projection GEMM, kv_reduce_b -> combine vector-copy B-panel, no memsets,
// tiled weight transposes, conv_final 4-lane reduce. LN separate pass
// (LN-GEMM fusion numerically refuted r14/r15).
// ============================================================================

typedef __bf16 bf16_t;
typedef __bf16 bf16x8 __attribute__((ext_vector_type(8)));
typedef __bf16 bf16x4 __attribute__((ext_vector_type(4)));
typedef float  f32x4  __attribute__((ext_vector_type(4)));

#define DEV __device__ __forceinline__

DEV float erf_fast(float x) {
  float ax = fabsf(x);
  float t = __builtin_amdgcn_rcpf(1.f + 0.3275911f * ax);
  float p = t * (0.254829592f + t * (-0.284496736f + t * (1.421413741f +
            t * (-1.453152027f + t * 1.061405429f))));
  float r = 1.f - p * __expf(-ax * ax);
  return copysignf(r, x);
}
DEV float geluf(float v) { return 0.5f * v * (1.f + erf_fast(v * 0.70710678118654752440f)); }
DEV float softplusf(float v) {
  float e = __expf(-fabsf(v));
  return fmaxf(v, 0.f) + __logf(1.f + e);
}

// Direct global->LDS 16B staging. LDS dest is wave-uniform base + lane*16.
DEV void gload16(const bf16_t* g, bf16_t* l) {
  __builtin_amdgcn_global_load_lds(
      (const __attribute__((address_space(1))) void*)g,
      (__attribute__((address_space(3))) void*)l, 16, 0, 0);
}

// ---------------------------------------------------------------------------
// GEMM: C[m,n] = sum_k A[m,k]*Bt[n,k].  A bf16 (batched rows), Bt bf16 [N][K].
// EPI: 1 = +bias +resid -> fp32; 2 = gelu(+bias) -> bf16;
//      3 = gelu(scale*x+bias)+pe -> fp32; 4 = gelu(scale*x+bias) -> bf16;
//      5 = tile<1024 ? softplus(+bias) : (+bias) -> bf16 (block-uniform)
// Pipeline per iter t:
//   wait vmcnt(2); s_barrier; stage B(t+1); stage A(t+2); ds_read; MFMA.
// A slack ~2 iters (HBM-ok), B slack ~1 iter (L2-ok).
// ---------------------------------------------------------------------------
template <int EPI, int K, int BN, int NTL>
__global__ __launch_bounds__(256, 4)
void gemm_bf16(const bf16_t* __restrict__ A, const bf16_t* __restrict__ Bt,
               void* Cout, const float* __restrict__ bias,
               const float* __restrict__ scale, const float* resid,
               const float* __restrict__ pe,
               int lda, long a_bstride, int rpb,
               int N, int ldc, long c_bstride, int c_roff)
{
  constexpr int MI = (BN == 128) ? 4 : 2;   // row-fragments per wave
  __shared__ bf16_t As[3][128 * 32];
  __shared__ bf16_t Bs[2][BN * 32];
  const int t = threadIdx.x;
  const int lane = t & 63;
  const int w = t >> 6;
  const int wrow = (BN == 128) ? (w >> 1) * 64 : w * 32;
  const int wcol = (BN == 128) ? (w & 1) * 64 : 0;

  // XCD-aware bijective remap (m204): bid%8 -> XCD; XCD k gets a contiguous
  // wgid chunk (n-tile fastest) so A-tile sharers co-reside on one L2.
  const int nwg = gridDim.x;
  const int q_ = nwg >> 3, r_ = nwg & 7;
  const int xcd = blockIdx.x & 7, idx_ = blockIdx.x >> 3;
  const int wgid = (xcd < r_ ? xcd * (q_ + 1) : r_ * (q_ + 1) + (xcd - r_) * q_) + idx_;
  const long m0 = (long)(wgid / NTL) * 128;
  const int n0 = (wgid % NTL) * BN;

  const int b = (int)(m0 / rpb);
  const int s_base = (int)(m0 % rpb);
  const bf16_t* Ab = A + (long)b * a_bstride + (long)s_base * lda;
  const bf16_t* Bb = Bt + (long)n0 * K;

  // staging source (pre-swizzled): lane covers row (lane>>2) of a 16-row
  // block, 16B slot ((lane&3) ^ ((row>>1)&3)).
  const int srow = lane >> 2;
  const int sslot = (lane & 3) ^ ((srow >> 1) & 3);
  const bf16_t* aS = Ab + (long)(w * 32 + srow) * lda + sslot * 8;
  const bf16_t* bS = Bb + (long)(w * 32 + srow) * K + sslot * 8;
  const int dsto = w * 1024;  // 32 rows x 32 elems per wave

#define STAGE_A(bufidx, kk)                                 \
  {                                                         \
    bf16_t* a_ = &As[bufidx][dsto];                         \
    gload16(aS + (kk), a_);                                 \
    gload16(aS + (kk) + 16 * (long)lda, a_ + 512);          \
  }
#define STAGE_B(bufidx, kk)                                 \
  if (BN == 128 || w < 2) {                                 \
    bf16_t* b_ = &Bs[bufidx][dsto];                         \
    gload16(bS + (kk), b_);                                 \
    gload16(bS + (kk) + 16 * (long)K, b_ + 512);            \
  }

  f32x4 acc[MI][4];
#pragma unroll
  for (int i = 0; i < MI; i++)
#pragma unroll
    for (int j = 0; j < 4; j++) acc[i][j] = (f32x4){0.f, 0.f, 0.f, 0.f};

  constexpr int NT = K >> 5;
  // prologue queue order: A(0), B(0), A(1) -> wait vmcnt(2) drains A0,B0.
  STAGE_A(0, 0);
  STAGE_B(0, 0);
  if (NT > 1) STAGE_A(1, 32);

#pragma unroll
  for (int tt = 0; tt < NT; ++tt) {
    if (tt + 1 < NT) {
      asm volatile("s_waitcnt vmcnt(2)" ::: "memory");
    } else {
      asm volatile("s_waitcnt vmcnt(0)" ::: "memory");
    }
    __builtin_amdgcn_s_barrier();
    __builtin_amdgcn_sched_barrier(0);
    if (tt + 1 < NT) STAGE_B((tt + 1) & 1, (tt + 1) * 32);
    if (tt + 2 < NT) STAGE_A((tt + 2) % 3, (tt + 2) * 32);
    const bf16_t* Acur = As[tt % 3];
    const bf16_t* Bcur = Bs[tt & 1];
    const int kb = (lane >> 4) * 16;
    bf16x8 af[MI], bfr[4];
#pragma unroll
    for (int i = 0; i < MI; i++) {
      int rA = wrow + i * 16 + (lane & 15);
      af[i] = *(const bf16x8*)((const char*)Acur + rA * 64 + (kb ^ (((rA >> 1) & 3) << 4)));
    }
#pragma unroll
    for (int j = 0; j < 4; j++) {
      int rB = wcol + j * 16 + (lane & 15);
      bfr[j] = *(const bf16x8*)((const char*)Bcur + rB * 64 + (kb ^ (((rB >> 1) & 3) << 4)));
    }
    __builtin_amdgcn_s_setprio(1);
#pragma unroll
    for (int mi = 0; mi < MI; mi++)
#pragma unroll
      for (int ni = 0; ni < 4; ni++)
        acc[mi][ni] = __builtin_amdgcn_mfma_f32_16x16x32_bf16(af[mi], bfr[ni], acc[mi][ni], 0, 0, 0);
    __builtin_amdgcn_s_setprio(0);
  }
#undef STAGE_A
#undef STAGE_B

  const int colbase = n0 + wcol + (lane & 15);
  float bias_r[4], scale_r[4];
#pragma unroll
  for (int ni = 0; ni < 4; ni++) {
    int col = colbase + ni * 16;
    bias_r[ni] = bias[col];
    scale_r[ni] = (EPI == 3 || EPI == 4) ? scale[col] : 0.f;
  }
  // EPI 5: softplus applies to the whole 64-col warp-tile or none of it
  // (tile boundary at col 1024 is 64-aligned) -> wave-uniform branch.
  const bool spAll = (EPI == 5) && ((n0 + wcol) < 1024);
#pragma unroll
  for (int mi = 0; mi < MI; mi++) {
#pragma unroll
    for (int j = 0; j < 4; j++) {
      int row = wrow + mi * 16 + ((lane >> 4) << 2) + j;
      long s = s_base + row;
      long cro = (long)b * c_bstride + (s + c_roff) * (long)ldc;
#pragma unroll
      for (int ni = 0; ni < 4; ni++) {
        int col = colbase + ni * 16;
        float v = acc[mi][ni][j];
        if constexpr (EPI == 1) {
          v += bias_r[ni] + resid[cro + col];
          ((float*)Cout)[cro + col] = v;
        } else if constexpr (EPI == 2) {
          v = geluf(v + bias_r[ni]);
          ((bf16_t*)Cout)[cro + col] = (bf16_t)v;
        } else if constexpr (EPI == 3) {
          v = geluf(v * scale_r[ni] + bias_r[ni]) + pe[s * 256 + col];
          ((float*)Cout)[cro + col] = v;
        } else if constexpr (EPI == 4) {
          v = geluf(v * scale_r[ni] + bias_r[ni]);
          ((bf16_t*)Cout)[cro + col] = (bf16_t)v;
        } else {  // 5
          v += bias_r[ni];
          if (spAll) v = softplusf(v);
          ((bf16_t*)Cout)[cro + col] = (bf16_t)v;
        }
      }
    }
  }
}

// ---------------------------------------------------------------------------
// LayerNorm over D=256, fp32 in -> bf16 out. 16 rows/block (4 waves x 4
// iterations), gamma/beta hoisted. Same per-row math as before.
// XCD chunk-remap: XCD k owns contiguous rows, matching GEMM m-chunk map.
// ---------------------------------------------------------------------------
__global__ __launch_bounds__(256)
void ln_kernel(const float* __restrict__ h, const float* __restrict__ g,
               const float* __restrict__ bta, bf16_t* __restrict__ out)
{
  int t = threadIdx.x;
  int lane = t & 63;
  const int G = gridDim.x;                 // divisible by 8
  const int wgid = (blockIdx.x & 7) * (G >> 3) + (blockIdx.x >> 3);
  const long row0 = (long)wgid * 16 + (t >> 6);
  const int c = lane * 4;
  const float4 gv = *(const float4*)(g + c);
  const float4 bv = *(const float4*)(bta + c);
#pragma unroll
  for (int it = 0; it < 4; ++it) {
    long row = row0 + it * 4;
    const float* hp = h + row * 256 + c;
    float4 v = *(const float4*)hp;
    float s = v.x + v.y + v.z + v.w;
    float q = v.x * v.x + v.y * v.y + v.z * v.z + v.w * v.w;
#pragma unroll
    for (int m = 32; m >= 1; m >>= 1) {
      s += __shfl_xor(s, m);
      q += __shfl_xor(q, m);
    }
    float mean = s * 0.00390625f;
    float var = q * 0.00390625f - mean * mean;
    float rstd = rsqrtf(var + 1e-5f);
    bf16x4 o;
    o[0] = (bf16_t)((v.x - mean) * rstd * gv.x + bv.x);
    o[1] = (bf16_t)((v.y - mean) * rstd * gv.y + bv.y);
    o[2] = (bf16_t)((v.z - mean) * rstd * gv.z + bv.z);
    o[3] = (bf16_t)((v.w - mean) * rstd * gv.w + bv.w);
    *(bf16x4*)(out + row * 256 + c) = o;
  }
}

// ---------------------------------------------------------------------------
// Embedding conv1: x[Bc,S] -> gelu(bn(conv1d k=7 pad=3)) -> h1p[Bc,S+4,128]
// Also zeroes h1p pad rows (0,1 at s0==0; 4098,4099 at s0==4032).
// ---------------------------------------------------------------------------
__global__ __launch_bounds__(256)
void conv1_kernel(const float* __restrict__ x, const float* __restrict__ w1,
                  const float* __restrict__ sc, const float* __restrict__ sb,
                  bf16_t* __restrict__ h1p)
{
  int b = blockIdx.x >> 6;
  int s0 = (blockIdx.x & 63) << 6;
  __shared__ float xs[70];
  __shared__ float ws[896];
  int t = threadIdx.x;
  if (t < 70) {
    int s = s0 + t - 3;
    xs[t] = (s >= 0 && s < 4096) ? x[(long)b * 4096 + s] : 0.f;
  }
  for (int i = t; i < 896; i += 256) ws[i] = w1[i];
  // zero pad rows (disjoint from data rows 2..4097)
  if (s0 == 0)
    h1p[((long)b * 4100 + (t >> 7)) * 128 + (t & 127)] = (bf16_t)0.f;
  if (s0 == 4032)
    h1p[((long)b * 4100 + 4098 + (t >> 7)) * 128 + (t & 127)] = (bf16_t)0.f;
  __syncthreads();
  int c = t & 127, so = t >> 7;
  float wr[7];
#pragma unroll
  for (int k = 0; k < 7; k++) wr[k] = ws[c * 7 + k];
  float scl = sc[c], sbv = sb[c];
  for (int p = 0; p < 32; p++) {
    int sl = p * 2 + so;
    float a = 0.f;
#pragma unroll
    for (int k = 0; k < 7; k++) a += xs[sl + k] * wr[k];
    a = geluf(a * scl + sbv);
    h1p[((long)b * 4100 + s0 + sl + 2) * 128 + c] = (bf16_t)a;
  }
}

// ---------------------------------------------------------------------------
// kv partial: per (b,h,chunk of 512 s): acc[f][d] += kp[s,f]*v[s,d]; +ksum.
// ---------------------------------------------------------------------------
__global__ __launch_bounds__(256)
void kv_partial(const bf16_t* __restrict__ qpkpv,
                float* __restrict__ pkv, float* __restrict__ pks)
{
  int bh = blockIdx.x >> 3, ch = blockIdx.x & 7;
  int b = bh >> 3, hh = bh & 7;
  int s0 = ch * 512;
  __shared__ float kps[32 * 64];
  __shared__ float vs[32 * 32];
  int t = threadIdx.x;
  int f = t & 63, dg = t >> 6;
  float acc[8] = {0.f, 0.f, 0.f, 0.f, 0.f, 0.f, 0.f, 0.f};
  float ks = 0.f;
  const int row = t >> 3, slot8 = (t & 7) * 8, slot4 = (t & 7) * 4;
  for (int sb = 0; sb < 512; sb += 32) {
    __syncthreads();
    {
      const bf16_t* rowp = qpkpv + ((long)b * 4096 + s0 + sb + row) * 1280;
      bf16x8 k8 = *(const bf16x8*)(rowp + 512 + hh * 64 + slot8);
#pragma unroll
      for (int j = 0; j < 8; j++) kps[row * 64 + slot8 + j] = (float)k8[j];
      bf16x4 v4 = *(const bf16x4*)(rowp + 1024 + hh * 32 + slot4);
#pragma unroll
      for (int j = 0; j < 4; j++) vs[row * 32 + slot4 + j] = (float)v4[j];
    }
    __syncthreads();
#pragma unroll 4
    for (int s = 0; s < 32; s++) {
      float kval = kps[s * 64 + f];
      float4 v0 = *(const float4*)&vs[s * 32 + dg * 8];
      float4 v1 = *(const float4*)&vs[s * 32 + dg * 8 + 4];
      acc[0] += kval * v0.x; acc[1] += kval * v0.y;
      acc[2] += kval * v0.z; acc[3] += kval * v0.w;
      acc[4] += kval * v1.x; acc[5] += kval * v1.y;
      acc[6] += kval * v1.z; acc[7] += kval * v1.w;
      ks += kval;
    }
  }
  long o = (long)blockIdx.x * 2048 + f * 32 + dg * 8;
#pragma unroll
  for (int j = 0; j < 8; j++) pkv[o + j] = acc[j];
  if (dg == 0) pks[blockIdx.x * 64 + f] = ks;
}

// ---------------------------------------------------------------------------
// kv_reduce_b: reduce the 8 chunk-partials into the exact [48][72] bf16
// B-panel layout combine_mfma stages (rows 0..31 = kv^T, row 32 = ksum,
// rows 33..47 + pad cols = 0). Same fp32 summation order as before ->
// bit-identical values. 4 blocks per bh (quarter-panel each) for latency.
// ---------------------------------------------------------------------------
__global__ __launch_bounds__(256)
void kv_reduce_b(const float* __restrict__ pkv, const float* __restrict__ pks,
                 bf16_t* __restrict__ kvb)
{
  int bh = blockIdx.x >> 2;
  int quarter = blockIdx.x & 3;
  int base = quarter * 864;                // 3456/4
  int t = threadIdx.x;
  for (int i = base + t; i < base + 864; i += 256) {
    int n = i / 72, f = i % 72;
    float s = 0.f;
    if (f < 64) {
      if (n < 32) {
#pragma unroll
        for (int ch = 0; ch < 8; ch++)
          s += pkv[((long)(bh * 8 + ch)) * 2048 + f * 32 + n];
      } else if (n == 32) {
#pragma unroll
        for (int ch = 0; ch < 8; ch++)
          s += pks[(bh * 8 + ch) * 64 + f];
      }
    }
    kvb[(long)bh * 3456 + i] = (bf16_t)s;
  }
}

// ---------------------------------------------------------------------------
// combine: ao[s, h*32+d] = (qp[s,:] @ kv[:,d]) / (qp[s,:]@ksum + 1e-8)
// B-panel comes precomputed from kv_reduce_b (straight vector copy to LDS).
// ---------------------------------------------------------------------------
__global__ __launch_bounds__(256, 4)
void combine_mfma(const bf16_t* __restrict__ qpkpv, const bf16_t* __restrict__ kvb,
                  bf16_t* __restrict__ ao)
{
  int bh = blockIdx.x >> 5;
  int s0 = (blockIdx.x & 31) << 7;
  int b = bh >> 3, hh = bh & 7;
  __shared__ bf16_t A_s[128 * 72];
  __shared__ bf16_t B_s[48 * 72];
  int t = threadIdx.x;
  for (int g = t; g < 1024; g += 256) {
    int row = g >> 3, slot = (g & 7) * 8;
    *(bf16x8*)&A_s[row * 72 + slot] =
        *(const bf16x8*)(qpkpv + ((long)b * 4096 + s0 + row) * 1280 + hh * 64 + slot);
  }
  {
    const bf16x8* kv8 = (const bf16x8*)(kvb + (long)bh * 3456);
    for (int i = t; i < 432; i += 256)
      ((bf16x8*)B_s)[i] = kv8[i];
  }
  __syncthreads();
  int lane = t & 63, w = t >> 6;
  f32x4 acc[2][3];
#pragma unroll
  for (int i = 0; i < 2; i++)
#pragma unroll
    for (int j = 0; j < 3; j++) acc[i][j] = (f32x4){0.f, 0.f, 0.f, 0.f};
#pragma unroll
  for (int kt = 0; kt < 2; kt++) {
    int ko = kt * 32 + (lane >> 4) * 8;
    bf16x8 a[2], bb[3];
#pragma unroll
    for (int i = 0; i < 2; i++)
      a[i] = *(const bf16x8*)&A_s[(w * 32 + i * 16 + (lane & 15)) * 72 + ko];
#pragma unroll
    for (int i = 0; i < 3; i++)
      bb[i] = *(const bf16x8*)&B_s[(i * 16 + (lane & 15)) * 72 + ko];
#pragma unroll
    for (int mi = 0; mi < 2; mi++)
#pragma unroll
      for (int ni = 0; ni < 3; ni++)
        acc[mi][ni] = __builtin_amdgcn_mfma_f32_16x16x32_bf16(a[mi], bb[ni], acc[mi][ni], 0, 0, 0);
  }
  long sbase = (long)b * 4096 + s0;
#pragma unroll
  for (int mi = 0; mi < 2; mi++)
#pragma unroll
    for (int j = 0; j < 4; j++) {
      int r = w * 32 + mi * 16 + ((lane >> 4) << 2) + j;
      float den = __shfl(acc[mi][2][j], (lane & 48)) + 1e-8f;
#pragma unroll
      for (int ni = 0; ni < 2; ni++) {
        int d = ni * 16 + (lane & 15);
        ao[(sbase + r) * 256 + hh * 32 + d] = (bf16_t)(acc[mi][ni][j] / den);
      }
    }
}

// ---------------------------------------------------------------------------
// h fp32 -> h_padded bf16 [Bc, S+4, 256] (rows offset +2). Also zeroes the
// hpad pad rows (0,1,4098,4099) and hdp pad rows (0,4097) per batch.
// ---------------------------------------------------------------------------
__global__ __launch_bounds__(256)
void cast_pad(const float* __restrict__ h, bf16_t* __restrict__ hp,
              bf16_t* __restrict__ hdp)
{
  long gid = (long)blockIdx.x * 256 + threadIdx.x;
  const int Bc = gridDim.x >> 9;           // grid = Bc*512
  if (gid < (long)Bc * 160) {
    int b = (int)(gid / 160);
    int r = (int)(gid % 160);
    bf16x8 z;
#pragma unroll
    for (int j = 0; j < 8; j++) z[j] = (bf16_t)0.f;
    if (r < 128) {
      int rr = r >> 5;                     // 0..3
      int row = (rr < 2) ? rr : 4096 + rr; // 0,1,4098,4099
      *(bf16x8*)(hp + ((long)b * 4100 + row) * 256 + (r & 31) * 8) = z;
    } else {
      int r2 = r - 128;                    // 0..31
      int row = (r2 >> 4) ? 4097 : 0;      // 0,4097
      *(bf16x8*)(hdp + ((long)b * 4098 + row) * 128 + (r2 & 15) * 8) = z;
    }
  }
  long i8 = gid * 8;
  long r = i8 >> 8;
  int c = (int)(i8 & 255);
  int b = (int)(r >> 12), s = (int)(r & 4095);
  float4 v0 = *(const float4*)(h + i8);
  float4 v1 = *(const float4*)(h + i8 + 4);
  bf16x8 o;
  o[0] = (bf16_t)v0.x; o[1] = (bf16_t)v0.y; o[2] = (bf16_t)v0.z; o[3] = (bf16_t)v0.w;
  o[4] = (bf16_t)v1.x; o[5] = (bf16_t)v1.y; o[6] = (bf16_t)v1.z; o[7] = (bf16_t)v1.w;
  *(bf16x8*)(hp + ((long)b * 4100 + s + 2) * 256 + c) = o;
}

// ---------------------------------------------------------------------------
// Final conv (DH->1, k=3, pad=1) + sigmoid -> out [Bc,S] fp32.
// 4 lanes per output (partial sums + shfl reduce); grid Bc*64 blocks.
// ---------------------------------------------------------------------------
__global__ __launch_bounds__(256)
void conv_final(const bf16_t* __restrict__ hdp, const float* __restrict__ w2,
                const float* __restrict__ b2, float* __restrict__ out)
{
  __shared__ float ws[384];
  int t = threadIdx.x;
  for (int i = t; i < 384; i += 256) ws[i] = w2[i];  // [c][k]
  __syncthreads();
  int part = t & 3;
  long idx = (long)blockIdx.x * 64 + (t >> 2);
  int b = (int)(idx >> 12);
  const bf16_t* base = hdp + ((long)b * 4098 + (idx & 4095)) * 128;
  float a = 0.f;
#pragma unroll
  for (int k = 0; k < 3; k++) {
#pragma unroll
    for (int cc = 0; cc < 4; cc++) {
      int c8 = part + cc * 4;
      bf16x8 v = *(const bf16x8*)(base + k * 128 + c8 * 8);
#pragma unroll
      for (int j = 0; j < 8; j++) a += (float)v[j] * ws[(c8 * 8 + j) * 3 + k];
    }
  }
  a += __shfl_xor(a, 1);
  a += __shfl_xor(a, 2);
  if (part == 0) out[idx] = 1.f / (1.f + __expf(-(a + b2[0])));
}

// ---------------------------------------------------------------------------
// Prep kernels (once per launch)
// ---------------------------------------------------------------------------
__global__ __launch_bounds__(256)
void prep_weff(const float* __restrict__ wq, const float* __restrict__ wk,
               const float* __restrict__ wv, const float* __restrict__ bq,
               const float* __restrict__ bk, const float* __restrict__ bv,
               const float* __restrict__ rf, bf16_t* __restrict__ weff,
               float* __restrict__ beff)
{
  long idx = (long)blockIdx.x * 256 + threadIdx.x;  // 4*1280*256
  int d = (int)(idx & 255);
  long r = idx >> 8;
  int n = (int)(r % 1280);
  int l = (int)(r / 1280);
  float val;
  if (n < 1024) {
    int qk = n >> 9;
    int h = (n >> 6) & 7;
    int f = n & 63;
    const float* w = qk ? wk : wq;
    const float* rfh = rf + ((long)(l * 8 + h) * 32) * 64 + f;
    const float* wrow = w + ((long)l * 256 + d) * 256 + h * 32;
    float s = 0.f;
#pragma unroll
    for (int hd = 0; hd < 32; hd++) s += wrow[hd] * rfh[hd * 64];
    val = s;
  } else {
    val = wv[((long)l * 256 + d) * 256 + (n - 1024)];
  }
  weff[idx] = (bf16_t)val;
  if (idx < 4 * 1280) {
    int nn = (int)(idx % 1280);
    int ll = (int)(idx / 1280);
    float bvv;
    if (nn < 1024) {
      int qk = nn >> 9;
      int h = (nn >> 6) & 7;
      int f = nn & 63;
      const float* bsrc = qk ? bk : bq;
      float s = 0.f;
      for (int hd = 0; hd < 32; hd++)
        s += bsrc[ll * 256 + h * 32 + hd] * rf[((long)(ll * 8 + h) * 32 + hd) * 64 + f];
      bvv = s;
    } else {
      bvv = bv[ll * 256 + (nn - 1024)];
    }
    beff[idx] = bvv;
  }
}

// 32x32 LDS-tiled transpose+cast: src fp32 [l][K][N] -> dst bf16 [l][N][K].
__global__ __launch_bounds__(256)
void prep_cast_t32(const float* __restrict__ src, bf16_t* __restrict__ dst,
                   int K, int N)
{
  __shared__ float tile[32][33];
  const int kt = K >> 5, nt = N >> 5;
  int bid = blockIdx.x;
  int l = bid / (kt * nt);
  int rem = bid % (kt * nt);
  int ntile = rem / kt;          // n-tile index
  int ktile = rem % kt;          // k-tile index
  int n0 = ntile * 32, k0 = ktile * 32;
  int t = threadIdx.x;
  int c = t & 31, rbase = t >> 5;  // 8 rows per pass
#pragma unroll
  for (int i = 0; i < 4; i++) {
    int r = rbase + i * 8;
    tile[r][c] = src[((long)l * K + k0 + r) * N + n0 + c];
  }
  __syncthreads();
#pragma unroll
  for (int i = 0; i < 4; i++) {
    int r = rbase + i * 8;
    dst[((long)l * N + n0 + r) * K + k0 + c] = (bf16_t)tile[c][r];
  }
}

__global__ __launch_bounds__(256)
void prep_conv_t(const float* __restrict__ w, bf16_t* __restrict__ dst, int C, int KW)
{
  long idx = (long)blockIdx.x * 256 + threadIdx.x;  // O*C*KW
  int ckw = C * KW;
  int kk = (int)(idx % ckw);
  int o = (int)(idx / ckw);
  int kw = kk / C, c = kk % C;
  dst[idx] = (bf16_t)w[((long)o * C + c) * KW + kw];
}

__global__ __launch_bounds__(256)
void prep_bn(const float* g1, const float* b1, const float* cb1,
             const float* g2, const float* b2, const float* cb2,
             const float* g3, const float* b3, const float* cb3,
             float* sc1, float* sb1, float* sc2, float* sb2,
             float* sc3, float* sb3)
{
  int t = threadIdx.x;
  const float r = rsqrtf(1.f + 1e-5f);
  if (t < 128) { float s = g1[t] * r; sc1[t] = s; sb1[t] = cb1[t] * s + b1[t]; }
  if (t < 256) { float s = g2[t] * r; sc2[t] = s; sb2[t] = cb2[t] * s + b2[t]; }
  if (t < 128) { float s = g3[t] * r; sc3[t] = s; sb3[t] = cb3[t] * s + b3[t]; }
}

__global__ __launch_bounds__(256)
void pe_fill(float* __restrict__ pe)
{
  long idx = (long)blockIdx.x * 256 + threadIdx.x;  // 4096*256
  int dcol = (int)(idx & 255);
  int s = (int)(idx >> 8);
  int i2 = dcol >> 1;
  float freq = expf(-9.210340371976184f * (float)(2 * i2) / 256.f);
  float a = (float)s * freq;
  pe[idx] = (dcol & 1) ? cosf(a) : sinf(a);
}

// ---------------------------------------------------------------------------
extern "C" void kernel_launch(void* const* d_in, const int* in_sizes, int n_in,
                              void* d_out, int out_size, void* d_ws, size_t ws_size,
                              hipStream_t stream)
{
  (void)in_sizes; (void)n_in; (void)out_size;
  const float* x      = (const float*)d_in[0];
  const float* emb_w1 = (const float*)d_in[1];
  const float* emb_b1 = (const float*)d_in[2];
  const float* bn1_g  = (const float*)d_in[3];
  const float* bn1_b  = (const float*)d_in[4];
  const float* emb_w2 = (const float*)d_in[5];
  const float* emb_b2 = (const float*)d_in[6];
  const float* bn2_g  = (const float*)d_in[7];
  const float* bn2_b  = (const float*)d_in[8];
  const float* wq     = (const float*)d_in[9];
  const float* bq     = (const float*)d_in[10];
  const float* wk     = (const float*)d_in[11];
  const float* bk     = (const float*)d_in[12];
  const float* wv     = (const float*)d_in[13];
  const float* bv     = (const float*)d_in[14];
  const float* wo     = (const float*)d_in[15];
  const float* bo     = (const float*)d_in[16];
  const float* rf     = (const float*)d_in[17];
  const float* ln1_g  = (const float*)d_in[18];
  const float* ln1_b  = (const float*)d_in[19];
  const float* ln2_g  = (const float*)d_in[20];
  const float* ln2_b  = (const float*)d_in[21];
  const float* ff_w1  = (const float*)d_in[22];
  const float* ff_b1  = (const float*)d_in[23];
  const float* ff_w2  = (const float*)d_in[24];
  const float* ff_b2  = (const float*)d_in[25];
  const float* dec_w1 = (const float*)d_in[26];
  const float* dec_b1 = (const float*)d_in[27];
  const float* bn3_g  = (const float*)d_in[28];
  const float* bn3_b  = (const float*)d_in[29];
  const float* dec_w2 = (const float*)d_in[30];
  const float* dec_b2 = (const float*)d_in[31];

  char* W = (char*)d_ws;

  // ---- fixed region (weights, ~12.2 MB; reserve 16 MB) ----
  bf16_t* weff = (bf16_t*)(W + 0);                     // 4*1280*256*2 = 2,621,440
  float*  beff = (float*)(W + 2621440);                // 20,480
  bf16_t* wot  = (bf16_t*)(W + 2641920);               // 524,288
  bf16_t* w1t  = (bf16_t*)(W + 3166208);               // 2,097,152
  bf16_t* w2t  = (bf16_t*)(W + 5263360);               // 2,097,152
  bf16_t* c2t  = (bf16_t*)(W + 7360512);               // 327,680
  bf16_t* d1t  = (bf16_t*)(W + 7688192);               // 327,680
  float*  pe   = (float*)(W + 8015872);                // 4,194,304
  float*  sc1  = (float*)(W + 12210176);
  float*  sb1  = (float*)(W + 12211200);
  float*  sc2  = (float*)(W + 12212224);
  float*  sb2  = (float*)(W + 12213248);
  float*  sc3  = (float*)(W + 12214272);
  float*  sb3  = (float*)(W + 12215296);
  const size_t FIXED_END = 16777216;

  // ---- pick batch chunk Bc so workspace fits ws_size ----
  // per-B: h 4MB + ao 2MB + big 10MB + pkv 512K + pks 16K + kvb 54K
  const size_t PER_B = 17440768;
  int Bc = 32;
  while (Bc > 1 && FIXED_END + (size_t)Bc * PER_B > ws_size) Bc >>= 1;

  char* P = W + FIXED_END;
  float*  h     = (float*)P;
  bf16_t* xa    = (bf16_t*)(P + (size_t)Bc * 4194304);
  bf16_t* ao    = xa;  // xa dead after fused qkv gemm; ao dead before ln2
  char*   big   = P + (size_t)Bc * (4194304 + 2097152);
  bf16_t* qpkpv = (bf16_t*)big;
  bf16_t* f1    = (bf16_t*)big;                               // after qpkpv dead
  bf16_t* h1p   = (bf16_t*)big;                               // pre-loop
  bf16_t* hpad  = (bf16_t*)big;                               // post-loop
  bf16_t* hdp   = (bf16_t*)(big + (size_t)Bc * 4100 * 256 * 2);
  float*  pkv   = (float*)(big + (size_t)Bc * 10485760);
  float*  pks   = (float*)((char*)pkv + (size_t)Bc * 524288);
  bf16_t* kvb   = (bf16_t*)((char*)pks + (size_t)Bc * 16384);

  // ---- weight prep (once) ----
  prep_weff<<<5120, 256, 0, stream>>>(wq, wk, wv, bq, bk, bv, rf, weff, beff);
  prep_cast_t32<<<256, 256, 0, stream>>>(wo, wot, 256, 256);
  prep_cast_t32<<<1024, 256, 0, stream>>>(ff_w1, w1t, 256, 1024);
  prep_cast_t32<<<1024, 256, 0, stream>>>(ff_w2, w2t, 1024, 256);
  prep_conv_t<<<640, 256, 0, stream>>>(emb_w2, c2t, 128, 5);
  prep_conv_t<<<640, 256, 0, stream>>>(dec_w1, d1t, 256, 5);
  prep_bn<<<1, 256, 0, stream>>>(bn1_g, bn1_b, emb_b1, bn2_g, bn2_b, emb_b2,
                                 bn3_g, bn3_b, dec_b1, sc1, sb1, sc2, sb2, sc3, sb3);
  pe_fill<<<4096, 256, 0, stream>>>(pe);

  for (int c0 = 0; c0 < 32; c0 += Bc) {
    const float* xc = x + (size_t)c0 * 4096;

    // ---- embedding (conv1 zeroes its own pad rows) ----
    conv1_kernel<<<Bc * 64, 256, 0, stream>>>(xc, emb_w1, sc1, sb1, h1p);
    gemm_bf16<3, 640, 64, 4><<<Bc * 128, 256, 0, stream>>>(
        h1p, c2t, h, sb2, sc2, nullptr, pe,
        128, 4100L * 128, 4096, 256, 256, 4096L * 256, 0);

    // ---- transformer layers ----
    for (int l = 0; l < 4; l++) {
      ln_kernel<<<Bc * 256, 256, 0, stream>>>(h, ln1_g + l * 256, ln1_b + l * 256, xa);
      gemm_bf16<5, 256, 128, 10><<<Bc * 320, 256, 0, stream>>>(
          xa, weff + (long)l * 327680, qpkpv, beff + l * 1280, nullptr, nullptr, nullptr,
          256, 4096L * 256, 4096, 1280, 1280, 4096L * 1280, 0);
      kv_partial<<<Bc * 64, 256, 0, stream>>>(qpkpv, pkv, pks);
      kv_reduce_b<<<Bc * 32, 256, 0, stream>>>(pkv, pks, kvb);
      combine_mfma<<<Bc * 256, 256, 0, stream>>>(qpkpv, kvb, ao);
      gemm_bf16<1, 256, 64, 4><<<Bc * 128, 256, 0, stream>>>(
          ao, wot + (long)l * 65536, h, bo + l * 256, nullptr, h, nullptr,
          256, 4096L * 256, 4096, 256, 256, 4096L * 256, 0);
      ln_kernel<<<Bc * 256, 256, 0, stream>>>(h, ln2_g + l * 256, ln2_b + l * 256, xa);
      gemm_bf16<2, 256, 128, 8><<<Bc * 256, 256, 0, stream>>>(
          xa, w1t + (long)l * 262144, f1, ff_b1 + l * 1024, nullptr, nullptr, nullptr,
          256, 4096L * 256, 4096, 1024, 1024, 4096L * 1024, 0);
      gemm_bf16<1, 1024, 64, 4><<<Bc * 128, 256, 0, stream>>>(
          f1, w2t + (long)l * 262144, h, ff_b2 + l * 256, nullptr, h, nullptr,
          1024, 4096L * 1024, 4096, 256, 256, 4096L * 256, 0);
    }

    // ---- decoder (cast_pad zeroes hpad + hdp pad rows) ----
    cast_pad<<<Bc * 512, 256, 0, stream>>>(h, hpad, hdp);
    gemm_bf16<4, 1280, 64, 2><<<Bc * 64, 256, 0, stream>>>(
        hpad, d1t, hdp, sb3, sc3, nullptr, nullptr,
        256, 4100L * 256, 4096, 128, 128, 4098L * 128, 1);
    conv_final<<<Bc * 64, 256, 0, stream>>>(hdp, dec_w2, dec_b2,
                                            (float*)d_out + (size_t)c0 * 4096);
  }
}

// Round 21
// 3824.081 us; speedup vs baseline: 1.5938x; 1.0621x over previous
//
#include <hip/hip_runtime.h>
#include <hip/hip_bf16.h>
#include <math.h>

// ============================================================================
// PPGPeakPerformer forward on MI355X (gfx950)
// B=32 S=4096 D=256 DH=128 H=8 HD=32 F=64 L=4
// r21 = r20 (best passing, 4062us) + kv_partial LDS double-buffer:
//   was 16 iters x 2 barriers with no load/compute overlap; now prefetch
//   tile t+1 into regs during compute of tile t, ONE barrier/iter.
//   Per-thread accumulation order unchanged -> bit-identical pkv/pks.
// Core unchanged: 128xBN GEMM (BN=128 wide, BN=64 narrow), BK=32, A triple-
// buffer depth-2 + counted vmcnt(2), B double-buffer, 40KB LDS, 4 blocks/CU,
// bijective XCD chunk-remap, both-sides swizzle, fast erf, fused q/k RF
// projection GEMM, kv_reduce_b -> combine vector-copy B-panel, no memsets,
// tiled weight transposes, conv_final 4-lane reduce, 16-row ln blocks.
// LN separate pass (LN-GEMM fusion numerically refuted r14/r15).
// ============================================================================

typedef __bf16 bf16_t;
typedef __bf16 bf16x8 __attribute__((ext_vector_type(8)));
typedef __bf16 bf16x4 __attribute__((ext_vector_type(4)));
typedef float  f32x4  __attribute__((ext_vector_type(4)));

#define DEV __device__ __forceinline__

DEV float erf_fast(float x) {
  float ax = fabsf(x);
  float t = __builtin_amdgcn_rcpf(1.f + 0.3275911f * ax);
  float p = t * (0.254829592f + t * (-0.284496736f + t * (1.421413741f +
            t * (-1.453152027f + t * 1.061405429f))));
  float r = 1.f - p * __expf(-ax * ax);
  return copysignf(r, x);
}
DEV float geluf(float v) { return 0.5f * v * (1.f + erf_fast(v * 0.70710678118654752440f)); }
DEV float softplusf(float v) {
  float e = __expf(-fabsf(v));
  return fmaxf(v, 0.f) + __logf(1.f + e);
}

// Direct global->LDS 16B staging. LDS dest is wave-uniform base + lane*16.
DEV void gload16(const bf16_t* g, bf16_t* l) {
  __builtin_amdgcn_global_load_lds(
      (const __attribute__((address_space(1))) void*)g,
      (__attribute__((address_space(3))) void*)l, 16, 0, 0);
}

// ---------------------------------------------------------------------------
// GEMM: C[m,n] = sum_k A[m,k]*Bt[n,k].  A bf16 (batched rows), Bt bf16 [N][K].
// EPI: 1 = +bias +resid -> fp32; 2 = gelu(+bias) -> bf16;
//      3 = gelu(scale*x+bias)+pe -> fp32; 4 = gelu(scale*x+bias) -> bf16;
//      5 = tile<1024 ? softplus(+bias) : (+bias) -> bf16 (block-uniform)
// Pipeline per iter t:
//   wait vmcnt(2); s_barrier; stage B(t+1); stage A(t+2); ds_read; MFMA.
// A slack ~2 iters (HBM-ok), B slack ~1 iter (L2-ok).
// ---------------------------------------------------------------------------
template <int EPI, int K, int BN, int NTL>
__global__ __launch_bounds__(256, 4)
void gemm_bf16(const bf16_t* __restrict__ A, const bf16_t* __restrict__ Bt,
               void* Cout, const float* __restrict__ bias,
               const float* __restrict__ scale, const float* resid,
               const float* __restrict__ pe,
               int lda, long a_bstride, int rpb,
               int N, int ldc, long c_bstride, int c_roff)
{
  constexpr int MI = (BN == 128) ? 4 : 2;   // row-fragments per wave
  __shared__ bf16_t As[3][128 * 32];
  __shared__ bf16_t Bs[2][BN * 32];
  const int t = threadIdx.x;
  const int lane = t & 63;
  const int w = t >> 6;
  const int wrow = (BN == 128) ? (w >> 1) * 64 : w * 32;
  const int wcol = (BN == 128) ? (w & 1) * 64 : 0;

  // XCD-aware bijective remap (m204): bid%8 -> XCD; XCD k gets a contiguous
  // wgid chunk (n-tile fastest) so A-tile sharers co-reside on one L2.
  const int nwg = gridDim.x;
  const int q_ = nwg >> 3, r_ = nwg & 7;
  const int xcd = blockIdx.x & 7, idx_ = blockIdx.x >> 3;
  const int wgid = (xcd < r_ ? xcd * (q_ + 1) : r_ * (q_ + 1) + (xcd - r_) * q_) + idx_;
  const long m0 = (long)(wgid / NTL) * 128;
  const int n0 = (wgid % NTL) * BN;

  const int b = (int)(m0 / rpb);
  const int s_base = (int)(m0 % rpb);
  const bf16_t* Ab = A + (long)b * a_bstride + (long)s_base * lda;
  const bf16_t* Bb = Bt + (long)n0 * K;

  // staging source (pre-swizzled): lane covers row (lane>>2) of a 16-row
  // block, 16B slot ((lane&3) ^ ((row>>1)&3)).
  const int srow = lane >> 2;
  const int sslot = (lane & 3) ^ ((srow >> 1) & 3);
  const bf16_t* aS = Ab + (long)(w * 32 + srow) * lda + sslot * 8;
  const bf16_t* bS = Bb + (long)(w * 32 + srow) * K + sslot * 8;
  const int dsto = w * 1024;  // 32 rows x 32 elems per wave

#define STAGE_A(bufidx, kk)                                 \
  {                                                         \
    bf16_t* a_ = &As[bufidx][dsto];                         \
    gload16(aS + (kk), a_);                                 \
    gload16(aS + (kk) + 16 * (long)lda, a_ + 512);          \
  }
#define STAGE_B(bufidx, kk)                                 \
  if (BN == 128 || w < 2) {                                 \
    bf16_t* b_ = &Bs[bufidx][dsto];                         \
    gload16(bS + (kk), b_);                                 \
    gload16(bS + (kk) + 16 * (long)K, b_ + 512);            \
  }

  f32x4 acc[MI][4];
#pragma unroll
  for (int i = 0; i < MI; i++)
#pragma unroll
    for (int j = 0; j < 4; j++) acc[i][j] = (f32x4){0.f, 0.f, 0.f, 0.f};

  constexpr int NT = K >> 5;
  // prologue queue order: A(0), B(0), A(1) -> wait vmcnt(2) drains A0,B0.
  STAGE_A(0, 0);
  STAGE_B(0, 0);
  if (NT > 1) STAGE_A(1, 32);

#pragma unroll
  for (int tt = 0; tt < NT; ++tt) {
    if (tt + 1 < NT) {
      asm volatile("s_waitcnt vmcnt(2)" ::: "memory");
    } else {
      asm volatile("s_waitcnt vmcnt(0)" ::: "memory");
    }
    __builtin_amdgcn_s_barrier();
    __builtin_amdgcn_sched_barrier(0);
    if (tt + 1 < NT) STAGE_B((tt + 1) & 1, (tt + 1) * 32);
    if (tt + 2 < NT) STAGE_A((tt + 2) % 3, (tt + 2) * 32);
    const bf16_t* Acur = As[tt % 3];
    const bf16_t* Bcur = Bs[tt & 1];
    const int kb = (lane >> 4) * 16;
    bf16x8 af[MI], bfr[4];
#pragma unroll
    for (int i = 0; i < MI; i++) {
      int rA = wrow + i * 16 + (lane & 15);
      af[i] = *(const bf16x8*)((const char*)Acur + rA * 64 + (kb ^ (((rA >> 1) & 3) << 4)));
    }
#pragma unroll
    for (int j = 0; j < 4; j++) {
      int rB = wcol + j * 16 + (lane & 15);
      bfr[j] = *(const bf16x8*)((const char*)Bcur + rB * 64 + (kb ^ (((rB >> 1) & 3) << 4)));
    }
    __builtin_amdgcn_s_setprio(1);
#pragma unroll
    for (int mi = 0; mi < MI; mi++)
#pragma unroll
      for (int ni = 0; ni < 4; ni++)
        acc[mi][ni] = __builtin_amdgcn_mfma_f32_16x16x32_bf16(af[mi], bfr[ni], acc[mi][ni], 0, 0, 0);
    __builtin_amdgcn_s_setprio(0);
  }
#undef STAGE_A
#undef STAGE_B

  const int colbase = n0 + wcol + (lane & 15);
  float bias_r[4], scale_r[4];
#pragma unroll
  for (int ni = 0; ni < 4; ni++) {
    int col = colbase + ni * 16;
    bias_r[ni] = bias[col];
    scale_r[ni] = (EPI == 3 || EPI == 4) ? scale[col] : 0.f;
  }
  // EPI 5: softplus applies to the whole 64-col warp-tile or none of it
  // (tile boundary at col 1024 is 64-aligned) -> wave-uniform branch.
  const bool spAll = (EPI == 5) && ((n0 + wcol) < 1024);
#pragma unroll
  for (int mi = 0; mi < MI; mi++) {
#pragma unroll
    for (int j = 0; j < 4; j++) {
      int row = wrow + mi * 16 + ((lane >> 4) << 2) + j;
      long s = s_base + row;
      long cro = (long)b * c_bstride + (s + c_roff) * (long)ldc;
#pragma unroll
      for (int ni = 0; ni < 4; ni++) {
        int col = colbase + ni * 16;
        float v = acc[mi][ni][j];
        if constexpr (EPI == 1) {
          v += bias_r[ni] + resid[cro + col];
          ((float*)Cout)[cro + col] = v;
        } else if constexpr (EPI == 2) {
          v = geluf(v + bias_r[ni]);
          ((bf16_t*)Cout)[cro + col] = (bf16_t)v;
        } else if constexpr (EPI == 3) {
          v = geluf(v * scale_r[ni] + bias_r[ni]) + pe[s * 256 + col];
          ((float*)Cout)[cro + col] = v;
        } else if constexpr (EPI == 4) {
          v = geluf(v * scale_r[ni] + bias_r[ni]);
          ((bf16_t*)Cout)[cro + col] = (bf16_t)v;
        } else {  // 5
          v += bias_r[ni];
          if (spAll) v = softplusf(v);
          ((bf16_t*)Cout)[cro + col] = (bf16_t)v;
        }
      }
    }
  }
}

// ---------------------------------------------------------------------------
// LayerNorm over D=256, fp32 in -> bf16 out. 16 rows/block (4 waves x 4
// iterations), gamma/beta hoisted. XCD chunk-remap matches GEMM m-chunk map.
// ---------------------------------------------------------------------------
__global__ __launch_bounds__(256)
void ln_kernel(const float* __restrict__ h, const float* __restrict__ g,
               const float* __restrict__ bta, bf16_t* __restrict__ out)
{
  int t = threadIdx.x;
  int lane = t & 63;
  const int G = gridDim.x;                 // divisible by 8
  const int wgid = (blockIdx.x & 7) * (G >> 3) + (blockIdx.x >> 3);
  const long row0 = (long)wgid * 16 + (t >> 6);
  const int c = lane * 4;
  const float4 gv = *(const float4*)(g + c);
  const float4 bv = *(const float4*)(bta + c);
#pragma unroll
  for (int it = 0; it < 4; ++it) {
    long row = row0 + it * 4;
    const float* hp = h + row * 256 + c;
    float4 v = *(const float4*)hp;
    float s = v.x + v.y + v.z + v.w;
    float q = v.x * v.x + v.y * v.y + v.z * v.z + v.w * v.w;
#pragma unroll
    for (int m = 32; m >= 1; m >>= 1) {
      s += __shfl_xor(s, m);
      q += __shfl_xor(q, m);
    }
    float mean = s * 0.00390625f;
    float var = q * 0.00390625f - mean * mean;
    float rstd = rsqrtf(var + 1e-5f);
    bf16x4 o;
    o[0] = (bf16_t)((v.x - mean) * rstd * gv.x + bv.x);
    o[1] = (bf16_t)((v.y - mean) * rstd * gv.y + bv.y);
    o[2] = (bf16_t)((v.z - mean) * rstd * gv.z + bv.z);
    o[3] = (bf16_t)((v.w - mean) * rstd * gv.w + bv.w);
    *(bf16x4*)(out + row * 256 + c) = o;
  }
}

// ---------------------------------------------------------------------------
// Embedding conv1: x[Bc,S] -> gelu(bn(conv1d k=7 pad=3)) -> h1p[Bc,S+4,128]
// Also zeroes h1p pad rows (0,1 at s0==0; 4098,4099 at s0==4032).
// ---------------------------------------------------------------------------
__global__ __launch_bounds__(256)
void conv1_kernel(const float* __restrict__ x, const float* __restrict__ w1,
                  const float* __restrict__ sc, const float* __restrict__ sb,
                  bf16_t* __restrict__ h1p)
{
  int b = blockIdx.x >> 6;
  int s0 = (blockIdx.x & 63) << 6;
  __shared__ float xs[70];
  __shared__ float ws[896];
  int t = threadIdx.x;
  if (t < 70) {
    int s = s0 + t - 3;
    xs[t] = (s >= 0 && s < 4096) ? x[(long)b * 4096 + s] : 0.f;
  }
  for (int i = t; i < 896; i += 256) ws[i] = w1[i];
  // zero pad rows (disjoint from data rows 2..4097)
  if (s0 == 0)
    h1p[((long)b * 4100 + (t >> 7)) * 128 + (t & 127)] = (bf16_t)0.f;
  if (s0 == 4032)
    h1p[((long)b * 4100 + 4098 + (t >> 7)) * 128 + (t & 127)] = (bf16_t)0.f;
  __syncthreads();
  int c = t & 127, so = t >> 7;
  float wr[7];
#pragma unroll
  for (int k = 0; k < 7; k++) wr[k] = ws[c * 7 + k];
  float scl = sc[c], sbv = sb[c];
  for (int p = 0; p < 32; p++) {
    int sl = p * 2 + so;
    float a = 0.f;
#pragma unroll
    for (int k = 0; k < 7; k++) a += xs[sl + k] * wr[k];
    a = geluf(a * scl + sbv);
    h1p[((long)b * 4100 + s0 + sl + 2) * 128 + c] = (bf16_t)a;
  }
}

// ---------------------------------------------------------------------------
// kv partial: per (b,h,chunk of 512 s): acc[f][d] += kp[s,f]*v[s,d]; +ksum.
// DOUBLE-BUFFERED: prefetch tile t+1 into regs during compute of tile t,
// one barrier per iteration (was 2). Per-thread accumulation order is
// unchanged (s ascending within and across tiles) -> bit-identical output.
// ---------------------------------------------------------------------------
__global__ __launch_bounds__(256)
void kv_partial(const bf16_t* __restrict__ qpkpv,
                float* __restrict__ pkv, float* __restrict__ pks)
{
  int bh = blockIdx.x >> 3, ch = blockIdx.x & 7;
  int b = bh >> 3, hh = bh & 7;
  int s0 = ch * 512;
  __shared__ float kps[2][32 * 64];
  __shared__ float vs[2][32 * 32];
  int t = threadIdx.x;
  int f = t & 63, dg = t >> 6;
  float acc[8] = {0.f, 0.f, 0.f, 0.f, 0.f, 0.f, 0.f, 0.f};
  float ks = 0.f;
  const int row = t >> 3, slot8 = (t & 7) * 8, slot4 = (t & 7) * 4;

  // prologue: tile 0 -> regs -> buf0
  bf16x8 k8;
  bf16x4 v4;
  {
    const bf16_t* rowp = qpkpv + ((long)b * 4096 + s0 + row) * 1280;
    k8 = *(const bf16x8*)(rowp + 512 + hh * 64 + slot8);
    v4 = *(const bf16x4*)(rowp + 1024 + hh * 32 + slot4);
  }
#pragma unroll
  for (int j = 0; j < 8; j++) kps[0][row * 64 + slot8 + j] = (float)k8[j];
#pragma unroll
  for (int j = 0; j < 4; j++) vs[0][row * 32 + slot4 + j] = (float)v4[j];
  __syncthreads();

  for (int it = 0; it < 16; ++it) {
    const int cur = it & 1;
    // prefetch tile it+1 into regs (no LDS dependency)
    bf16x8 nk8;
    bf16x4 nv4;
    if (it + 1 < 16) {
      const bf16_t* rowp = qpkpv + ((long)b * 4096 + s0 + (it + 1) * 32 + row) * 1280;
      nk8 = *(const bf16x8*)(rowp + 512 + hh * 64 + slot8);
      nv4 = *(const bf16x4*)(rowp + 1024 + hh * 32 + slot4);
    }
    // compute from buf[cur]
#pragma unroll 4
    for (int s = 0; s < 32; s++) {
      float kval = kps[cur][s * 64 + f];
      float4 v0 = *(const float4*)&vs[cur][s * 32 + dg * 8];
      float4 v1 = *(const float4*)&vs[cur][s * 32 + dg * 8 + 4];
      acc[0] += kval * v0.x; acc[1] += kval * v0.y;
      acc[2] += kval * v0.z; acc[3] += kval * v0.w;
      acc[4] += kval * v1.x; acc[5] += kval * v1.y;
      acc[6] += kval * v1.z; acc[7] += kval * v1.w;
      ks += kval;
    }
    // write tile it+1 into buf[cur^1] (safe: last read of that buffer was
    // iteration it-1's compute, separated by the barrier below at it-1)
    if (it + 1 < 16) {
#pragma unroll
      for (int j = 0; j < 8; j++) kps[cur ^ 1][row * 64 + slot8 + j] = (float)nk8[j];
#pragma unroll
      for (int j = 0; j < 4; j++) vs[cur ^ 1][row * 32 + slot4 + j] = (float)nv4[j];
      __syncthreads();
    }
  }
  long o = (long)blockIdx.x * 2048 + f * 32 + dg * 8;
#pragma unroll
  for (int j = 0; j < 8; j++) pkv[o + j] = acc[j];
  if (dg == 0) pks[blockIdx.x * 64 + f] = ks;
}

// ---------------------------------------------------------------------------
// kv_reduce_b: reduce the 8 chunk-partials into the exact [48][72] bf16
// B-panel layout combine_mfma stages (rows 0..31 = kv^T, row 32 = ksum,
// rows 33..47 + pad cols = 0). Same fp32 summation order -> bit-identical.
// 4 blocks per bh (quarter-panel each) for latency.
// ---------------------------------------------------------------------------
__global__ __launch_bounds__(256)
void kv_reduce_b(const float* __restrict__ pkv, const float* __restrict__ pks,
                 bf16_t* __restrict__ kvb)
{
  int bh = blockIdx.x >> 2;
  int quarter = blockIdx.x & 3;
  int base = quarter * 864;                // 3456/4
  int t = threadIdx.x;
  for (int i = base + t; i < base + 864; i += 256) {
    int n = i / 72, f = i % 72;
    float s = 0.f;
    if (f < 64) {
      if (n < 32) {
#pragma unroll
        for (int ch = 0; ch < 8; ch++)
          s += pkv[((long)(bh * 8 + ch)) * 2048 + f * 32 + n];
      } else if (n == 32) {
#pragma unroll
        for (int ch = 0; ch < 8; ch++)
          s += pks[(bh * 8 + ch) * 64 + f];
      }
    }
    kvb[(long)bh * 3456 + i] = (bf16_t)s;
  }
}

// ---------------------------------------------------------------------------
// combine: ao[s, h*32+d] = (qp[s,:] @ kv[:,d]) / (qp[s,:]@ksum + 1e-8)
// B-panel comes precomputed from kv_reduce_b (straight vector copy to LDS).
// ---------------------------------------------------------------------------
__global__ __launch_bounds__(256, 4)
void combine_mfma(const bf16_t* __restrict__ qpkpv, const bf16_t* __restrict__ kvb,
                  bf16_t* __restrict__ ao)
{
  int bh = blockIdx.x >> 5;
  int s0 = (blockIdx.x & 31) << 7;
  int b = bh >> 3, hh = bh & 7;
  __shared__ bf16_t A_s[128 * 72];
  __shared__ bf16_t B_s[48 * 72];
  int t = threadIdx.x;
  for (int g = t; g < 1024; g += 256) {
    int row = g >> 3, slot = (g & 7) * 8;
    *(bf16x8*)&A_s[row * 72 + slot] =
        *(const bf16x8*)(qpkpv + ((long)b * 4096 + s0 + row) * 1280 + hh * 64 + slot);
  }
  {
    const bf16x8* kv8 = (const bf16x8*)(kvb + (long)bh * 3456);
    for (int i = t; i < 432; i += 256)
      ((bf16x8*)B_s)[i] = kv8[i];
  }
  __syncthreads();
  int lane = t & 63, w = t >> 6;
  f32x4 acc[2][3];
#pragma unroll
  for (int i = 0; i < 2; i++)
#pragma unroll
    for (int j = 0; j < 3; j++) acc[i][j] = (f32x4){0.f, 0.f, 0.f, 0.f};
#pragma unroll
  for (int kt = 0; kt < 2; kt++) {
    int ko = kt * 32 + (lane >> 4) * 8;
    bf16x8 a[2], bb[3];
#pragma unroll
    for (int i = 0; i < 2; i++)
      a[i] = *(const bf16x8*)&A_s[(w * 32 + i * 16 + (lane & 15)) * 72 + ko];
#pragma unroll
    for (int i = 0; i < 3; i++)
      bb[i] = *(const bf16x8*)&B_s[(i * 16 + (lane & 15)) * 72 + ko];
#pragma unroll
    for (int mi = 0; mi < 2; mi++)
#pragma unroll
      for (int ni = 0; ni < 3; ni++)
        acc[mi][ni] = __builtin_amdgcn_mfma_f32_16x16x32_bf16(a[mi], bb[ni], acc[mi][ni], 0, 0, 0);
  }
  long sbase = (long)b * 4096 + s0;
#pragma unroll
  for (int mi = 0; mi < 2; mi++)
#pragma unroll
    for (int j = 0; j < 4; j++) {
      int r = w * 32 + mi * 16 + ((lane >> 4) << 2) + j;
      float den = __shfl(acc[mi][2][j], (lane & 48)) + 1e-8f;
#pragma unroll
      for (int ni = 0; ni < 2; ni++) {
        int d = ni * 16 + (lane & 15);
        ao[(sbase + r) * 256 + hh * 32 + d] = (bf16_t)(acc[mi][ni][j] / den);
      }
    }
}

// ---------------------------------------------------------------------------
// h fp32 -> h_padded bf16 [Bc, S+4, 256] (rows offset +2). Also zeroes the
// hpad pad rows (0,1,4098,4099) and hdp pad rows (0,4097) per batch.
// ---------------------------------------------------------------------------
__global__ __launch_bounds__(256)
void cast_pad(const float* __restrict__ h, bf16_t* __restrict__ hp,
              bf16_t* __restrict__ hdp)
{
  long gid = (long)blockIdx.x * 256 + threadIdx.x;
  const int Bc = gridDim.x >> 9;           // grid = Bc*512
  if (gid < (long)Bc * 160) {
    int b = (int)(gid / 160);
    int r = (int)(gid % 160);
    bf16x8 z;
#pragma unroll
    for (int j = 0; j < 8; j++) z[j] = (bf16_t)0.f;
    if (r < 128) {
      int rr = r >> 5;                     // 0..3
      int row = (rr < 2) ? rr : 4096 + rr; // 0,1,4098,4099
      *(bf16x8*)(hp + ((long)b * 4100 + row) * 256 + (r & 31) * 8) = z;
    } else {
      int r2 = r - 128;                    // 0..31
      int row = (r2 >> 4) ? 4097 : 0;      // 0,4097
      *(bf16x8*)(hdp + ((long)b * 4098 + row) * 128 + (r2 & 15) * 8) = z;
    }
  }
  long i8 = gid * 8;
  long r = i8 >> 8;
  int c = (int)(i8 & 255);
  int b = (int)(r >> 12), s = (int)(r & 4095);
  float4 v0 = *(const float4*)(h + i8);
  float4 v1 = *(const float4*)(h + i8 + 4);
  bf16x8 o;
  o[0] = (bf16_t)v0.x; o[1] = (bf16_t)v0.y; o[2] = (bf16_t)v0.z; o[3] = (bf16_t)v0.w;
  o[4] = (bf16_t)v1.x; o[5] = (bf16_t)v1.y; o[6] = (bf16_t)v1.z; o[7] = (bf16_t)v1.w;
  *(bf16x8*)(hp + ((long)b * 4100 + s + 2) * 256 + c) = o;
}

// ---------------------------------------------------------------------------
// Final conv (DH->1, k=3, pad=1) + sigmoid -> out [Bc,S] fp32.
// 4 lanes per output (partial sums + shfl reduce); grid Bc*64 blocks.
// ---------------------------------------------------------------------------
__global__ __launch_bounds__(256)
void conv_final(const bf16_t* __restrict__ hdp, const float* __restrict__ w2,
                const float* __restrict__ b2, float* __restrict__ out)
{
  __shared__ float ws[384];
  int t = threadIdx.x;
  for (int i = t; i < 384; i += 256) ws[i] = w2[i];  // [c][k]
  __syncthreads();
  int part = t & 3;
  long idx = (long)blockIdx.x * 64 + (t >> 2);
  int b = (int)(idx >> 12);
  const bf16_t* base = hdp + ((long)b * 4098 + (idx & 4095)) * 128;
  float a = 0.f;
#pragma unroll
  for (int k = 0; k < 3; k++) {
#pragma unroll
    for (int cc = 0; cc < 4; cc++) {
      int c8 = part + cc * 4;
      bf16x8 v = *(const bf16x8*)(base + k * 128 + c8 * 8);
#pragma unroll
      for (int j = 0; j < 8; j++) a += (float)v[j] * ws[(c8 * 8 + j) * 3 + k];
    }
  }
  a += __shfl_xor(a, 1);
  a += __shfl_xor(a, 2);
  if (part == 0) out[idx] = 1.f / (1.f + __expf(-(a + b2[0])));
}

// ---------------------------------------------------------------------------
// Prep kernels (once per launch)
// ---------------------------------------------------------------------------
__global__ __launch_bounds__(256)
void prep_weff(const float* __restrict__ wq, const float* __restrict__ wk,
               const float* __restrict__ wv, const float* __restrict__ bq,
               const float* __restrict__ bk, const float* __restrict__ bv,
               const float* __restrict__ rf, bf16_t* __restrict__ weff,
               float* __restrict__ beff)
{
  long idx = (long)blockIdx.x * 256 + threadIdx.x;  // 4*1280*256
  int d = (int)(idx & 255);
  long r = idx >> 8;
  int n = (int)(r % 1280);
  int l = (int)(r / 1280);
  float val;
  if (n < 1024) {
    int qk = n >> 9;
    int h = (n >> 6) & 7;
    int f = n & 63;
    const float* w = qk ? wk : wq;
    const float* rfh = rf + ((long)(l * 8 + h) * 32) * 64 + f;
    const float* wrow = w + ((long)l * 256 + d) * 256 + h * 32;
    float s = 0.f;
#pragma unroll
    for (int hd = 0; hd < 32; hd++) s += wrow[hd] * rfh[hd * 64];
    val = s;
  } else {
    val = wv[((long)l * 256 + d) * 256 + (n - 1024)];
  }
  weff[idx] = (bf16_t)val;
  if (idx < 4 * 1280) {
    int nn = (int)(idx % 1280);
    int ll = (int)(idx / 1280);
    float bvv;
    if (nn < 1024) {
      int qk = nn >> 9;
      int h = (nn >> 6) & 7;
      int f = nn & 63;
      const float* bsrc = qk ? bk : bq;
      float s = 0.f;
      for (int hd = 0; hd < 32; hd++)
        s += bsrc[ll * 256 + h * 32 + hd] * rf[((long)(ll * 8 + h) * 32 + hd) * 64 + f];
      bvv = s;
    } else {
      bvv = bv[ll * 256 + (nn - 1024)];
    }
    beff[idx] = bvv;
  }
}

// 32x32 LDS-tiled transpose+cast: src fp32 [l][K][N] -> dst bf16 [l][N][K].
__global__ __launch_bounds__(256)
void prep_cast_t32(const float* __restrict__ src, bf16_t* __restrict__ dst,
                   int K, int N)
{
  __shared__ float tile[32][33];
  const int kt = K >> 5, nt = N >> 5;
  int bid = blockIdx.x;
  int l = bid / (kt * nt);
  int rem = bid % (kt * nt);
  int ntile = rem / kt;          // n-tile index
  int ktile = rem % kt;          // k-tile index
  int n0 = ntile * 32, k0 = ktile * 32;
  int t = threadIdx.x;
  int c = t & 31, rbase = t >> 5;  // 8 rows per pass
#pragma unroll
  for (int i = 0; i < 4; i++) {
    int r = rbase + i * 8;
    tile[r][c] = src[((long)l * K + k0 + r) * N + n0 + c];
  }
  __syncthreads();
#pragma unroll
  for (int i = 0; i < 4; i++) {
    int r = rbase + i * 8;
    dst[((long)l * N + n0 + r) * K + k0 + c] = (bf16_t)tile[c][r];
  }
}

__global__ __launch_bounds__(256)
void prep_conv_t(const float* __restrict__ w, bf16_t* __restrict__ dst, int C, int KW)
{
  long idx = (long)blockIdx.x * 256 + threadIdx.x;  // O*C*KW
  int ckw = C * KW;
  int kk = (int)(idx % ckw);
  int o = (int)(idx / ckw);
  int kw = kk / C, c = kk % C;
  dst[idx] = (bf16_t)w[((long)o * C + c) * KW + kw];
}

__global__ __launch_bounds__(256)
void prep_bn(const float* g1, const float* b1, const float* cb1,
             const float* g2, const float* b2, const float* cb2,
             const float* g3, const float* b3, const float* cb3,
             float* sc1, float* sb1, float* sc2, float* sb2,
             float* sc3, float* sb3)
{
  int t = threadIdx.x;
  const float r = rsqrtf(1.f + 1e-5f);
  if (t < 128) { float s = g1[t] * r; sc1[t] = s; sb1[t] = cb1[t] * s + b1[t]; }
  if (t < 256) { float s = g2[t] * r; sc2[t] = s; sb2[t] = cb2[t] * s + b2[t]; }
  if (t < 128) { float s = g3[t] * r; sc3[t] = s; sb3[t] = cb3[t] * s + b3[t]; }
}

__global__ __launch_bounds__(256)
void pe_fill(float* __restrict__ pe)
{
  long idx = (long)blockIdx.x * 256 + threadIdx.x;  // 4096*256
  int dcol = (int)(idx & 255);
  int s = (int)(idx >> 8);
  int i2 = dcol >> 1;
  float freq = expf(-9.210340371976184f * (float)(2 * i2) / 256.f);
  float a = (float)s * freq;
  pe[idx] = (dcol & 1) ? cosf(a) : sinf(a);
}

// ---------------------------------------------------------------------------
extern "C" void kernel_launch(void* const* d_in, const int* in_sizes, int n_in,
                              void* d_out, int out_size, void* d_ws, size_t ws_size,
                              hipStream_t stream)
{
  (void)in_sizes; (void)n_in; (void)out_size;
  const float* x      = (const float*)d_in[0];
  const float* emb_w1 = (const float*)d_in[1];
  const float* emb_b1 = (const float*)d_in[2];
  const float* bn1_g  = (const float*)d_in[3];
  const float* bn1_b  = (const float*)d_in[4];
  const float* emb_w2 = (const float*)d_in[5];
  const float* emb_b2 = (const float*)d_in[6];
  const float* bn2_g  = (const float*)d_in[7];
  const float* bn2_b  = (const float*)d_in[8];
  const float* wq     = (const float*)d_in[9];
  const float* bq     = (const float*)d_in[10];
  const float* wk     = (const float*)d_in[11];
  const float* bk     = (const float*)d_in[12];
  const float* wv     = (const float*)d_in[13];
  const float* bv     = (const float*)d_in[14];
  const float* wo     = (const float*)d_in[15];
  const float* bo     = (const float*)d_in[16];
  const float* rf     = (const float*)d_in[17];
  const float* ln1_g  = (const float*)d_in[18];
  const float* ln1_b  = (const float*)d_in[19];
  const float* ln2_g  = (const float*)d_in[20];
  const float* ln2_b  = (const float*)d_in[21];
  const float* ff_w1  = (const float*)d_in[22];
  const float* ff_b1  = (const float*)d_in[23];
  const float* ff_w2  = (const float*)d_in[24];
  const float* ff_b2  = (const float*)d_in[25];
  const float* dec_w1 = (const float*)d_in[26];
  const float* dec_b1 = (const float*)d_in[27];
  const float* bn3_g  = (const float*)d_in[28];
  const float* bn3_b  = (const float*)d_in[29];
  const float* dec_w2 = (const float*)d_in[30];
  const float* dec_b2 = (const float*)d_in[31];

  char* W = (char*)d_ws;

  // ---- fixed region (weights, ~12.2 MB; reserve 16 MB) ----
  bf16_t* weff = (bf16_t*)(W + 0);                     // 4*1280*256*2 = 2,621,440
  float*  beff = (float*)(W + 2621440);                // 20,480
  bf16_t* wot  = (bf16_t*)(W + 2641920);               // 524,288
  bf16_t* w1t  = (bf16_t*)(W + 3166208);               // 2,097,152
  bf16_t* w2t  = (bf16_t*)(W + 5263360);               // 2,097,152
  bf16_t* c2t  = (bf16_t*)(W + 7360512);               // 327,680
  bf16_t* d1t  = (bf16_t*)(W + 7688192);               // 327,680
  float*  pe   = (float*)(W + 8015872);                // 4,194,304
  float*  sc1  = (float*)(W + 12210176);
  float*  sb1  = (float*)(W + 12211200);
  float*  sc2  = (float*)(W + 12212224);
  float*  sb2  = (float*)(W + 12213248);
  float*  sc3  = (float*)(W + 12214272);
  float*  sb3  = (float*)(W + 12215296);
  const size_t FIXED_END = 16777216;

  // ---- pick batch chunk Bc so workspace fits ws_size ----
  // per-B: h 4MB + ao 2MB + big 10MB + pkv 512K + pks 16K + kvb 54K
  const size_t PER_B = 17440768;
  int Bc = 32;
  while (Bc > 1 && FIXED_END + (size_t)Bc * PER_B > ws_size) Bc >>= 1;

  char* P = W + FIXED_END;
  float*  h     = (float*)P;
  bf16_t* xa    = (bf16_t*)(P + (size_t)Bc * 4194304);
  bf16_t* ao    = xa;  // xa dead after fused qkv gemm; ao dead before ln2
  char*   big   = P + (size_t)Bc * (4194304 + 2097152);
  bf16_t* qpkpv = (bf16_t*)big;
  bf16_t* f1    = (bf16_t*)big;                               // after qpkpv dead
  bf16_t* h1p   = (bf16_t*)big;                               // pre-loop
  bf16_t* hpad  = (bf16_t*)big;                               // post-loop
  bf16_t* hdp   = (bf16_t*)(big + (size_t)Bc * 4100 * 256 * 2);
  float*  pkv   = (float*)(big + (size_t)Bc * 10485760);
  float*  pks   = (float*)((char*)pkv + (size_t)Bc * 524288);
  bf16_t* kvb   = (bf16_t*)((char*)pks + (size_t)Bc * 16384);

  // ---- weight prep (once) ----
  prep_weff<<<5120, 256, 0, stream>>>(wq, wk, wv, bq, bk, bv, rf, weff, beff);
  prep_cast_t32<<<256, 256, 0, stream>>>(wo, wot, 256, 256);
  prep_cast_t32<<<1024, 256, 0, stream>>>(ff_w1, w1t, 256, 1024);
  prep_cast_t32<<<1024, 256, 0, stream>>>(ff_w2, w2t, 1024, 256);
  prep_conv_t<<<640, 256, 0, stream>>>(emb_w2, c2t, 128, 5);
  prep_conv_t<<<640, 256, 0, stream>>>(dec_w1, d1t, 256, 5);
  prep_bn<<<1, 256, 0, stream>>>(bn1_g, bn1_b, emb_b1, bn2_g, bn2_b, emb_b2,
                                 bn3_g, bn3_b, dec_b1, sc1, sb1, sc2, sb2, sc3, sb3);
  pe_fill<<<4096, 256, 0, stream>>>(pe);

  for (int c0 = 0; c0 < 32; c0 += Bc) {
    const float* xc = x + (size_t)c0 * 4096;

    // ---- embedding (conv1 zeroes its own pad rows) ----
    conv1_kernel<<<Bc * 64, 256, 0, stream>>>(xc, emb_w1, sc1, sb1, h1p);
    gemm_bf16<3, 640, 64, 4><<<Bc * 128, 256, 0, stream>>>(
        h1p, c2t, h, sb2, sc2, nullptr, pe,
        128, 4100L * 128, 4096, 256, 256, 4096L * 256, 0);

    // ---- transformer layers ----
    for (int l = 0; l < 4; l++) {
      ln_kernel<<<Bc * 256, 256, 0, stream>>>(h, ln1_g + l * 256, ln1_b + l * 256, xa);
      gemm_bf16<5, 256, 128, 10><<<Bc * 320, 256, 0, stream>>>(
          xa, weff + (long)l * 327680, qpkpv, beff + l * 1280, nullptr, nullptr, nullptr,
          256, 4096L * 256, 4096, 1280, 1280, 4096L * 1280, 0);
      kv_partial<<<Bc * 64, 256, 0, stream>>>(qpkpv, pkv, pks);
      kv_reduce_b<<<Bc * 32, 256, 0, stream>>>(pkv, pks, kvb);
      combine_mfma<<<Bc * 256, 256, 0, stream>>>(qpkpv, kvb, ao);
      gemm_bf16<1, 256, 64, 4><<<Bc * 128, 256, 0, stream>>>(
          ao, wot + (long)l * 65536, h, bo + l * 256, nullptr, h, nullptr,
          256, 4096L * 256, 4096, 256, 256, 4096L * 256, 0);
      ln_kernel<<<Bc * 256, 256, 0, stream>>>(h, ln2_g + l * 256, ln2_b + l * 256, xa);
      gemm_bf16<2, 256, 128, 8><<<Bc * 256, 256, 0, stream>>>(
          xa, w1t + (long)l * 262144, f1, ff_b1 + l * 1024, nullptr, nullptr, nullptr,
          256, 4096L * 256, 4096, 1024, 1024, 4096L * 1024, 0);
      gemm_bf16<1, 1024, 64, 4><<<Bc * 128, 256, 0, stream>>>(
          f1, w2t + (long)l * 262144, h, ff_b2 + l * 256, nullptr, h, nullptr,
          1024, 4096L * 1024, 4096, 256, 256, 4096L * 256, 0);
    }

    // ---- decoder (cast_pad zeroes hpad + hdp pad rows) ----
    cast_pad<<<Bc * 512, 256, 0, stream>>>(h, hpad, hdp);
    gemm_bf16<4, 1280, 64, 2><<<Bc * 64, 256, 0, stream>>>(
        hpad, d1t, hdp, sb3, sc3, nullptr, nullptr,
        256, 4100L * 256, 4096, 128, 128, 4098L * 128, 1);
    conv_final<<<Bc * 64, 256, 0, stream>>>(hdp, dec_w2, dec_b2,
                                            (float*)d_out + (size_t)c0 * 4096);
  }
}

// Round 22
// 3802.795 us; speedup vs baseline: 1.6027x; 1.0056x over previous
//
#include <hip/hip_runtime.h>
#include <hip/hip_bf16.h>
#include <math.h>

// ============================================================================
// PPGPeakPerformer forward on MI355X (gfx950)
// B=32 S=4096 D=256 DH=128 H=8 HD=32 F=64 L=4
// r22 = r21 (best passing, 3824us) + occupancy bumps (pure hints, no math):
//   combine_mfma (256,4)->(256,6): LDS 25.6KB<=26.6, VGPR 40<=85 (no cliff)
//   kv_partial: explicit (256,6): LDS 24KB, ~48 VGPR <= 85
// Core unchanged: 128xBN GEMM (BN=128 wide, BN=64 narrow), BK=32, A triple-
// buffer depth-2 + counted vmcnt(2), B double-buffer, 40KB LDS, 4 blocks/CU,
// bijective XCD chunk-remap, both-sides swizzle, fast erf, fused q/k RF
// projection GEMM, kv_partial reg-prefetch double-buffer (1 barrier/iter),
// kv_reduce_b -> combine vector-copy B-panel, no memsets, tiled weight
// transposes, conv_final 4-lane reduce, 16-row ln blocks. LN separate pass
// (LN-GEMM fusion numerically refuted r14/r15).
// ============================================================================

typedef __bf16 bf16_t;
typedef __bf16 bf16x8 __attribute__((ext_vector_type(8)));
typedef __bf16 bf16x4 __attribute__((ext_vector_type(4)));
typedef float  f32x4  __attribute__((ext_vector_type(4)));

#define DEV __device__ __forceinline__

DEV float erf_fast(float x) {
  float ax = fabsf(x);
  float t = __builtin_amdgcn_rcpf(1.f + 0.3275911f * ax);
  float p = t * (0.254829592f + t * (-0.284496736f + t * (1.421413741f +
            t * (-1.453152027f + t * 1.061405429f))));
  float r = 1.f - p * __expf(-ax * ax);
  return copysignf(r, x);
}
DEV float geluf(float v) { return 0.5f * v * (1.f + erf_fast(v * 0.70710678118654752440f)); }
DEV float softplusf(float v) {
  float e = __expf(-fabsf(v));
  return fmaxf(v, 0.f) + __logf(1.f + e);
}

// Direct global->LDS 16B staging. LDS dest is wave-uniform base + lane*16.
DEV void gload16(const bf16_t* g, bf16_t* l) {
  __builtin_amdgcn_global_load_lds(
      (const __attribute__((address_space(1))) void*)g,
      (__attribute__((address_space(3))) void*)l, 16, 0, 0);
}

// ---------------------------------------------------------------------------
// GEMM: C[m,n] = sum_k A[m,k]*Bt[n,k].  A bf16 (batched rows), Bt bf16 [N][K].
// EPI: 1 = +bias +resid -> fp32; 2 = gelu(+bias) -> bf16;
//      3 = gelu(scale*x+bias)+pe -> fp32; 4 = gelu(scale*x+bias) -> bf16;
//      5 = tile<1024 ? softplus(+bias) : (+bias) -> bf16 (block-uniform)
// Pipeline per iter t:
//   wait vmcnt(2); s_barrier; stage B(t+1); stage A(t+2); ds_read; MFMA.
// A slack ~2 iters (HBM-ok), B slack ~1 iter (L2-ok).
// ---------------------------------------------------------------------------
template <int EPI, int K, int BN, int NTL>
__global__ __launch_bounds__(256, 4)
void gemm_bf16(const bf16_t* __restrict__ A, const bf16_t* __restrict__ Bt,
               void* Cout, const float* __restrict__ bias,
               const float* __restrict__ scale, const float* resid,
               const float* __restrict__ pe,
               int lda, long a_bstride, int rpb,
               int N, int ldc, long c_bstride, int c_roff)
{
  constexpr int MI = (BN == 128) ? 4 : 2;   // row-fragments per wave
  __shared__ bf16_t As[3][128 * 32];
  __shared__ bf16_t Bs[2][BN * 32];
  const int t = threadIdx.x;
  const int lane = t & 63;
  const int w = t >> 6;
  const int wrow = (BN == 128) ? (w >> 1) * 64 : w * 32;
  const int wcol = (BN == 128) ? (w & 1) * 64 : 0;

  // XCD-aware bijective remap (m204): bid%8 -> XCD; XCD k gets a contiguous
  // wgid chunk (n-tile fastest) so A-tile sharers co-reside on one L2.
  const int nwg = gridDim.x;
  const int q_ = nwg >> 3, r_ = nwg & 7;
  const int xcd = blockIdx.x & 7, idx_ = blockIdx.x >> 3;
  const int wgid = (xcd < r_ ? xcd * (q_ + 1) : r_ * (q_ + 1) + (xcd - r_) * q_) + idx_;
  const long m0 = (long)(wgid / NTL) * 128;
  const int n0 = (wgid % NTL) * BN;

  const int b = (int)(m0 / rpb);
  const int s_base = (int)(m0 % rpb);
  const bf16_t* Ab = A + (long)b * a_bstride + (long)s_base * lda;
  const bf16_t* Bb = Bt + (long)n0 * K;

  // staging source (pre-swizzled): lane covers row (lane>>2) of a 16-row
  // block, 16B slot ((lane&3) ^ ((row>>1)&3)).
  const int srow = lane >> 2;
  const int sslot = (lane & 3) ^ ((srow >> 1) & 3);
  const bf16_t* aS = Ab + (long)(w * 32 + srow) * lda + sslot * 8;
  const bf16_t* bS = Bb + (long)(w * 32 + srow) * K + sslot * 8;
  const int dsto = w * 1024;  // 32 rows x 32 elems per wave

#define STAGE_A(bufidx, kk)                                 \
  {                                                         \
    bf16_t* a_ = &As[bufidx][dsto];                         \
    gload16(aS + (kk), a_);                                 \
    gload16(aS + (kk) + 16 * (long)lda, a_ + 512);          \
  }
#define STAGE_B(bufidx, kk)                                 \
  if (BN == 128 || w < 2) {                                 \
    bf16_t* b_ = &Bs[bufidx][dsto];                         \
    gload16(bS + (kk), b_);                                 \
    gload16(bS + (kk) + 16 * (long)K, b_ + 512);            \
  }

  f32x4 acc[MI][4];
#pragma unroll
  for (int i = 0; i < MI; i++)
#pragma unroll
    for (int j = 0; j < 4; j++) acc[i][j] = (f32x4){0.f, 0.f, 0.f, 0.f};

  constexpr int NT = K >> 5;
  // prologue queue order: A(0), B(0), A(1) -> wait vmcnt(2) drains A0,B0.
  STAGE_A(0, 0);
  STAGE_B(0, 0);
  if (NT > 1) STAGE_A(1, 32);

#pragma unroll
  for (int tt = 0; tt < NT; ++tt) {
    if (tt + 1 < NT) {
      asm volatile("s_waitcnt vmcnt(2)" ::: "memory");
    } else {
      asm volatile("s_waitcnt vmcnt(0)" ::: "memory");
    }
    __builtin_amdgcn_s_barrier();
    __builtin_amdgcn_sched_barrier(0);
    if (tt + 1 < NT) STAGE_B((tt + 1) & 1, (tt + 1) * 32);
    if (tt + 2 < NT) STAGE_A((tt + 2) % 3, (tt + 2) * 32);
    const bf16_t* Acur = As[tt % 3];
    const bf16_t* Bcur = Bs[tt & 1];
    const int kb = (lane >> 4) * 16;
    bf16x8 af[MI], bfr[4];
#pragma unroll
    for (int i = 0; i < MI; i++) {
      int rA = wrow + i * 16 + (lane & 15);
      af[i] = *(const bf16x8*)((const char*)Acur + rA * 64 + (kb ^ (((rA >> 1) & 3) << 4)));
    }
#pragma unroll
    for (int j = 0; j < 4; j++) {
      int rB = wcol + j * 16 + (lane & 15);
      bfr[j] = *(const bf16x8*)((const char*)Bcur + rB * 64 + (kb ^ (((rB >> 1) & 3) << 4)));
    }
    __builtin_amdgcn_s_setprio(1);
#pragma unroll
    for (int mi = 0; mi < MI; mi++)
#pragma unroll
      for (int ni = 0; ni < 4; ni++)
        acc[mi][ni] = __builtin_amdgcn_mfma_f32_16x16x32_bf16(af[mi], bfr[ni], acc[mi][ni], 0, 0, 0);
    __builtin_amdgcn_s_setprio(0);
  }
#undef STAGE_A
#undef STAGE_B

  const int colbase = n0 + wcol + (lane & 15);
  float bias_r[4], scale_r[4];
#pragma unroll
  for (int ni = 0; ni < 4; ni++) {
    int col = colbase + ni * 16;
    bias_r[ni] = bias[col];
    scale_r[ni] = (EPI == 3 || EPI == 4) ? scale[col] : 0.f;
  }
  // EPI 5: softplus applies to the whole 64-col warp-tile or none of it
  // (tile boundary at col 1024 is 64-aligned) -> wave-uniform branch.
  const bool spAll = (EPI == 5) && ((n0 + wcol) < 1024);
#pragma unroll
  for (int mi = 0; mi < MI; mi++) {
#pragma unroll
    for (int j = 0; j < 4; j++) {
      int row = wrow + mi * 16 + ((lane >> 4) << 2) + j;
      long s = s_base + row;
      long cro = (long)b * c_bstride + (s + c_roff) * (long)ldc;
#pragma unroll
      for (int ni = 0; ni < 4; ni++) {
        int col = colbase + ni * 16;
        float v = acc[mi][ni][j];
        if constexpr (EPI == 1) {
          v += bias_r[ni] + resid[cro + col];
          ((float*)Cout)[cro + col] = v;
        } else if constexpr (EPI == 2) {
          v = geluf(v + bias_r[ni]);
          ((bf16_t*)Cout)[cro + col] = (bf16_t)v;
        } else if constexpr (EPI == 3) {
          v = geluf(v * scale_r[ni] + bias_r[ni]) + pe[s * 256 + col];
          ((float*)Cout)[cro + col] = v;
        } else if constexpr (EPI == 4) {
          v = geluf(v * scale_r[ni] + bias_r[ni]);
          ((bf16_t*)Cout)[cro + col] = (bf16_t)v;
        } else {  // 5
          v += bias_r[ni];
          if (spAll) v = softplusf(v);
          ((bf16_t*)Cout)[cro + col] = (bf16_t)v;
        }
      }
    }
  }
}

// ---------------------------------------------------------------------------
// LayerNorm over D=256, fp32 in -> bf16 out. 16 rows/block (4 waves x 4
// iterations), gamma/beta hoisted. XCD chunk-remap matches GEMM m-chunk map.
// ---------------------------------------------------------------------------
__global__ __launch_bounds__(256)
void ln_kernel(const float* __restrict__ h, const float* __restrict__ g,
               const float* __restrict__ bta, bf16_t* __restrict__ out)
{
  int t = threadIdx.x;
  int lane = t & 63;
  const int G = gridDim.x;                 // divisible by 8
  const int wgid = (blockIdx.x & 7) * (G >> 3) + (blockIdx.x >> 3);
  const long row0 = (long)wgid * 16 + (t >> 6);
  const int c = lane * 4;
  const float4 gv = *(const float4*)(g + c);
  const float4 bv = *(const float4*)(bta + c);
#pragma unroll
  for (int it = 0; it < 4; ++it) {
    long row = row0 + it * 4;
    const float* hp = h + row * 256 + c;
    float4 v = *(const float4*)hp;
    float s = v.x + v.y + v.z + v.w;
    float q = v.x * v.x + v.y * v.y + v.z * v.z + v.w * v.w;
#pragma unroll
    for (int m = 32; m >= 1; m >>= 1) {
      s += __shfl_xor(s, m);
      q += __shfl_xor(q, m);
    }
    float mean = s * 0.00390625f;
    float var = q * 0.00390625f - mean * mean;
    float rstd = rsqrtf(var + 1e-5f);
    bf16x4 o;
    o[0] = (bf16_t)((v.x - mean) * rstd * gv.x + bv.x);
    o[1] = (bf16_t)((v.y - mean) * rstd * gv.y + bv.y);
    o[2] = (bf16_t)((v.z - mean) * rstd * gv.z + bv.z);
    o[3] = (bf16_t)((v.w - mean) * rstd * gv.w + bv.w);
    *(bf16x4*)(out + row * 256 + c) = o;
  }
}

// ---------------------------------------------------------------------------
// Embedding conv1: x[Bc,S] -> gelu(bn(conv1d k=7 pad=3)) -> h1p[Bc,S+4,128]
// Also zeroes h1p pad rows (0,1 at s0==0; 4098,4099 at s0==4032).
// ---------------------------------------------------------------------------
__global__ __launch_bounds__(256)
void conv1_kernel(const float* __restrict__ x, const float* __restrict__ w1,
                  const float* __restrict__ sc, const float* __restrict__ sb,
                  bf16_t* __restrict__ h1p)
{
  int b = blockIdx.x >> 6;
  int s0 = (blockIdx.x & 63) << 6;
  __shared__ float xs[70];
  __shared__ float ws[896];
  int t = threadIdx.x;
  if (t < 70) {
    int s = s0 + t - 3;
    xs[t] = (s >= 0 && s < 4096) ? x[(long)b * 4096 + s] : 0.f;
  }
  for (int i = t; i < 896; i += 256) ws[i] = w1[i];
  // zero pad rows (disjoint from data rows 2..4097)
  if (s0 == 0)
    h1p[((long)b * 4100 + (t >> 7)) * 128 + (t & 127)] = (bf16_t)0.f;
  if (s0 == 4032)
    h1p[((long)b * 4100 + 4098 + (t >> 7)) * 128 + (t & 127)] = (bf16_t)0.f;
  __syncthreads();
  int c = t & 127, so = t >> 7;
  float wr[7];
#pragma unroll
  for (int k = 0; k < 7; k++) wr[k] = ws[c * 7 + k];
  float scl = sc[c], sbv = sb[c];
  for (int p = 0; p < 32; p++) {
    int sl = p * 2 + so;
    float a = 0.f;
#pragma unroll
    for (int k = 0; k < 7; k++) a += xs[sl + k] * wr[k];
    a = geluf(a * scl + sbv);
    h1p[((long)b * 4100 + s0 + sl + 2) * 128 + c] = (bf16_t)a;
  }
}

// ---------------------------------------------------------------------------
// kv partial: per (b,h,chunk of 512 s): acc[f][d] += kp[s,f]*v[s,d]; +ksum.
// Reg-prefetch double-buffer, 1 barrier/iter; accumulation order unchanged.
// ---------------------------------------------------------------------------
__global__ __launch_bounds__(256, 6)
void kv_partial(const bf16_t* __restrict__ qpkpv,
                float* __restrict__ pkv, float* __restrict__ pks)
{
  int bh = blockIdx.x >> 3, ch = blockIdx.x & 7;
  int b = bh >> 3, hh = bh & 7;
  int s0 = ch * 512;
  __shared__ float kps[2][32 * 64];
  __shared__ float vs[2][32 * 32];
  int t = threadIdx.x;
  int f = t & 63, dg = t >> 6;
  float acc[8] = {0.f, 0.f, 0.f, 0.f, 0.f, 0.f, 0.f, 0.f};
  float ks = 0.f;
  const int row = t >> 3, slot8 = (t & 7) * 8, slot4 = (t & 7) * 4;

  // prologue: tile 0 -> regs -> buf0
  bf16x8 k8;
  bf16x4 v4;
  {
    const bf16_t* rowp = qpkpv + ((long)b * 4096 + s0 + row) * 1280;
    k8 = *(const bf16x8*)(rowp + 512 + hh * 64 + slot8);
    v4 = *(const bf16x4*)(rowp + 1024 + hh * 32 + slot4);
  }
#pragma unroll
  for (int j = 0; j < 8; j++) kps[0][row * 64 + slot8 + j] = (float)k8[j];
#pragma unroll
  for (int j = 0; j < 4; j++) vs[0][row * 32 + slot4 + j] = (float)v4[j];
  __syncthreads();

  for (int it = 0; it < 16; ++it) {
    const int cur = it & 1;
    // prefetch tile it+1 into regs (no LDS dependency)
    bf16x8 nk8;
    bf16x4 nv4;
    if (it + 1 < 16) {
      const bf16_t* rowp = qpkpv + ((long)b * 4096 + s0 + (it + 1) * 32 + row) * 1280;
      nk8 = *(const bf16x8*)(rowp + 512 + hh * 64 + slot8);
      nv4 = *(const bf16x4*)(rowp + 1024 + hh * 32 + slot4);
    }
    // compute from buf[cur]
#pragma unroll 4
    for (int s = 0; s < 32; s++) {
      float kval = kps[cur][s * 64 + f];
      float4 v0 = *(const float4*)&vs[cur][s * 32 + dg * 8];
      float4 v1 = *(const float4*)&vs[cur][s * 32 + dg * 8 + 4];
      acc[0] += kval * v0.x; acc[1] += kval * v0.y;
      acc[2] += kval * v0.z; acc[3] += kval * v0.w;
      acc[4] += kval * v1.x; acc[5] += kval * v1.y;
      acc[6] += kval * v1.z; acc[7] += kval * v1.w;
      ks += kval;
    }
    // write tile it+1 into buf[cur^1]
    if (it + 1 < 16) {
#pragma unroll
      for (int j = 0; j < 8; j++) kps[cur ^ 1][row * 64 + slot8 + j] = (float)nk8[j];
#pragma unroll
      for (int j = 0; j < 4; j++) vs[cur ^ 1][row * 32 + slot4 + j] = (float)nv4[j];
      __syncthreads();
    }
  }
  long o = (long)blockIdx.x * 2048 + f * 32 + dg * 8;
#pragma unroll
  for (int j = 0; j < 8; j++) pkv[o + j] = acc[j];
  if (dg == 0) pks[blockIdx.x * 64 + f] = ks;
}

// ---------------------------------------------------------------------------
// kv_reduce_b: reduce the 8 chunk-partials into the exact [48][72] bf16
// B-panel layout combine_mfma stages. Same fp32 summation order.
// 4 blocks per bh (quarter-panel each).
// ---------------------------------------------------------------------------
__global__ __launch_bounds__(256)
void kv_reduce_b(const float* __restrict__ pkv, const float* __restrict__ pks,
                 bf16_t* __restrict__ kvb)
{
  int bh = blockIdx.x >> 2;
  int quarter = blockIdx.x & 3;
  int base = quarter * 864;                // 3456/4
  int t = threadIdx.x;
  for (int i = base + t; i < base + 864; i += 256) {
    int n = i / 72, f = i % 72;
    float s = 0.f;
    if (f < 64) {
      if (n < 32) {
#pragma unroll
        for (int ch = 0; ch < 8; ch++)
          s += pkv[((long)(bh * 8 + ch)) * 2048 + f * 32 + n];
      } else if (n == 32) {
#pragma unroll
        for (int ch = 0; ch < 8; ch++)
          s += pks[(bh * 8 + ch) * 64 + f];
      }
    }
    kvb[(long)bh * 3456 + i] = (bf16_t)s;
  }
}

// ---------------------------------------------------------------------------
// combine: ao[s, h*32+d] = (qp[s,:] @ kv[:,d]) / (qp[s,:]@ksum + 1e-8)
// B-panel precomputed by kv_reduce_b (straight vector copy to LDS).
// 6 blocks/CU (LDS 25.6KB, VGPR 40 -> safe).
// ---------------------------------------------------------------------------
__global__ __launch_bounds__(256, 6)
void combine_mfma(const bf16_t* __restrict__ qpkpv, const bf16_t* __restrict__ kvb,
                  bf16_t* __restrict__ ao)
{
  int bh = blockIdx.x >> 5;
  int s0 = (blockIdx.x & 31) << 7;
  int b = bh >> 3, hh = bh & 7;
  __shared__ bf16_t A_s[128 * 72];
  __shared__ bf16_t B_s[48 * 72];
  int t = threadIdx.x;
  for (int g = t; g < 1024; g += 256) {
    int row = g >> 3, slot = (g & 7) * 8;
    *(bf16x8*)&A_s[row * 72 + slot] =
        *(const bf16x8*)(qpkpv + ((long)b * 4096 + s0 + row) * 1280 + hh * 64 + slot);
  }
  {
    const bf16x8* kv8 = (const bf16x8*)(kvb + (long)bh * 3456);
    for (int i = t; i < 432; i += 256)
      ((bf16x8*)B_s)[i] = kv8[i];
  }
  __syncthreads();
  int lane = t & 63, w = t >> 6;
  f32x4 acc[2][3];
#pragma unroll
  for (int i = 0; i < 2; i++)
#pragma unroll
    for (int j = 0; j < 3; j++) acc[i][j] = (f32x4){0.f, 0.f, 0.f, 0.f};
#pragma unroll
  for (int kt = 0; kt < 2; kt++) {
    int ko = kt * 32 + (lane >> 4) * 8;
    bf16x8 a[2], bb[3];
#pragma unroll
    for (int i = 0; i < 2; i++)
      a[i] = *(const bf16x8*)&A_s[(w * 32 + i * 16 + (lane & 15)) * 72 + ko];
#pragma unroll
    for (int i = 0; i < 3; i++)
      bb[i] = *(const bf16x8*)&B_s[(i * 16 + (lane & 15)) * 72 + ko];
#pragma unroll
    for (int mi = 0; mi < 2; mi++)
#pragma unroll
      for (int ni = 0; ni < 3; ni++)
        acc[mi][ni] = __builtin_amdgcn_mfma_f32_16x16x32_bf16(a[mi], bb[ni], acc[mi][ni], 0, 0, 0);
  }
  long sbase = (long)b * 4096 + s0;
#pragma unroll
  for (int mi = 0; mi < 2; mi++)
#pragma unroll
    for (int j = 0; j < 4; j++) {
      int r = w * 32 + mi * 16 + ((lane >> 4) << 2) + j;
      float den = __shfl(acc[mi][2][j], (lane & 48)) + 1e-8f;
#pragma unroll
      for (int ni = 0; ni < 2; ni++) {
        int d = ni * 16 + (lane & 15);
        ao[(sbase + r) * 256 + hh * 32 + d] = (bf16_t)(acc[mi][ni][j] / den);
      }
    }
}

// ---------------------------------------------------------------------------
// h fp32 -> h_padded bf16 [Bc, S+4, 256] (rows offset +2). Also zeroes the
// hpad pad rows (0,1,4098,4099) and hdp pad rows (0,4097) per batch.
// ---------------------------------------------------------------------------
__global__ __launch_bounds__(256)
void cast_pad(const float* __restrict__ h, bf16_t* __restrict__ hp,
              bf16_t* __restrict__ hdp)
{
  long gid = (long)blockIdx.x * 256 + threadIdx.x;
  const int Bc = gridDim.x >> 9;           // grid = Bc*512
  if (gid < (long)Bc * 160) {
    int b = (int)(gid / 160);
    int r = (int)(gid % 160);
    bf16x8 z;
#pragma unroll
    for (int j = 0; j < 8; j++) z[j] = (bf16_t)0.f;
    if (r < 128) {
      int rr = r >> 5;                     // 0..3
      int row = (rr < 2) ? rr : 4096 + rr; // 0,1,4098,4099
      *(bf16x8*)(hp + ((long)b * 4100 + row) * 256 + (r & 31) * 8) = z;
    } else {
      int r2 = r - 128;                    // 0..31
      int row = (r2 >> 4) ? 4097 : 0;      // 0,4097
      *(bf16x8*)(hdp + ((long)b * 4098 + row) * 128 + (r2 & 15) * 8) = z;
    }
  }
  long i8 = gid * 8;
  long r = i8 >> 8;
  int c = (int)(i8 & 255);
  int b = (int)(r >> 12), s = (int)(r & 4095);
  float4 v0 = *(const float4*)(h + i8);
  float4 v1 = *(const float4*)(h + i8 + 4);
  bf16x8 o;
  o[0] = (bf16_t)v0.x; o[1] = (bf16_t)v0.y; o[2] = (bf16_t)v0.z; o[3] = (bf16_t)v0.w;
  o[4] = (bf16_t)v1.x; o[5] = (bf16_t)v1.y; o[6] = (bf16_t)v1.z; o[7] = (bf16_t)v1.w;
  *(bf16x8*)(hp + ((long)b * 4100 + s + 2) * 256 + c) = o;
}

// ---------------------------------------------------------------------------
// Final conv (DH->1, k=3, pad=1) + sigmoid -> out [Bc,S] fp32.
// 4 lanes per output (partial sums + shfl reduce); grid Bc*64 blocks.
// ---------------------------------------------------------------------------
__global__ __launch_bounds__(256)
void conv_final(const bf16_t* __restrict__ hdp, const float* __restrict__ w2,
                const float* __restrict__ b2, float* __restrict__ out)
{
  __shared__ float ws[384];
  int t = threadIdx.x;
  for (int i = t; i < 384; i += 256) ws[i] = w2[i];  // [c][k]
  __syncthreads();
  int part = t & 3;
  long idx = (long)blockIdx.x * 64 + (t >> 2);
  int b = (int)(idx >> 12);
  const bf16_t* base = hdp + ((long)b * 4098 + (idx & 4095)) * 128;
  float a = 0.f;
#pragma unroll
  for (int k = 0; k < 3; k++) {
#pragma unroll
    for (int cc = 0; cc < 4; cc++) {
      int c8 = part + cc * 4;
      bf16x8 v = *(const bf16x8*)(base + k * 128 + c8 * 8);
#pragma unroll
      for (int j = 0; j < 8; j++) a += (float)v[j] * ws[(c8 * 8 + j) * 3 + k];
    }
  }
  a += __shfl_xor(a, 1);
  a += __shfl_xor(a, 2);
  if (part == 0) out[idx] = 1.f / (1.f + __expf(-(a + b2[0])));
}

// ---------------------------------------------------------------------------
// Prep kernels (once per launch)
// ---------------------------------------------------------------------------
__global__ __launch_bounds__(256)
void prep_weff(const float* __restrict__ wq, const float* __restrict__ wk,
               const float* __restrict__ wv, const float* __restrict__ bq,
               const float* __restrict__ bk, const float* __restrict__ bv,
               const float* __restrict__ rf, bf16_t* __restrict__ weff,
               float* __restrict__ beff)
{
  long idx = (long)blockIdx.x * 256 + threadIdx.x;  // 4*1280*256
  int d = (int)(idx & 255);
  long r = idx >> 8;
  int n = (int)(r % 1280);
  int l = (int)(r / 1280);
  float val;
  if (n < 1024) {
    int qk = n >> 9;
    int h = (n >> 6) & 7;
    int f = n & 63;
    const float* w = qk ? wk : wq;
    const float* rfh = rf + ((long)(l * 8 + h) * 32) * 64 + f;
    const float* wrow = w + ((long)l * 256 + d) * 256 + h * 32;
    float s = 0.f;
#pragma unroll
    for (int hd = 0; hd < 32; hd++) s += wrow[hd] * rfh[hd * 64];
    val = s;
  } else {
    val = wv[((long)l * 256 + d) * 256 + (n - 1024)];
  }
  weff[idx] = (bf16_t)val;
  if (idx < 4 * 1280) {
    int nn = (int)(idx % 1280);
    int ll = (int)(idx / 1280);
    float bvv;
    if (nn < 1024) {
      int qk = nn >> 9;
      int h = (nn >> 6) & 7;
      int f = nn & 63;
      const float* bsrc = qk ? bk : bq;
      float s = 0.f;
      for (int hd = 0; hd < 32; hd++)
        s += bsrc[ll * 256 + h * 32 + hd] * rf[((long)(ll * 8 + h) * 32 + hd) * 64 + f];
      bvv = s;
    } else {
      bvv = bv[ll * 256 + (nn - 1024)];
    }
    beff[idx] = bvv;
  }
}

// 32x32 LDS-tiled transpose+cast: src fp32 [l][K][N] -> dst bf16 [l][N][K].
__global__ __launch_bounds__(256)
void prep_cast_t32(const float* __restrict__ src, bf16_t* __restrict__ dst,
                   int K, int N)
{
  __shared__ float tile[32][33];
  const int kt = K >> 5, nt = N >> 5;
  int bid = blockIdx.x;
  int l = bid / (kt * nt);
  int rem = bid % (kt * nt);
  int ntile = rem / kt;          // n-tile index
  int ktile = rem % kt;          // k-tile index
  int n0 = ntile * 32, k0 = ktile * 32;
  int t = threadIdx.x;
  int c = t & 31, rbase = t >> 5;  // 8 rows per pass
#pragma unroll
  for (int i = 0; i < 4; i++) {
    int r = rbase + i * 8;
    tile[r][c] = src[((long)l * K + k0 + r) * N + n0 + c];
  }
  __syncthreads();
#pragma unroll
  for (int i = 0; i < 4; i++) {
    int r = rbase + i * 8;
    dst[((long)l * N + n0 + r) * K + k0 + c] = (bf16_t)tile[c][r];
  }
}

__global__ __launch_bounds__(256)
void prep_conv_t(const float* __restrict__ w, bf16_t* __restrict__ dst, int C, int KW)
{
  long idx = (long)blockIdx.x * 256 + threadIdx.x;  // O*C*KW
  int ckw = C * KW;
  int kk = (int)(idx % ckw);
  int o = (int)(idx / ckw);
  int kw = kk / C, c = kk % C;
  dst[idx] = (bf16_t)w[((long)o * C + c) * KW + kw];
}

__global__ __launch_bounds__(256)
void prep_bn(const float* g1, const float* b1, const float* cb1,
             const float* g2, const float* b2, const float* cb2,
             const float* g3, const float* b3, const float* cb3,
             float* sc1, float* sb1, float* sc2, float* sb2,
             float* sc3, float* sb3)
{
  int t = threadIdx.x;
  const float r = rsqrtf(1.f + 1e-5f);
  if (t < 128) { float s = g1[t] * r; sc1[t] = s; sb1[t] = cb1[t] * s + b1[t]; }
  if (t < 256) { float s = g2[t] * r; sc2[t] = s; sb2[t] = cb2[t] * s + b2[t]; }
  if (t < 128) { float s = g3[t] * r; sc3[t] = s; sb3[t] = cb3[t] * s + b3[t]; }
}

__global__ __launch_bounds__(256)
void pe_fill(float* __restrict__ pe)
{
  long idx = (long)blockIdx.x * 256 + threadIdx.x;  // 4096*256
  int dcol = (int)(idx & 255);
  int s = (int)(idx >> 8);
  int i2 = dcol >> 1;
  float freq = expf(-9.210340371976184f * (float)(2 * i2) / 256.f);
  float a = (float)s * freq;
  pe[idx] = (dcol & 1) ? cosf(a) : sinf(a);
}

// ---------------------------------------------------------------------------
extern "C" void kernel_launch(void* const* d_in, const int* in_sizes, int n_in,
                              void* d_out, int out_size, void* d_ws, size_t ws_size,
                              hipStream_t stream)
{
  (void)in_sizes; (void)n_in; (void)out_size;
  const float* x      = (const float*)d_in[0];
  const float* emb_w1 = (const float*)d_in[1];
  const float* emb_b1 = (const float*)d_in[2];
  const float* bn1_g  = (const float*)d_in[3];
  const float* bn1_b  = (const float*)d_in[4];
  const float* emb_w2 = (const float*)d_in[5];
  const float* emb_b2 = (const float*)d_in[6];
  const float* bn2_g  = (const float*)d_in[7];
  const float* bn2_b  = (const float*)d_in[8];
  const float* wq     = (const float*)d_in[9];
  const float* bq     = (const float*)d_in[10];
  const float* wk     = (const float*)d_in[11];
  const float* bk     = (const float*)d_in[12];
  const float* wv     = (const float*)d_in[13];
  const float* bv     = (const float*)d_in[14];
  const float* wo     = (const float*)d_in[15];
  const float* bo     = (const float*)d_in[16];
  const float* rf     = (const float*)d_in[17];
  const float* ln1_g  = (const float*)d_in[18];
  const float* ln1_b  = (const float*)d_in[19];
  const float* ln2_g  = (const float*)d_in[20];
  const float* ln2_b  = (const float*)d_in[21];
  const float* ff_w1  = (const float*)d_in[22];
  const float* ff_b1  = (const float*)d_in[23];
  const float* ff_w2  = (const float*)d_in[24];
  const float* ff_b2  = (const float*)d_in[25];
  const float* dec_w1 = (const float*)d_in[26];
  const float* dec_b1 = (const float*)d_in[27];
  const float* bn3_g  = (const float*)d_in[28];
  const float* bn3_b  = (const float*)d_in[29];
  const float* dec_w2 = (const float*)d_in[30];
  const float* dec_b2 = (const float*)d_in[31];

  char* W = (char*)d_ws;

  // ---- fixed region (weights, ~12.2 MB; reserve 16 MB) ----
  bf16_t* weff = (bf16_t*)(W + 0);                     // 4*1280*256*2 = 2,621,440
  float*  beff = (float*)(W + 2621440);                // 20,480
  bf16_t* wot  = (bf16_t*)(W + 2641920);               // 524,288
  bf16_t* w1t  = (bf16_t*)(W + 3166208);               // 2,097,152
  bf16_t* w2t  = (bf16_t*)(W + 5263360);               // 2,097,152
  bf16_t* c2t  = (bf16_t*)(W + 7360512);               // 327,680
  bf16_t* d1t  = (bf16_t*)(W + 7688192);               // 327,680
  float*  pe   = (float*)(W + 8015872);                // 4,194,304
  float*  sc1  = (float*)(W + 12210176);
  float*  sb1  = (float*)(W + 12211200);
  float*  sc2  = (float*)(W + 12212224);
  float*  sb2  = (float*)(W + 12213248);
  float*  sc3  = (float*)(W + 12214272);
  float*  sb3  = (float*)(W + 12215296);
  const size_t FIXED_END = 16777216;

  // ---- pick batch chunk Bc so workspace fits ws_size ----
  // per-B: h 4MB + ao 2MB + big 10MB + pkv 512K + pks 16K + kvb 54K
  const size_t PER_B = 17440768;
  int Bc = 32;
  while (Bc > 1 && FIXED_END + (size_t)Bc * PER_B > ws_size) Bc >>= 1;

  char* P = W + FIXED_END;
  float*  h     = (float*)P;
  bf16_t* xa    = (bf16_t*)(P + (size_t)Bc * 4194304);
  bf16_t* ao    = xa;  // xa dead after fused qkv gemm; ao dead before ln2
  char*   big   = P + (size_t)Bc * (4194304 + 2097152);
  bf16_t* qpkpv = (bf16_t*)big;
  bf16_t* f1    = (bf16_t*)big;                               // after qpkpv dead
  bf16_t* h1p   = (bf16_t*)big;                               // pre-loop
  bf16_t* hpad  = (bf16_t*)big;                               // post-loop
  bf16_t* hdp   = (bf16_t*)(big + (size_t)Bc * 4100 * 256 * 2);
  float*  pkv   = (float*)(big + (size_t)Bc * 10485760);
  float*  pks   = (float*)((char*)pkv + (size_t)Bc * 524288);
  bf16_t* kvb   = (bf16_t*)((char*)pks + (size_t)Bc * 16384);

  // ---- weight prep (once) ----
  prep_weff<<<5120, 256, 0, stream>>>(wq, wk, wv, bq, bk, bv, rf, weff, beff);
  prep_cast_t32<<<256, 256, 0, stream>>>(wo, wot, 256, 256);
  prep_cast_t32<<<1024, 256, 0, stream>>>(ff_w1, w1t, 256, 1024);
  prep_cast_t32<<<1024, 256, 0, stream>>>(ff_w2, w2t, 1024, 256);
  prep_conv_t<<<640, 256, 0, stream>>>(emb_w2, c2t, 128, 5);
  prep_conv_t<<<640, 256, 0, stream>>>(dec_w1, d1t, 256, 5);
  prep_bn<<<1, 256, 0, stream>>>(bn1_g, bn1_b, emb_b1, bn2_g, bn2_b, emb_b2,
                                 bn3_g, bn3_b, dec_b1, sc1, sb1, sc2, sb2, sc3, sb3);
  pe_fill<<<4096, 256, 0, stream>>>(pe);

  for (int c0 = 0; c0 < 32; c0 += Bc) {
    const float* xc = x + (size_t)c0 * 4096;

    // ---- embedding (conv1 zeroes its own pad rows) ----
    conv1_kernel<<<Bc * 64, 256, 0, stream>>>(xc, emb_w1, sc1, sb1, h1p);
    gemm_bf16<3, 640, 64, 4><<<Bc * 128, 256, 0, stream>>>(
        h1p, c2t, h, sb2, sc2, nullptr, pe,
        128, 4100L * 128, 4096, 256, 256, 4096L * 256, 0);

    // ---- transformer layers ----
    for (int l = 0; l < 4; l++) {
      ln_kernel<<<Bc * 256, 256, 0, stream>>>(h, ln1_g + l * 256, ln1_b + l * 256, xa);
      gemm_bf16<5, 256, 128, 10><<<Bc * 320, 256, 0, stream>>>(
          xa, weff + (long)l * 327680, qpkpv, beff + l * 1280, nullptr, nullptr, nullptr,
          256, 4096L * 256, 4096, 1280, 1280, 4096L * 1280, 0);
      kv_partial<<<Bc * 64, 256, 0, stream>>>(qpkpv, pkv, pks);
      kv_reduce_b<<<Bc * 32, 256, 0, stream>>>(pkv, pks, kvb);
      combine_mfma<<<Bc * 256, 256, 0, stream>>>(qpkpv, kvb, ao);
      gemm_bf16<1, 256, 64, 4><<<Bc * 128, 256, 0, stream>>>(
          ao, wot + (long)l * 65536, h, bo + l * 256, nullptr, h, nullptr,
          256, 4096L * 256, 4096, 256, 256, 4096L * 256, 0);
      ln_kernel<<<Bc * 256, 256, 0, stream>>>(h, ln2_g + l * 256, ln2_b + l * 256, xa);
      gemm_bf16<2, 256, 128, 8><<<Bc * 256, 256, 0, stream>>>(
          xa, w1t + (long)l * 262144, f1, ff_b1 + l * 1024, nullptr, nullptr, nullptr,
          256, 4096L * 256, 4096, 1024, 1024, 4096L * 1024, 0);
      gemm_bf16<1, 1024, 64, 4><<<Bc * 128, 256, 0, stream>>>(
          f1, w2t + (long)l * 262144, h, ff_b2 + l * 256, nullptr, h, nullptr,
          1024, 4096L * 1024, 4096, 256, 256, 4096L * 256, 0);
    }

    // ---- decoder (cast_pad zeroes hpad + hdp pad rows) ----
    cast_pad<<<Bc * 512, 256, 0, stream>>>(h, hpad, hdp);
    gemm_bf16<4, 1280, 64, 2><<<Bc * 64, 256, 0, stream>>>(
        hpad, d1t, hdp, sb3, sc3, nullptr, nullptr,
        256, 4100L * 256, 4096, 128, 128, 4098L * 128, 1);
    conv_final<<<Bc * 64, 256, 0, stream>>>(hdp, dec_w2, dec_b2,
                                            (float*)d_out + (size_t)c0 * 4096);
  }
}